// Round 1
// baseline (3366.289 us; speedup 1.0000x reference)
//
#include <hip/hip_runtime.h>
#include <math.h>

// Banyan compose: phase-1 schedule construction + phase-2 CE replay, all on device.
// Sizes: B=64, L=64, E=256, CH=16. V=30000.
// N0 = #unique tokens (minus pad) <= 4095; merges <= 4032 -> N <= 8127 (+2 for eos/sos).
// T = 2 * total merges <= 8064.

#define HASH_SIZE 32768
#define HASH_MASK 32767
#define NMAX 8192
#define PRES 30720

__device__ __forceinline__ unsigned hash0(int key) {
    return (((unsigned)key) * 2654435761u) >> 17; // 15 bits
}

// ---- setup kernels ----

__global__ void mark_kernel(const int* __restrict__ x, int* __restrict__ presence) {
    int i = blockIdx.x * blockDim.x + threadIdx.x;
    if (i < 4096) presence[x[i]] = 1;
}

__global__ __launch_bounds__(1024) void scan_kernel(const int* __restrict__ presence,
                                                    int* __restrict__ rank,
                                                    int* __restrict__ tokens,
                                                    int* __restrict__ meta) {
    __shared__ int part[1024];
    int tid = threadIdx.x;
    int base = tid * 30;
    int loc[30];
    int s = 0;
#pragma unroll
    for (int i = 0; i < 30; ++i) { loc[i] = s; s += presence[base + i]; }
    part[tid] = s;
    __syncthreads();
    for (int off = 1; off < 1024; off <<= 1) {
        int v = (tid >= off) ? part[tid - off] : 0;
        __syncthreads();
        part[tid] += v;
        __syncthreads();
    }
    int excl = (tid == 0) ? 0 : part[tid - 1];
#pragma unroll
    for (int i = 0; i < 30; ++i) {
        int r = excl + loc[i];
        rank[base + i] = r;
        if (presence[base + i]) tokens[r] = base + i;
    }
    if (tid == 1023) { meta[0] = part[1023]; meta[1] = part[1023] - 1; }
}

__global__ void map_index_kernel(const int* __restrict__ x, const int* __restrict__ rank,
                                 const int* __restrict__ meta, int* __restrict__ index_g) {
    int i = blockIdx.x * blockDim.x + threadIdx.x;
    if (i < 4096) {
        int r = rank[x[i]];
        index_g[i] = (r == meta[0] - 1) ? -1 : r;  // largest unique token (pad) -> -1
    }
}

// one block per node: gather emb row, compute norm
__global__ void copy_feats_kernel(const float* __restrict__ emb, const int* __restrict__ tokens,
                                  const int* __restrict__ meta, float* __restrict__ feats,
                                  float* __restrict__ norms) {
    int n = blockIdx.x;
    if (n >= meta[1]) return;
    int t = tokens[n];
    int k = threadIdx.x; // 64 threads
    const float4* src = (const float4*)(emb + (size_t)t * 256);
    float4* dst = (float4*)(feats + (size_t)n * 256);
    float4 v = src[k];
    dst[k] = v;
    float ss = v.x * v.x + v.y * v.y + v.z * v.z + v.w * v.w;
#pragma unroll
    for (int off = 32; off >= 1; off >>= 1) ss += __shfl_down(ss, off);
    if (k == 0) norms[n] = sqrtf(ss);
}

// one block per (row b, pair j): initial cosine
__global__ void init_cos_kernel(const float* __restrict__ feats, const float* __restrict__ norms,
                                const int* __restrict__ index_g, float* __restrict__ cos_g) {
    int bid = blockIdx.x;
    int b = bid / 63, j = bid % 63;
    int l = index_g[b * 64 + j], r = index_g[b * 64 + j + 1];
    float c = -INFINITY;
    if (r != -1) {
        int k = threadIdx.x; // 64
        const float4* fa = (const float4*)(feats + (size_t)l * 256);
        const float4* fb = (const float4*)(feats + (size_t)r * 256);
        float4 a = fa[k], bb = fb[k];
        float d = a.x * bb.x + a.y * bb.y + a.z * bb.z + a.w * bb.w;
#pragma unroll
        for (int off = 32; off >= 1; off >>= 1) d += __shfl_down(d, off);
        c = d / fmaxf(norms[l] * norms[r], 1e-8f);
    }
    if (threadIdx.x == 0) cos_g[b * 64 + j] = c;
}

// ---- the sequential merge loop: single block, 256 threads ----

__global__ __launch_bounds__(256) void iterate_kernel(
    float* __restrict__ feats, float* __restrict__ norms,
    const int* __restrict__ index_g, const float* __restrict__ cos_g,
    int* __restrict__ hk, int* __restrict__ hv,
    int* __restrict__ targets, int* __restrict__ meta,
    const float* __restrict__ comp_l, const float* __restrict__ comp_r,
    const float* __restrict__ cb, const float* __restrict__ eos,
    const float* __restrict__ sos) {
    __shared__ int s_idx[64][64];
    __shared__ float s_cos[64][64];
    __shared__ int s_ms[64], s_l[64], s_r[64], s_ls[64], s_rs[64], s_nid[64], s_key[64];
    __shared__ int s_act[64], s_new[64], s_first[64];
    __shared__ int s_rank[64], s_actrank[64];
    __shared__ int s_pairL[64], s_pairR[64];
    __shared__ int s_nact, s_newcount;
    __shared__ float s_sl[16], s_sr[16], s_cb[16];
    __shared__ float s_red[256];

    int tid = threadIdx.x;
    for (int i = tid; i < 64 * 64; i += 256) {
        s_idx[i >> 6][i & 63] = index_g[i];
        s_cos[i >> 6][i & 63] = cos_g[i];
    }
    if (tid < 16) {
        s_sl[tid] = 1.f / (1.f + __expf(-comp_l[tid]));
        s_sr[tid] = 1.f / (1.f + __expf(-comp_r[tid]));
        s_cb[tid] = cb[tid];
    }
    int Ncur = meta[1];
    int Tcur = 0;
    __syncthreads();

    for (int W = 64; W >= 2; --W) {
        int base = Ncur;
        // Phase A: per-row argmax + candidate
        if (tid < 64) {
            int b = tid;
            int act = (s_idx[b][1] != -1) ? 1 : 0;
            s_act[b] = act;
            s_new[b] = 0;
            if (act) {
                float best = -INFINITY;
                int ms = 0;
                for (int j = 0; j < W - 1; ++j) {
                    float c = s_cos[b][j];
                    if (c > best) { best = c; ms = j; }
                }
                s_ms[b] = ms;
                int l = s_idx[b][ms], r = s_idx[b][ms + 1];
                s_l[b] = l; s_r[b] = r;
                s_ls[b] = (ms == 0) ? -1 : s_idx[b][ms - 1];
                s_rs[b] = (ms + 2 == W) ? -2 : s_idx[b][ms + 2];
                int key = l * 8192 + r;
                s_key[b] = key;
                unsigned h = hash0(key);
                int nid = -1;
                int found = 0;
                while (true) {
                    int k2 = hk[h];
                    if (k2 == -1) break;
                    if (k2 == key) { found = 1; nid = hv[h]; break; }
                    h = (h + 1) & HASH_MASK;
                }
                s_nid[b] = nid;
                s_new[b] = found ? 0 : 1;
            }
        }
        __syncthreads();
        // Phase B1: first-occurrence + active rank
        if (tid < 64) {
            int b = tid;
            int f = 0;
            if (s_new[b]) {
                f = 1;
                for (int j = 0; j < b; ++j)
                    if (s_new[j] && s_key[j] == s_key[b]) { f = 0; break; }
            }
            s_first[b] = f;
            int ar = 0;
            for (int j = 0; j < b; ++j) ar += s_act[j];
            s_actrank[b] = ar;
            if (b == 63) s_nact = ar + s_act[63];
        }
        __syncthreads();
        // Phase B2: rank among sorted new keys
        if (tid < 64) {
            int b = tid;
            if (s_new[b]) {
                int rk = 0;
                for (int j = 0; j < 64; ++j)
                    if (s_first[j] && s_key[j] < s_key[b]) rk++;
                s_rank[b] = rk;
            }
            if (b == 63) {
                int nc = 0;
                for (int j = 0; j < 64; ++j) nc += s_first[j];
                s_newcount = nc;
            }
        }
        __syncthreads();
        // Phase C: assign node ids, insert hash, record targets + pair map
        if (tid < 64) {
            int b = tid;
            if (s_act[b]) {
                int nid = s_new[b] ? (base + s_rank[b]) : s_nid[b];
                s_nid[b] = nid;
                if (s_first[b]) {
                    s_pairL[s_rank[b]] = s_l[b];
                    s_pairR[s_rank[b]] = s_r[b];
                    unsigned h = hash0(s_key[b]);
                    while (true) {
                        int prev = atomicCAS(&hk[h], -1, s_key[b]);
                        if (prev == -1) { hv[h] = nid; break; }
                        h = (h + 1) & HASH_MASK;
                    }
                }
                int o1 = Tcur + s_actrank[b];
                targets[o1 * 3 + 0] = s_l[b];
                targets[o1 * 3 + 1] = s_ls[b];
                targets[o1 * 3 + 2] = s_r[b];
                int o2 = Tcur + s_nact + s_actrank[b];
                targets[o2 * 3 + 0] = s_r[b];
                targets[o2 * 3 + 1] = s_l[b];
                targets[o2 * 3 + 2] = s_rs[b];
            }
        }
        __syncthreads();
        // Phase D: compose new node features
        {
            int total = s_newcount * 256;
            for (int idx = tid; idx < total; idx += 256) {
                int k = idx >> 8, e = idx & 255, col = e & 15;
                float lv = feats[(size_t)s_pairL[k] * 256 + e];
                float rv = feats[(size_t)s_pairR[k] * 256 + e];
                feats[(size_t)(base + k) * 256 + e] = lv * s_sl[col] + rv * s_sr[col] + s_cb[col];
            }
        }
        __syncthreads();
        // Phase D2: norms of new nodes
        if (tid < s_newcount) {
            const float* f = feats + (size_t)(base + tid) * 256;
            float ss = 0.f;
#pragma unroll 8
            for (int e = 0; e < 256; ++e) { float v = f[e]; ss += v * v; }
            norms[base + tid] = sqrtf(ss);
        }
        __syncthreads();
        // Phase E: index compaction + cos shift (row-private, serial per row)
        if (tid < 64) {
            int b = tid;
            if (s_act[b]) {
                int ms = s_ms[b];
                s_idx[b][ms] = s_nid[b];
                for (int j = ms + 1; j < W - 1; ++j) s_idx[b][j] = s_idx[b][j + 1];
                for (int j = ms + 1; j <= W - 3; ++j) s_cos[b][j] = s_cos[b][j + 1];
            }
        }
        __syncthreads();
        // Phase F: recompute cos for the two pairs adjacent to the merge
        {
            int s = tid >> 1;
            int half = tid & 1;
            int b2 = s >> 1;
            int which = s & 1;
            int Wn = W - 1;
            float partial = 0.f;
            int jj = -2, ln = -1, rn = -1;
            if (s_act[b2]) {
                int ms = s_ms[b2];
                int j = (which == 0) ? (ms - 1) : ms;
                if (j >= 0 && j <= Wn - 2) {
                    jj = j;
                    ln = s_idx[b2][j];
                    rn = s_idx[b2][j + 1];
                    if (rn != -1) {
                        const float* fa = feats + (size_t)ln * 256 + half * 128;
                        const float* fb = feats + (size_t)rn * 256 + half * 128;
#pragma unroll 16
                        for (int e = 0; e < 128; ++e) partial += fa[e] * fb[e];
                    }
                }
            }
            s_red[tid] = partial;
            __syncthreads();
            if (half == 0 && jj != -2) {
                if (rn == -1) {
                    s_cos[b2][jj] = -INFINITY;
                } else {
                    float d = s_red[tid] + s_red[tid + 1];
                    s_cos[b2][jj] = d / fmaxf(norms[ln] * norms[rn], 1e-8f);
                }
            }
        }
        __syncthreads();
        Ncur += s_newcount;
        Tcur += 2 * s_nact;
        __syncthreads();
    }
    // append eos, sos
    {
        int e = tid;
        if (e < 256) {
            feats[(size_t)Ncur * 256 + e] = eos[e];
            feats[(size_t)(Ncur + 1) * 256 + e] = sos[e];
        }
    }
    if (tid == 0) { meta[2] = Ncur; meta[3] = Tcur; }
}

// ---- loss: 16 triples per block, online logsumexp over all nodes ----

__global__ __launch_bounds__(256) void loss_kernel(
    const float* __restrict__ feats, const int* __restrict__ targets,
    const int* __restrict__ meta, const float* __restrict__ comp_l,
    const float* __restrict__ comp_r, const float* __restrict__ cb,
    float* __restrict__ acc) {
    __shared__ float s_out[16][260];
    __shared__ float s_tile[32][260];
    __shared__ float s_sl[16], s_sr[16], s_cb[16];
    int T = meta[3];
    int Ntot = meta[2] + 2;
    int t0base = blockIdx.x * 16;
    if (t0base >= T) return;
    int tid = threadIdx.x;
    if (tid < 16) {
        s_sl[tid] = 1.f / (1.f + __expf(-comp_l[tid]));
        s_sr[tid] = 1.f / (1.f + __expf(-comp_r[tid]));
        s_cb[tid] = cb[tid];
    }
    __syncthreads();
    for (int idx = tid; idx < 16 * 256; idx += 256) {
        int tt = idx >> 8, e = idx & 255;
        int ti = t0base + tt;
        float v = 0.f;
        if (ti < T) {
            int i1 = targets[ti * 3 + 1], i2 = targets[ti * 3 + 2];
            if (i1 < 0) i1 += Ntot;
            if (i2 < 0) i2 += Ntot;
            v = feats[(size_t)i1 * 256 + e] * s_sl[e & 15] +
                feats[(size_t)i2 * 256 + e] * s_sr[e & 15] + s_cb[e & 15];
        }
        s_out[tt][e] = v;
    }
    __syncthreads();
    int g = tid >> 4, k = tid & 15;
    int ti = t0base + g;
    bool act = ti < T;
    float m = -INFINITY, ssum = 0.f;
    for (int nb = 0; nb < Ntot; nb += 32) {
        int cnt = min(32, Ntot - nb);
        for (int idx = tid; idx < cnt * 64; idx += 256) {
            int row = idx >> 6, c4 = idx & 63;
            ((float4*)(&s_tile[row][0]))[c4] =
                ((const float4*)(feats + (size_t)(nb + row) * 256))[c4];
        }
        __syncthreads();
        if (act) {
#pragma unroll
            for (int rr = 0; rr < 2; ++rr) {
                int n = k + rr * 16;
                if (n < cnt) {
                    const float4* fo = (const float4*)(&s_out[g][0]);
                    const float4* fn = (const float4*)(&s_tile[n][0]);
                    float d = 0.f;
#pragma unroll
                    for (int e4 = 0; e4 < 64; ++e4) {
                        float4 a = fo[e4], b = fn[e4];
                        d += a.x * b.x + a.y * b.y + a.z * b.z + a.w * b.w;
                    }
                    if (d > m) { ssum = ssum * __expf(m - d) + 1.f; m = d; }
                    else ssum += __expf(d - m);
                }
            }
        }
        __syncthreads();
    }
    for (int off = 1; off < 16; off <<= 1) {
        float m2 = __shfl_xor(m, off);
        float s2 = __shfl_xor(ssum, off);
        float mn = fmaxf(m, m2);
        ssum = ssum * __expf(m - mn) + s2 * __expf(m2 - mn);
        m = mn;
    }
    float tl = 0.f;
    if (act) {
        int t0 = targets[ti * 3 + 0];
        const float* ft = feats + (size_t)t0 * 256;
        const float* fo = &s_out[g][0];
#pragma unroll
        for (int e = 0; e < 16; ++e) tl += fo[k * 16 + e] * ft[k * 16 + e];
    }
    for (int off = 1; off < 16; off <<= 1) tl += __shfl_xor(tl, off);
    if (act && k == 0) atomicAdd(acc, (m + __logf(ssum)) - tl);
}

__global__ void finalize_kernel(const float* __restrict__ acc, const int* __restrict__ meta,
                                float* __restrict__ out) {
    out[0] = acc[0] / (float)meta[3];
}

extern "C" void kernel_launch(void* const* d_in, const int* in_sizes, int n_in,
                              void* d_out, int out_size, void* d_ws, size_t ws_size,
                              hipStream_t stream) {
    const int* x = (const int*)d_in[0];
    const float* emb = (const float*)d_in[1];
    const float* comp_l = (const float*)d_in[2];
    const float* comp_r = (const float*)d_in[3];
    const float* cb = (const float*)d_in[4];
    const float* sos = (const float*)d_in[5];
    const float* eos = (const float*)d_in[6];
    float* out = (float*)d_out;

    float* feats = (float*)d_ws;                 // 8192*256
    float* norms = feats + (size_t)NMAX * 256;   // 8192
    int* index_g = (int*)(norms + NMAX);         // 4096
    float* cos_g = (float*)(index_g + 4096);     // 4096
    int* presence = (int*)(cos_g + 4096);        // 30720
    int* rankbuf = presence + PRES;              // 30720
    int* tokens = rankbuf + PRES;                // 4096
    int* hk = tokens + 4096;                     // 32768
    int* hv = hk + HASH_SIZE;                    // 32768
    int* targets = hv + HASH_SIZE;               // 8192*3
    int* meta = targets + NMAX * 3;              // 64
    float* acc = (float*)(meta + 64);            // 1

    hipMemsetAsync(presence, 0, PRES * sizeof(int), stream);
    hipMemsetAsync(hk, 0xFF, HASH_SIZE * sizeof(int), stream);
    hipMemsetAsync(acc, 0, sizeof(float), stream);

    mark_kernel<<<16, 256, 0, stream>>>(x, presence);
    scan_kernel<<<1, 1024, 0, stream>>>(presence, rankbuf, tokens, meta);
    map_index_kernel<<<16, 256, 0, stream>>>(x, rankbuf, meta, index_g);
    copy_feats_kernel<<<4096, 64, 0, stream>>>(emb, tokens, meta, feats, norms);
    init_cos_kernel<<<64 * 63, 64, 0, stream>>>(feats, norms, index_g, cos_g);
    iterate_kernel<<<1, 256, 0, stream>>>(feats, norms, index_g, cos_g, hk, hv,
                                          targets, meta, comp_l, comp_r, cb, eos, sos);
    loss_kernel<<<504, 256, 0, stream>>>(feats, targets, meta, comp_l, comp_r, cb, acc);
    finalize_kernel<<<1, 1, 0, stream>>>(acc, meta, out);
}

// Round 2
// 2502.877 us; speedup vs baseline: 1.3450x; 1.3450x over previous
//
#include <hip/hip_runtime.h>
#include <math.h>

// Banyan compose: phase-1 schedule construction + phase-2 CE replay, all on device.
// Sizes: B=64, L=64, E=256, CH=16. V=30000.

#define HASH_SIZE 32768
#define HASH_MASK 32767
#define NMAX 8192
#define PRES 30720

__device__ __forceinline__ unsigned hash0(int key) {
    return (((unsigned)key) * 2654435761u) >> 17; // 15 bits
}

// ---- setup kernels ----

__global__ void mark_kernel(const int* __restrict__ x, int* __restrict__ presence) {
    int i = blockIdx.x * blockDim.x + threadIdx.x;
    if (i < 4096) presence[x[i]] = 1;
}

__global__ __launch_bounds__(1024) void scan_kernel(const int* __restrict__ presence,
                                                    int* __restrict__ rank,
                                                    int* __restrict__ tokens,
                                                    int* __restrict__ meta) {
    __shared__ int part[1024];
    int tid = threadIdx.x;
    int base = tid * 30;
    int loc[30];
    int s = 0;
#pragma unroll
    for (int i = 0; i < 30; ++i) { loc[i] = s; s += presence[base + i]; }
    part[tid] = s;
    __syncthreads();
    for (int off = 1; off < 1024; off <<= 1) {
        int v = (tid >= off) ? part[tid - off] : 0;
        __syncthreads();
        part[tid] += v;
        __syncthreads();
    }
    int excl = (tid == 0) ? 0 : part[tid - 1];
#pragma unroll
    for (int i = 0; i < 30; ++i) {
        int r = excl + loc[i];
        rank[base + i] = r;
        if (presence[base + i]) tokens[r] = base + i;
    }
    if (tid == 1023) { meta[0] = part[1023]; meta[1] = part[1023] - 1; }
}

__global__ void map_index_kernel(const int* __restrict__ x, const int* __restrict__ rank,
                                 const int* __restrict__ meta, int* __restrict__ index_g) {
    int i = blockIdx.x * blockDim.x + threadIdx.x;
    if (i < 4096) {
        int r = rank[x[i]];
        index_g[i] = (r == meta[0] - 1) ? -1 : r;  // largest unique token (pad) -> -1
    }
}

// one block per node: gather emb row, compute norm
__global__ void copy_feats_kernel(const float* __restrict__ emb, const int* __restrict__ tokens,
                                  const int* __restrict__ meta, float* __restrict__ feats,
                                  float* __restrict__ norms) {
    int n = blockIdx.x;
    if (n >= meta[1]) return;
    int t = tokens[n];
    int k = threadIdx.x; // 64 threads
    const float4* src = (const float4*)(emb + (size_t)t * 256);
    float4* dst = (float4*)(feats + (size_t)n * 256);
    float4 v = src[k];
    dst[k] = v;
    float ss = v.x * v.x + v.y * v.y + v.z * v.z + v.w * v.w;
#pragma unroll
    for (int off = 32; off >= 1; off >>= 1) ss += __shfl_down(ss, off);
    if (k == 0) norms[n] = sqrtf(ss);
}

// one block per (row b, pair j): initial cosine
__global__ void init_cos_kernel(const float* __restrict__ feats, const float* __restrict__ norms,
                                const int* __restrict__ index_g, float* __restrict__ cos_g) {
    int bid = blockIdx.x;
    int b = bid / 63, j = bid % 63;
    int l = index_g[b * 64 + j], r = index_g[b * 64 + j + 1];
    float c = -INFINITY;
    if (r != -1) {
        int k = threadIdx.x; // 64
        const float4* fa = (const float4*)(feats + (size_t)l * 256);
        const float4* fb = (const float4*)(feats + (size_t)r * 256);
        float4 a = fa[k], bb = fb[k];
        float d = a.x * bb.x + a.y * bb.y + a.z * bb.z + a.w * bb.w;
#pragma unroll
        for (int off = 32; off >= 1; off >>= 1) d += __shfl_down(d, off);
        c = d / fmaxf(norms[l] * norms[r], 1e-8f);
    }
    if (threadIdx.x == 0) cos_g[b * 64 + j] = c;
}

// ---- the sequential merge loop: single block, 1024 threads (16 waves) ----

__global__ __launch_bounds__(1024) void iterate_kernel(
    float* __restrict__ feats, float* __restrict__ norms,
    const int* __restrict__ index_g, const float* __restrict__ cos_g,
    int* __restrict__ hk, int* __restrict__ hv,
    int* __restrict__ targets, int* __restrict__ meta,
    const float* __restrict__ comp_l, const float* __restrict__ comp_r,
    const float* __restrict__ cb, const float* __restrict__ eos,
    const float* __restrict__ sos) {
    __shared__ int s_idx[64][65];    // padded: kills bank conflicts on column access
    __shared__ float s_cos[64][65];
    __shared__ int s_ms[64], s_l[64], s_r[64], s_ls[64], s_rs[64], s_nid[64], s_key[64];
    __shared__ int s_act[64], s_new[64], s_first[64];
    __shared__ int s_rank[64], s_actrank[64];
    __shared__ int s_pairL[64], s_pairR[64];
    __shared__ int s_nact, s_newcount;
    __shared__ float s_sl[16], s_sr[16], s_cb[16];

    int tid = threadIdx.x;
    int lane = tid & 63, wave = tid >> 6;
    for (int i = tid; i < 64 * 64; i += 1024) {
        s_idx[i >> 6][i & 63] = index_g[i];
        s_cos[i >> 6][i & 63] = cos_g[i];
    }
    if (tid < 16) {
        s_sl[tid] = 1.f / (1.f + __expf(-comp_l[tid]));
        s_sr[tid] = 1.f / (1.f + __expf(-comp_r[tid]));
        s_cb[tid] = cb[tid];
    }
    int Ncur = meta[1];
    int Tcur = 0;
    __syncthreads();
    // per-lane compose coefficients for float4 at element offset 4*lane
    int c0 = 4 * (lane & 3);
    float4 sl4 = make_float4(s_sl[c0], s_sl[c0 + 1], s_sl[c0 + 2], s_sl[c0 + 3]);
    float4 sr4 = make_float4(s_sr[c0], s_sr[c0 + 1], s_sr[c0 + 2], s_sr[c0 + 3]);
    float4 cb4 = make_float4(s_cb[c0], s_cb[c0 + 1], s_cb[c0 + 2], s_cb[c0 + 3]);

    for (int W = 64; W >= 2; --W) {
        int base = Ncur;
        // Phase A: per-row argmax + hash lookup
        if (tid < 64) {
            int b = tid;
            int act = (s_idx[b][1] != -1) ? 1 : 0;
            s_act[b] = act;
            s_new[b] = 0;
            if (act) {
                float best = -INFINITY;
                int ms = 0;
                for (int j = 0; j < W - 1; ++j) {
                    float c = s_cos[b][j];
                    if (c > best) { best = c; ms = j; }
                }
                s_ms[b] = ms;
                int l = s_idx[b][ms], r = s_idx[b][ms + 1];
                s_l[b] = l; s_r[b] = r;
                s_ls[b] = (ms == 0) ? -1 : s_idx[b][ms - 1];
                s_rs[b] = (ms + 2 == W) ? -2 : s_idx[b][ms + 2];
                int key = l * 8192 + r;
                s_key[b] = key;
                unsigned h = hash0(key);
                int nid = -1;
                int found = 0;
                while (true) {
                    int k2 = hk[h];
                    if (k2 == -1) break;
                    if (k2 == key) { found = 1; nid = hv[h]; break; }
                    h = (h + 1) & HASH_MASK;
                }
                s_nid[b] = nid;
                s_new[b] = found ? 0 : 1;
            }
        }
        __syncthreads();
        // Phase B1: first-occurrence + active rank
        if (tid < 64) {
            int b = tid;
            int f = 0;
            if (s_new[b]) {
                f = 1;
                for (int j = 0; j < b; ++j)
                    if (s_new[j] && s_key[j] == s_key[b]) { f = 0; break; }
            }
            s_first[b] = f;
            int ar = 0;
            for (int j = 0; j < b; ++j) ar += s_act[j];
            s_actrank[b] = ar;
            if (b == 63) s_nact = ar + s_act[63];
        }
        __syncthreads();
        // Phase B2: rank among sorted new keys
        if (tid < 64) {
            int b = tid;
            if (s_new[b]) {
                int rk = 0;
                for (int j = 0; j < 64; ++j)
                    if (s_first[j] && s_key[j] < s_key[b]) rk++;
                s_rank[b] = rk;
            }
            if (b == 63) {
                int nc = 0;
                for (int j = 0; j < 64; ++j) nc += s_first[j];
                s_newcount = nc;
            }
        }
        __syncthreads();
        // Phase C: assign node ids, insert hash, record targets + pair map
        if (tid < 64) {
            int b = tid;
            if (s_act[b]) {
                int nid = s_new[b] ? (base + s_rank[b]) : s_nid[b];
                s_nid[b] = nid;
                if (s_first[b]) {
                    s_pairL[s_rank[b]] = s_l[b];
                    s_pairR[s_rank[b]] = s_r[b];
                    unsigned h = hash0(s_key[b]);
                    while (true) {
                        int prev = atomicCAS(&hk[h], -1, s_key[b]);
                        if (prev == -1) { hv[h] = nid; break; }
                        h = (h + 1) & HASH_MASK;
                    }
                }
                int o1 = Tcur + s_actrank[b];
                targets[o1 * 3 + 0] = s_l[b];
                targets[o1 * 3 + 1] = s_ls[b];
                targets[o1 * 3 + 2] = s_r[b];
                int o2 = Tcur + s_nact + s_actrank[b];
                targets[o2 * 3 + 0] = s_r[b];
                targets[o2 * 3 + 1] = s_l[b];
                targets[o2 * 3 + 2] = s_rs[b];
            }
        }
        __syncthreads();
        // Phase D (fused w/ norm): one wave per new node, float4 loads + shfl reduce
        for (int kk = wave; kk < s_newcount; kk += 16) {
            const float4* fl = (const float4*)(feats + (size_t)s_pairL[kk] * 256);
            const float4* fr = (const float4*)(feats + (size_t)s_pairR[kk] * 256);
            float4 a = fl[lane], b = fr[lane];
            float4 v;
            v.x = a.x * sl4.x + b.x * sr4.x + cb4.x;
            v.y = a.y * sl4.y + b.y * sr4.y + cb4.y;
            v.z = a.z * sl4.z + b.z * sr4.z + cb4.z;
            v.w = a.w * sl4.w + b.w * sr4.w + cb4.w;
            ((float4*)(feats + (size_t)(base + kk) * 256))[lane] = v;
            float ss = v.x * v.x + v.y * v.y + v.z * v.z + v.w * v.w;
#pragma unroll
            for (int off = 32; off >= 1; off >>= 1) ss += __shfl_down(ss, off);
            if (lane == 0) norms[base + kk] = sqrtf(ss);
        }
        __syncthreads();
        // Phase E: index compaction + cos shift (row-private, serial per row)
        if (tid < 64) {
            int b = tid;
            if (s_act[b]) {
                int ms = s_ms[b];
                s_idx[b][ms] = s_nid[b];
                for (int j = ms + 1; j < W - 1; ++j) s_idx[b][j] = s_idx[b][j + 1];
                for (int j = ms + 1; j <= W - 3; ++j) s_cos[b][j] = s_cos[b][j + 1];
            }
        }
        __syncthreads();
        // Phase F: recompute cos for the two pairs adjacent to each merge.
        // One wave per dot product: 128 tasks over 16 waves, float4 + shfl reduce.
        for (int task = wave; task < 128; task += 16) {
            int b2 = task >> 1;
            int which = task & 1;
            if (!s_act[b2]) continue;
            int ms = s_ms[b2];
            int j = which ? ms : ms - 1;
            if (j < 0 || j > W - 3) continue;   // valid pair slots: 0..(W-1)-2
            int ln = s_idx[b2][j], rn = s_idx[b2][j + 1];
            float c;
            if (rn == -1) {
                c = -INFINITY;
            } else {
                const float4* fa = (const float4*)(feats + (size_t)ln * 256);
                const float4* fb = (const float4*)(feats + (size_t)rn * 256);
                float4 a = fa[lane], bb = fb[lane];
                float d = a.x * bb.x + a.y * bb.y + a.z * bb.z + a.w * bb.w;
#pragma unroll
                for (int off = 32; off >= 1; off >>= 1) d += __shfl_down(d, off);
                c = d / fmaxf(norms[ln] * norms[rn], 1e-8f);
            }
            if (lane == 0) s_cos[b2][j] = c;
        }
        __syncthreads();
        Ncur += s_newcount;
        Tcur += 2 * s_nact;
        __syncthreads();
    }
    // append eos, sos
    if (tid < 256) {
        feats[(size_t)Ncur * 256 + tid] = eos[tid];
        feats[(size_t)(Ncur + 1) * 256 + tid] = sos[tid];
    }
    if (tid == 0) { meta[2] = Ncur; meta[3] = Tcur; }
}

// ---- loss: 16 triples per block, online logsumexp over all nodes ----

__global__ __launch_bounds__(256) void loss_kernel(
    const float* __restrict__ feats, const int* __restrict__ targets,
    const int* __restrict__ meta, const float* __restrict__ comp_l,
    const float* __restrict__ comp_r, const float* __restrict__ cb,
    float* __restrict__ acc) {
    __shared__ float s_out[16][260];
    __shared__ float s_tile[32][260];
    __shared__ float s_sl[16], s_sr[16], s_cb[16];
    int T = meta[3];
    int Ntot = meta[2] + 2;
    int t0base = blockIdx.x * 16;
    if (t0base >= T) return;
    int tid = threadIdx.x;
    if (tid < 16) {
        s_sl[tid] = 1.f / (1.f + __expf(-comp_l[tid]));
        s_sr[tid] = 1.f / (1.f + __expf(-comp_r[tid]));
        s_cb[tid] = cb[tid];
    }
    __syncthreads();
    for (int idx = tid; idx < 16 * 256; idx += 256) {
        int tt = idx >> 8, e = idx & 255;
        int ti = t0base + tt;
        float v = 0.f;
        if (ti < T) {
            int i1 = targets[ti * 3 + 1], i2 = targets[ti * 3 + 2];
            if (i1 < 0) i1 += Ntot;
            if (i2 < 0) i2 += Ntot;
            v = feats[(size_t)i1 * 256 + e] * s_sl[e & 15] +
                feats[(size_t)i2 * 256 + e] * s_sr[e & 15] + s_cb[e & 15];
        }
        s_out[tt][e] = v;
    }
    __syncthreads();
    int g = tid >> 4, k = tid & 15;
    int ti = t0base + g;
    bool act = ti < T;
    float m = -INFINITY, ssum = 0.f;
    for (int nb = 0; nb < Ntot; nb += 32) {
        int cnt = min(32, Ntot - nb);
        for (int idx = tid; idx < cnt * 64; idx += 256) {
            int row = idx >> 6, c4 = idx & 63;
            ((float4*)(&s_tile[row][0]))[c4] =
                ((const float4*)(feats + (size_t)(nb + row) * 256))[c4];
        }
        __syncthreads();
        if (act) {
#pragma unroll
            for (int rr = 0; rr < 2; ++rr) {
                int n = k + rr * 16;
                if (n < cnt) {
                    const float4* fo = (const float4*)(&s_out[g][0]);
                    const float4* fn = (const float4*)(&s_tile[n][0]);
                    float d = 0.f;
#pragma unroll
                    for (int e4 = 0; e4 < 64; ++e4) {
                        float4 a = fo[e4], b = fn[e4];
                        d += a.x * b.x + a.y * b.y + a.z * b.z + a.w * b.w;
                    }
                    if (d > m) { ssum = ssum * __expf(m - d) + 1.f; m = d; }
                    else ssum += __expf(d - m);
                }
            }
        }
        __syncthreads();
    }
    for (int off = 1; off < 16; off <<= 1) {
        float m2 = __shfl_xor(m, off);
        float s2 = __shfl_xor(ssum, off);
        float mn = fmaxf(m, m2);
        ssum = ssum * __expf(m - mn) + s2 * __expf(m2 - mn);
        m = mn;
    }
    float tl = 0.f;
    if (act) {
        int t0 = targets[ti * 3 + 0];
        const float* ft = feats + (size_t)t0 * 256;
        const float* fo = &s_out[g][0];
#pragma unroll
        for (int e = 0; e < 16; ++e) tl += fo[k * 16 + e] * ft[k * 16 + e];
    }
    for (int off = 1; off < 16; off <<= 1) tl += __shfl_xor(tl, off);
    if (act && k == 0) atomicAdd(acc, (m + __logf(ssum)) - tl);
}

__global__ void finalize_kernel(const float* __restrict__ acc, const int* __restrict__ meta,
                                float* __restrict__ out) {
    out[0] = acc[0] / (float)meta[3];
}

extern "C" void kernel_launch(void* const* d_in, const int* in_sizes, int n_in,
                              void* d_out, int out_size, void* d_ws, size_t ws_size,
                              hipStream_t stream) {
    const int* x = (const int*)d_in[0];
    const float* emb = (const float*)d_in[1];
    const float* comp_l = (const float*)d_in[2];
    const float* comp_r = (const float*)d_in[3];
    const float* cb = (const float*)d_in[4];
    const float* sos = (const float*)d_in[5];
    const float* eos = (const float*)d_in[6];
    float* out = (float*)d_out;

    float* feats = (float*)d_ws;                 // 8192*256
    float* norms = feats + (size_t)NMAX * 256;   // 8192
    int* index_g = (int*)(norms + NMAX);         // 4096
    float* cos_g = (float*)(index_g + 4096);     // 4096
    int* presence = (int*)(cos_g + 4096);        // 30720
    int* rankbuf = presence + PRES;              // 30720
    int* tokens = rankbuf + PRES;                // 4096
    int* hk = tokens + 4096;                     // 32768
    int* hv = hk + HASH_SIZE;                    // 32768
    int* targets = hv + HASH_SIZE;               // 8192*3
    int* meta = targets + NMAX * 3;              // 64
    float* acc = (float*)(meta + 64);            // 1

    hipMemsetAsync(presence, 0, PRES * sizeof(int), stream);
    hipMemsetAsync(hk, 0xFF, HASH_SIZE * sizeof(int), stream);
    hipMemsetAsync(acc, 0, sizeof(float), stream);

    mark_kernel<<<16, 256, 0, stream>>>(x, presence);
    scan_kernel<<<1, 1024, 0, stream>>>(presence, rankbuf, tokens, meta);
    map_index_kernel<<<16, 256, 0, stream>>>(x, rankbuf, meta, index_g);
    copy_feats_kernel<<<4096, 64, 0, stream>>>(emb, tokens, feats != 0 ? meta : meta, feats, norms);
    init_cos_kernel<<<64 * 63, 64, 0, stream>>>(feats, norms, index_g, cos_g);
    iterate_kernel<<<1, 1024, 0, stream>>>(feats, norms, index_g, cos_g, hk, hv,
                                           targets, meta, comp_l, comp_r, cb, eos, sos);
    loss_kernel<<<504, 256, 0, stream>>>(feats, targets, meta, comp_l, comp_r, cb, acc);
    finalize_kernel<<<1, 1, 0, stream>>>(acc, meta, out);
}

// Round 3
// 1913.625 us; speedup vs baseline: 1.7591x; 1.3079x over previous
//
#include <hip/hip_runtime.h>
#include <math.h>

// Banyan compose: phase-1 schedule construction + phase-2 CE replay, all on device.
// Sizes: B=64, L=64, E=256, CH=16. V=30000.
// Node ids < 8192 (N0 <= 4095 uniques + <= 4032 merges).

#define NMAX 8192
#define PRES 30720
#define HBITS 13
#define HSIZE 8192
#define HMASK 8191

__device__ __forceinline__ unsigned hash0(int key) {
    return (((unsigned)key) * 2654435761u) >> (32 - HBITS);
}

// ---- setup kernels ----

__global__ void mark_kernel(const int* __restrict__ x, int* __restrict__ presence) {
    int i = blockIdx.x * blockDim.x + threadIdx.x;
    if (i < 4096) presence[x[i]] = 1;
}

__global__ __launch_bounds__(1024) void scan_kernel(const int* __restrict__ presence,
                                                    int* __restrict__ rank,
                                                    int* __restrict__ tokens,
                                                    int* __restrict__ meta) {
    __shared__ int part[1024];
    int tid = threadIdx.x;
    int base = tid * 30;
    int loc[30];
    int s = 0;
#pragma unroll
    for (int i = 0; i < 30; ++i) { loc[i] = s; s += presence[base + i]; }
    part[tid] = s;
    __syncthreads();
    for (int off = 1; off < 1024; off <<= 1) {
        int v = (tid >= off) ? part[tid - off] : 0;
        __syncthreads();
        part[tid] += v;
        __syncthreads();
    }
    int excl = (tid == 0) ? 0 : part[tid - 1];
#pragma unroll
    for (int i = 0; i < 30; ++i) {
        int r = excl + loc[i];
        rank[base + i] = r;
        if (presence[base + i]) tokens[r] = base + i;
    }
    if (tid == 1023) { meta[0] = part[1023]; meta[1] = part[1023] - 1; }
}

__global__ void map_index_kernel(const int* __restrict__ x, const int* __restrict__ rank,
                                 const int* __restrict__ meta, int* __restrict__ index_g) {
    int i = blockIdx.x * blockDim.x + threadIdx.x;
    if (i < 4096) {
        int r = rank[x[i]];
        index_g[i] = (r == meta[0] - 1) ? -1 : r;  // largest unique token (pad) -> -1
    }
}

// one block per node: gather emb row, compute norm
__global__ void copy_feats_kernel(const float* __restrict__ emb, const int* __restrict__ tokens,
                                  const int* __restrict__ meta, float* __restrict__ feats,
                                  float* __restrict__ norms) {
    int n = blockIdx.x;
    if (n >= meta[1]) return;
    int t = tokens[n];
    int k = threadIdx.x; // 64 threads
    const float4* src = (const float4*)(emb + (size_t)t * 256);
    float4* dst = (float4*)(feats + (size_t)n * 256);
    float4 v = src[k];
    dst[k] = v;
    float ss = v.x * v.x + v.y * v.y + v.z * v.z + v.w * v.w;
#pragma unroll
    for (int off = 32; off >= 1; off >>= 1) ss += __shfl_down(ss, off);
    if (k == 0) norms[n] = sqrtf(ss);
}

// one block per (row b, pair j): initial cosine
__global__ void init_cos_kernel(const float* __restrict__ feats, const float* __restrict__ norms,
                                const int* __restrict__ index_g, float* __restrict__ cos_g) {
    int bid = blockIdx.x;
    int b = bid / 63, j = bid % 63;
    int l = index_g[b * 64 + j], r = index_g[b * 64 + j + 1];
    float c = -INFINITY;
    if (r != -1) {
        int k = threadIdx.x; // 64
        const float4* fa = (const float4*)(feats + (size_t)l * 256);
        const float4* fb = (const float4*)(feats + (size_t)r * 256);
        float4 a = fa[k], bb = fb[k];
        float d = a.x * bb.x + a.y * bb.y + a.z * bb.z + a.w * bb.w;
#pragma unroll
        for (int off = 32; off >= 1; off >>= 1) d += __shfl_down(d, off);
        c = d / fmaxf(norms[l] * norms[r], 1e-8f);
    }
    if (threadIdx.x == 0) cos_g[b * 64 + j] = c;
}

// ---- the sequential merge loop: single block, 1024 threads (16 waves) ----
// Wave 0 does all the scalar control (argmax, dedup, id assignment, targets,
// compaction) with ballots; then all 16 waves do the fused compose+dot phase
// with all global loads issued up-front. Only 2 barriers per iteration.

__global__ __launch_bounds__(1024) void iterate_kernel(
    float* __restrict__ feats, const float* __restrict__ norms_g,
    const int* __restrict__ index_g, const float* __restrict__ cos_g,
    int* __restrict__ targets, int* __restrict__ meta,
    const float* __restrict__ comp_l, const float* __restrict__ comp_r,
    const float* __restrict__ cb, const float* __restrict__ eos,
    const float* __restrict__ sos) {
    __shared__ int s_hk[HSIZE];
    __shared__ int s_hv[HSIZE];
    __shared__ float s_norm[NMAX];
    __shared__ int s_idx[64][65];    // padded: conflict-free column access
    __shared__ float s_cos[64][65];
    __shared__ int s_ms[64], s_l[64], s_r[64], s_ls[64], s_rs[64], s_nid[64], s_key[64];
    __shared__ int s_act[64], s_first[64];
    __shared__ int s_nact, s_newc;
    __shared__ float s_sl[16], s_sr[16], s_cb[16];

    int tid = threadIdx.x;
    int lane = tid & 63, wave = tid >> 6;
    int N0 = meta[1];
    for (int i = tid; i < HSIZE; i += 1024) s_hk[i] = -1;
    for (int i = tid; i < 4096; i += 1024) {
        s_idx[i >> 6][i & 63] = index_g[i];
        s_cos[i >> 6][i & 63] = cos_g[i];
    }
    for (int i = tid; i < N0; i += 1024) s_norm[i] = norms_g[i];
    if (tid < 16) {
        s_sl[tid] = 1.f / (1.f + __expf(-comp_l[tid]));
        s_sr[tid] = 1.f / (1.f + __expf(-comp_r[tid]));
        s_cb[tid] = cb[tid];
    }
    int Ncur = N0;
    int Tcur = 0;
    __syncthreads();
    // per-lane compose coefficients for float4 at element offset 4*lane
    int c0 = 4 * (lane & 3);
    float4 sl4 = make_float4(s_sl[c0], s_sl[c0 + 1], s_sl[c0 + 2], s_sl[c0 + 3]);
    float4 sr4 = make_float4(s_sr[c0], s_sr[c0 + 1], s_sr[c0 + 2], s_sr[c0 + 3]);
    float4 cb4 = make_float4(s_cb[c0], s_cb[c0 + 1], s_cb[c0 + 2], s_cb[c0 + 3]);

    for (int W = 64; W >= 2; --W) {
        int base = Ncur;
        // ---- wave-0 mega-phase: argmax + dedup + ids + targets + compaction ----
        if (wave == 0) {
            int b = lane;
            int act = (s_idx[b][1] != -1) ? 1 : 0;
            int ms = 0, l = 0, r = 0, ls = -1, rs = -2, key = 0, nid = 0, newf = 0;
            if (act) {
                float best = -INFINITY;
                for (int j = 0; j < W - 1; ++j) {
                    float c = s_cos[b][j];
                    if (c > best) { best = c; ms = j; }
                }
                l = s_idx[b][ms]; r = s_idx[b][ms + 1];
                ls = (ms == 0) ? -1 : s_idx[b][ms - 1];
                rs = (ms + 2 == W) ? -2 : s_idx[b][ms + 2];
                key = (l << HBITS) | r;     // lexicographic (l, r)
                unsigned h = hash0(key);
                int found = 0;
                while (true) {
                    int k2 = s_hk[h];
                    if (k2 == -1) break;
                    if (k2 == key) { found = 1; nid = s_hv[h]; break; }
                    h = (h + 1) & HMASK;
                }
                newf = found ? 0 : 1;
            }
            s_key[b] = key;
            s_act[b] = act;
            __builtin_amdgcn_wave_barrier();
            unsigned long long actmask = __ballot(act != 0);
            unsigned long long below = (b == 63) ? ~0ull >> 1 : ((1ull << b) - 1);
            int ar = __popcll(actmask & below);
            int nact = __popcll(actmask);
            unsigned long long newmask = __ballot(newf != 0);
            int f = 0;
            if (newf) {
                f = 1;
                unsigned long long mm = newmask & below;
                while (mm) {
                    int j = __builtin_ctzll(mm);
                    mm &= mm - 1;
                    if (s_key[j] == key) { f = 0; break; }
                }
            }
            unsigned long long firstmask = __ballot(f != 0);
            if (newf) {
                int rk = 0;
                unsigned long long mm = firstmask;
                while (mm) {
                    int j = __builtin_ctzll(mm);
                    mm &= mm - 1;
                    if (s_key[j] < key) rk++;
                }
                nid = base + rk;
            }
            s_first[b] = f;
            s_nid[b] = nid;
            s_ms[b] = ms; s_l[b] = l; s_r[b] = r; s_ls[b] = ls; s_rs[b] = rs;
            if (f) {
                unsigned h = hash0(key);
                while (true) {
                    int prev = atomicCAS(&s_hk[h], -1, key);
                    if (prev == -1) { s_hv[h] = nid; break; }
                    h = (h + 1) & HMASK;
                }
            }
            if (act) {
                int o1 = Tcur + ar;
                targets[o1 * 3 + 0] = l;
                targets[o1 * 3 + 1] = ls;
                targets[o1 * 3 + 2] = r;
                int o2 = Tcur + nact + ar;
                targets[o2 * 3 + 0] = r;
                targets[o2 * 3 + 1] = l;
                targets[o2 * 3 + 2] = rs;
            }
            // compaction: place nid, shift tail of index and cos
            if (act) {
                s_idx[b][ms] = nid;
                for (int j = ms + 1; j < W - 1; ++j) s_idx[b][j] = s_idx[b][j + 1];
                for (int j = ms + 1; j <= W - 3; ++j) s_cos[b][j] = s_cos[b][j + 1];
            }
            if (b == 0) { s_nact = nact; s_newc = __popcll(firstmask); }
        }
        __syncthreads();   // barrier 1
        int nact_r = s_nact, newc_r = s_newc;   // capture before wave0 can rewrite
        // ---- fused compose + neighbor-dot phase: one wave per row, 4 rounds,
        //      all 16 global row-loads issued before any store ----
        {
            int p_act[4], p_ms[4], p_first[4], p_nid[4], p_hasA[4], p_doC[4], p_Cval[4];
            float4 l4[4], r4[4], a4[4], c4[4];
            float nA[4], nC[4];
#pragma unroll
            for (int rr = 0; rr < 4; ++rr) {
                int b2 = wave + rr * 16;
                int act = s_act[b2];
                int ms = s_ms[b2];
                int hasA = act && (ms > 0);
                int doC = act && (ms + 2 < W);
                int l = act ? s_l[b2] : 0;
                int r = act ? s_r[b2] : 0;
                int A = hasA ? s_ls[b2] : 0;
                int Craw = doC ? s_rs[b2] : -1;
                int Cval = (doC && Craw != -1) ? 1 : 0;
                int C = Cval ? Craw : 0;
                p_act[rr] = act; p_ms[rr] = ms;
                p_first[rr] = s_first[b2]; p_nid[rr] = s_nid[b2];
                p_hasA[rr] = hasA; p_doC[rr] = doC; p_Cval[rr] = Cval;
                l4[rr] = ((const float4*)(feats + (size_t)l * 256))[lane];
                r4[rr] = ((const float4*)(feats + (size_t)r * 256))[lane];
                a4[rr] = ((const float4*)(feats + (size_t)A * 256))[lane];
                c4[rr] = ((const float4*)(feats + (size_t)C * 256))[lane];
                nA[rr] = s_norm[A];
                nC[rr] = s_norm[C];
            }
#pragma unroll
            for (int rr = 0; rr < 4; ++rr) {
                if (!p_act[rr]) continue;
                int b2 = wave + rr * 16;
                float4 a = l4[rr], bb = r4[rr];
                float4 v;
                v.x = a.x * sl4.x + bb.x * sr4.x + cb4.x;
                v.y = a.y * sl4.y + bb.y * sr4.y + cb4.y;
                v.z = a.z * sl4.z + bb.z * sr4.z + cb4.z;
                v.w = a.w * sl4.w + bb.w * sr4.w + cb4.w;
                float4 av = a4[rr], cv = c4[rr];
                float sv = v.x * v.x + v.y * v.y + v.z * v.z + v.w * v.w;
                float da = av.x * v.x + av.y * v.y + av.z * v.z + av.w * v.w;
                float dc = cv.x * v.x + cv.y * v.y + cv.z * v.z + cv.w * v.w;
#pragma unroll
                for (int off = 32; off >= 1; off >>= 1) {
                    sv += __shfl_down(sv, off);
                    da += __shfl_down(da, off);
                    dc += __shfl_down(dc, off);
                }
                if (p_first[rr])
                    ((float4*)(feats + (size_t)p_nid[rr] * 256))[lane] = v;
                if (lane == 0) {
                    float nn = sqrtf(sv);
                    if (p_first[rr]) s_norm[p_nid[rr]] = nn;
                    int ms = p_ms[rr];
                    if (p_hasA[rr]) s_cos[b2][ms - 1] = da / fmaxf(nA[rr] * nn, 1e-8f);
                    if (p_doC[rr])
                        s_cos[b2][ms] = p_Cval[rr] ? dc / fmaxf(nn * nC[rr], 1e-8f)
                                                   : -INFINITY;
                }
            }
        }
        __syncthreads();   // barrier 2
        Ncur = base + newc_r;
        Tcur += 2 * nact_r;
    }
    // append eos, sos
    if (tid < 256) {
        feats[(size_t)Ncur * 256 + tid] = eos[tid];
        feats[(size_t)(Ncur + 1) * 256 + tid] = sos[tid];
    }
    if (tid == 0) { meta[2] = Ncur; meta[3] = Tcur; }
}

// ---- loss: 16 triples per block, online logsumexp over all nodes ----

__global__ __launch_bounds__(256) void loss_kernel(
    const float* __restrict__ feats, const int* __restrict__ targets,
    const int* __restrict__ meta, const float* __restrict__ comp_l,
    const float* __restrict__ comp_r, const float* __restrict__ cb,
    float* __restrict__ acc) {
    __shared__ float s_out[16][260];
    __shared__ float s_tile[32][260];
    __shared__ float s_sl[16], s_sr[16], s_cb[16];
    int T = meta[3];
    int Ntot = meta[2] + 2;
    int t0base = blockIdx.x * 16;
    if (t0base >= T) return;
    int tid = threadIdx.x;
    if (tid < 16) {
        s_sl[tid] = 1.f / (1.f + __expf(-comp_l[tid]));
        s_sr[tid] = 1.f / (1.f + __expf(-comp_r[tid]));
        s_cb[tid] = cb[tid];
    }
    __syncthreads();
    for (int idx = tid; idx < 16 * 256; idx += 256) {
        int tt = idx >> 8, e = idx & 255;
        int ti = t0base + tt;
        float v = 0.f;
        if (ti < T) {
            int i1 = targets[ti * 3 + 1], i2 = targets[ti * 3 + 2];
            if (i1 < 0) i1 += Ntot;
            if (i2 < 0) i2 += Ntot;
            v = feats[(size_t)i1 * 256 + e] * s_sl[e & 15] +
                feats[(size_t)i2 * 256 + e] * s_sr[e & 15] + s_cb[e & 15];
        }
        s_out[tt][e] = v;
    }
    __syncthreads();
    int g = tid >> 4, k = tid & 15;
    int ti = t0base + g;
    bool act = ti < T;
    float m = -INFINITY, ssum = 0.f;
    for (int nb = 0; nb < Ntot; nb += 32) {
        int cnt = min(32, Ntot - nb);
        for (int idx = tid; idx < cnt * 64; idx += 256) {
            int row = idx >> 6, c4 = idx & 63;
            ((float4*)(&s_tile[row][0]))[c4] =
                ((const float4*)(feats + (size_t)(nb + row) * 256))[c4];
        }
        __syncthreads();
        if (act) {
#pragma unroll
            for (int rr = 0; rr < 2; ++rr) {
                int n = k + rr * 16;
                if (n < cnt) {
                    const float4* fo = (const float4*)(&s_out[g][0]);
                    const float4* fn = (const float4*)(&s_tile[n][0]);
                    float d = 0.f;
#pragma unroll
                    for (int e4 = 0; e4 < 64; ++e4) {
                        float4 a = fo[e4], b = fn[e4];
                        d += a.x * b.x + a.y * b.y + a.z * b.z + a.w * b.w;
                    }
                    if (d > m) { ssum = ssum * __expf(m - d) + 1.f; m = d; }
                    else ssum += __expf(d - m);
                }
            }
        }
        __syncthreads();
    }
    for (int off = 1; off < 16; off <<= 1) {
        float m2 = __shfl_xor(m, off);
        float s2 = __shfl_xor(ssum, off);
        float mn = fmaxf(m, m2);
        ssum = ssum * __expf(m - mn) + s2 * __expf(m2 - mn);
        m = mn;
    }
    float tl = 0.f;
    if (act) {
        int t0 = targets[ti * 3 + 0];
        const float* ft = feats + (size_t)t0 * 256;
        const float* fo = &s_out[g][0];
#pragma unroll
        for (int e = 0; e < 16; ++e) tl += fo[k * 16 + e] * ft[k * 16 + e];
    }
    for (int off = 1; off < 16; off <<= 1) tl += __shfl_xor(tl, off);
    if (act && k == 0) atomicAdd(acc, (m + __logf(ssum)) - tl);
}

__global__ void finalize_kernel(const float* __restrict__ acc, const int* __restrict__ meta,
                                float* __restrict__ out) {
    out[0] = acc[0] / (float)meta[3];
}

extern "C" void kernel_launch(void* const* d_in, const int* in_sizes, int n_in,
                              void* d_out, int out_size, void* d_ws, size_t ws_size,
                              hipStream_t stream) {
    const int* x = (const int*)d_in[0];
    const float* emb = (const float*)d_in[1];
    const float* comp_l = (const float*)d_in[2];
    const float* comp_r = (const float*)d_in[3];
    const float* cb = (const float*)d_in[4];
    const float* sos = (const float*)d_in[5];
    const float* eos = (const float*)d_in[6];
    float* out = (float*)d_out;

    float* feats = (float*)d_ws;                 // 8192*256
    float* norms = feats + (size_t)NMAX * 256;   // 8192
    int* index_g = (int*)(norms + NMAX);         // 4096
    float* cos_g = (float*)(index_g + 4096);     // 4096
    int* presence = (int*)(cos_g + 4096);        // 30720
    int* rankbuf = presence + PRES;              // 30720
    int* tokens = rankbuf + PRES;                // 4096
    int* targets = tokens + 4096;                // 8192*3
    int* meta = targets + NMAX * 3;              // 64
    float* acc = (float*)(meta + 64);            // 1

    hipMemsetAsync(presence, 0, PRES * sizeof(int), stream);
    hipMemsetAsync(acc, 0, sizeof(float), stream);

    mark_kernel<<<16, 256, 0, stream>>>(x, presence);
    scan_kernel<<<1, 1024, 0, stream>>>(presence, rankbuf, tokens, meta);
    map_index_kernel<<<16, 256, 0, stream>>>(x, rankbuf, meta, index_g);
    copy_feats_kernel<<<4096, 64, 0, stream>>>(emb, tokens, meta, feats, norms);
    init_cos_kernel<<<64 * 63, 64, 0, stream>>>(feats, norms, index_g, cos_g);
    iterate_kernel<<<1, 1024, 0, stream>>>(feats, norms, index_g, cos_g,
                                           targets, meta, comp_l, comp_r, cb, eos, sos);
    loss_kernel<<<504, 256, 0, stream>>>(feats, targets, meta, comp_l, comp_r, cb, acc);
    finalize_kernel<<<1, 1, 0, stream>>>(acc, meta, out);
}

// Round 4
// 1512.289 us; speedup vs baseline: 2.2260x; 1.2654x over previous
//
#include <hip/hip_runtime.h>
#include <math.h>

// Banyan compose: phase-1 schedule construction + phase-2 CE replay, all on device.
// Sizes: B=64, L=64, E=256, CH=16. V=30000. Node ids < 8192.

#define NMAX 8192
#define PRES 30720
#define HBITS 13
#define HSIZE 8192
#define HMASK 8191

typedef float f32x4 __attribute__((ext_vector_type(4)));
typedef short short8 __attribute__((ext_vector_type(8)));

__device__ __forceinline__ unsigned hash0(int key) {
    return (((unsigned)key) * 2654435761u) >> (32 - HBITS);
}

// float -> bf16 bits (RTNE), bf16 bits -> float
__device__ __forceinline__ unsigned short f2bf(float f) {
    unsigned u = __float_as_uint(f);
    unsigned r = ((u >> 16) & 1u) + 0x7FFFu;
    return (unsigned short)((u + r) >> 16);
}
__device__ __forceinline__ float bf2f(unsigned short b) {
    return __uint_as_float(((unsigned)b) << 16);
}

// ---- setup kernels ----

__global__ void mark_kernel(const int* __restrict__ x, int* __restrict__ presence) {
    int i = blockIdx.x * blockDim.x + threadIdx.x;
    if (i < 4096) presence[x[i]] = 1;
}

__global__ __launch_bounds__(1024) void scan_kernel(const int* __restrict__ presence,
                                                    int* __restrict__ rank,
                                                    int* __restrict__ tokens,
                                                    int* __restrict__ meta) {
    __shared__ int part[1024];
    int tid = threadIdx.x;
    int base = tid * 30;
    int loc[30];
    int s = 0;
#pragma unroll
    for (int i = 0; i < 30; ++i) { loc[i] = s; s += presence[base + i]; }
    part[tid] = s;
    __syncthreads();
    for (int off = 1; off < 1024; off <<= 1) {
        int v = (tid >= off) ? part[tid - off] : 0;
        __syncthreads();
        part[tid] += v;
        __syncthreads();
    }
    int excl = (tid == 0) ? 0 : part[tid - 1];
#pragma unroll
    for (int i = 0; i < 30; ++i) {
        int r = excl + loc[i];
        rank[base + i] = r;
        if (presence[base + i]) tokens[r] = base + i;
    }
    if (tid == 1023) { meta[0] = part[1023]; meta[1] = part[1023] - 1; }
}

__global__ void map_index_kernel(const int* __restrict__ x, const int* __restrict__ rank,
                                 const int* __restrict__ meta, int* __restrict__ index_g) {
    int i = blockIdx.x * blockDim.x + threadIdx.x;
    if (i < 4096) {
        int r = rank[x[i]];
        index_g[i] = (r == meta[0] - 1) ? -1 : r;
    }
}

__global__ void copy_feats_kernel(const float* __restrict__ emb, const int* __restrict__ tokens,
                                  const int* __restrict__ meta, float* __restrict__ feats,
                                  float* __restrict__ norms) {
    int n = blockIdx.x;
    if (n >= meta[1]) return;
    int t = tokens[n];
    int k = threadIdx.x; // 64
    const float4* src = (const float4*)(emb + (size_t)t * 256);
    float4* dst = (float4*)(feats + (size_t)n * 256);
    float4 v = src[k];
    dst[k] = v;
    float ss = v.x * v.x + v.y * v.y + v.z * v.z + v.w * v.w;
#pragma unroll
    for (int off = 32; off >= 1; off >>= 1) ss += __shfl_down(ss, off);
    if (k == 0) norms[n] = sqrtf(ss);
}

__global__ void init_cos_kernel(const float* __restrict__ feats, const float* __restrict__ norms,
                                const int* __restrict__ index_g, float* __restrict__ cos_g) {
    int bid = blockIdx.x;
    int b = bid / 63, j = bid % 63;
    int l = index_g[b * 64 + j], r = index_g[b * 64 + j + 1];
    float c = -INFINITY;
    if (r != -1) {
        int k = threadIdx.x;
        const float4* fa = (const float4*)(feats + (size_t)l * 256);
        const float4* fb = (const float4*)(feats + (size_t)r * 256);
        float4 a = fa[k], bb = fb[k];
        float d = a.x * bb.x + a.y * bb.y + a.z * bb.z + a.w * bb.w;
#pragma unroll
        for (int off = 32; off >= 1; off >>= 1) d += __shfl_down(d, off);
        c = d / fmaxf(norms[l] * norms[r], 1e-8f);
    }
    if (threadIdx.x == 0) cos_g[b * 64 + j] = c;
}

// ---- sequential merge loop: 1 block, 1024 threads. Positional alive-mask per
// row (wave-0 lane registers): no compaction/shift ever. Dedup/rank via shfl
// all-to-all (no LDS key scans). 2 barriers per iteration. ----

__global__ __launch_bounds__(1024) void iterate_kernel(
    float* __restrict__ feats, const float* __restrict__ norms_g,
    const int* __restrict__ index_g, const float* __restrict__ cos_g,
    int* __restrict__ targets, int* __restrict__ meta,
    const float* __restrict__ comp_l, const float* __restrict__ comp_r,
    const float* __restrict__ cb, const float* __restrict__ eos,
    const float* __restrict__ sos) {
    __shared__ int s_hk[HSIZE];
    __shared__ int s_hv[HSIZE];
    __shared__ float s_norm[NMAX];
    __shared__ int s_idx[64][65];     // position-indexed, never shifted
    __shared__ float s_cos[64][65];   // cos(pos p, succ(p)); -inf if dead/invalid
    __shared__ int s_p[64], s_pp[64], s_l[64], s_r[64], s_ls[64], s_rs[64];
    __shared__ int s_nid[64], s_act[64], s_first[64], s_cf[64];
    __shared__ int s_nact, s_newc;
    __shared__ float s_sl[16], s_sr[16], s_cb[16];

    int tid = threadIdx.x;
    int lane = tid & 63, wave = tid >> 6;
    int N0 = meta[1];
    for (int i = tid; i < HSIZE; i += 1024) s_hk[i] = -1;
    for (int i = tid; i < 4096; i += 1024) {
        int b = i >> 6, j = i & 63;
        s_idx[b][j] = index_g[i];
        s_cos[b][j] = (j == 63) ? -INFINITY : cos_g[i];
    }
    for (int i = tid; i < N0; i += 1024) s_norm[i] = norms_g[i];
    if (tid < 16) {
        s_sl[tid] = 1.f / (1.f + __expf(-comp_l[tid]));
        s_sr[tid] = 1.f / (1.f + __expf(-comp_r[tid]));
        s_cb[tid] = cb[tid];
    }
    int Ncur = N0;
    int Tcur = 0;
    __syncthreads();
    int c0 = 4 * (lane & 3);
    float4 sl4 = make_float4(s_sl[c0], s_sl[c0 + 1], s_sl[c0 + 2], s_sl[c0 + 3]);
    float4 sr4 = make_float4(s_sr[c0], s_sr[c0 + 1], s_sr[c0 + 2], s_sr[c0 + 3]);
    float4 cb4 = make_float4(s_cb[c0], s_cb[c0 + 1], s_cb[c0 + 2], s_cb[c0 + 3]);

    // wave-0 persistent per-row state
    unsigned long long mask = ~0ull;  // alive positions
    int nreal = 0;
    if (wave == 0) {
        int b = lane;
        for (int j = 0; j < 64; ++j) nreal += (s_idx[b][j] != -1) ? 1 : 0;
    }

    for (int it = 0; it < 63; ++it) {
        int base = Ncur;
        if (wave == 0) {
            int b = lane;
            int act = (nreal >= 2) ? 1 : 0;
            int p = 0, q = 0, pp = -1, l = 0, r = 0, lsn = -1, rsn = -2;
            int key = 0, nid = 0, newf = 0, cf = 0;
            if (act) {
                float best = s_cos[b][0];
                for (int j = 1; j < 63; ++j) {
                    float c = s_cos[b][j];
                    if (c > best) { best = c; p = j; }
                }
                unsigned long long after = (mask >> 1) >> p;   // bits strictly above p
                q = p + 1 + __builtin_ctzll(after);
                l = s_idx[b][p]; r = s_idx[b][q];
                unsigned long long bel = mask & ((1ull << p) - 1ull);
                if (bel) { pp = 63 - __builtin_clzll(bel); lsn = s_idx[b][pp]; }
                unsigned long long aft2 = (q < 63) ? (mask >> (q + 1)) : 0ull;
                int ssp = -1;
                if (aft2) { ssp = q + 1 + __builtin_ctzll(aft2); rsn = s_idx[b][ssp]; }
                key = (l << HBITS) | r;
                unsigned h = hash0(key);
                int found = 0;
                while (true) {
                    int k2 = s_hk[h];
                    if (k2 == -1) break;
                    if (k2 == key) { found = 1; nid = s_hv[h]; break; }
                    h = (h + 1) & HMASK;
                }
                newf = found ? 0 : 1;
                cf = (ssp >= 0 && rsn != -1) ? 1 : 0;
            }
            unsigned long long actmask = __ballot(act != 0);
            unsigned long long newmask = __ballot(newf != 0);
            unsigned long long below = (1ull << b) - 1ull;
            int ar = __popcll(actmask & below);
            int nact = __popcll(actmask);
            // first-occurrence among duplicates (uniform shfl all-to-all)
            int f = newf;
            if (newmask) {
                for (int j = 0; j < 64; ++j) {
                    int kj = __shfl(key, j);
                    if (f && ((newmask >> j) & 1ull) && j < b && kj == key) f = 0;
                }
            }
            unsigned long long firstmask = __ballot(f != 0);
            // rank among sorted unique new keys
            int rk = 0;
            if (firstmask) {
                for (int j = 0; j < 64; ++j) {
                    int kj = __shfl(key, j);
                    if (((firstmask >> j) & 1ull) && kj < key) rk++;
                }
            }
            if (newf) nid = base + rk;
            if (f) {
                unsigned h = hash0(key);
                while (true) {
                    int prev = atomicCAS(&s_hk[h], -1, key);
                    if (prev == -1) { s_hv[h] = nid; break; }
                    h = (h + 1) & HMASK;
                }
            }
            if (act) {
                int o1 = Tcur + ar;
                targets[o1 * 3 + 0] = l;
                targets[o1 * 3 + 1] = lsn;
                targets[o1 * 3 + 2] = r;
                int o2 = Tcur + nact + ar;
                targets[o2 * 3 + 0] = r;
                targets[o2 * 3 + 1] = l;
                targets[o2 * 3 + 2] = rsn;
                // state update: remove q, place nid at p, preset cos slots
                mask &= ~(1ull << q);
                nreal -= 1;
                s_idx[b][p] = nid;
                s_cos[b][p] = -INFINITY;
                s_cos[b][q] = -INFINITY;
            }
            s_act[b] = act;
            s_first[b] = (act && f) ? 1 : 0;
            s_nid[b] = nid;
            s_p[b] = p; s_pp[b] = pp;
            s_l[b] = l; s_r[b] = r; s_ls[b] = lsn; s_rs[b] = rsn;
            s_cf[b] = cf;
            if (b == 0) { s_nact = nact; s_newc = __popcll(firstmask); }
        }
        __syncthreads();   // barrier 1
        int nact_r = s_nact, newc_r = s_newc;
        // fused compose + neighbor-dot: one wave per row, 4 rounds, loads first
        {
            int p_act[4], p_first[4], p_nid[4], p_hasA[4], p_cf[4], p_p[4], p_pp[4];
            float4 l4[4], r4[4], a4[4], c4[4];
            float nA[4], nC[4];
#pragma unroll
            for (int rr = 0; rr < 4; ++rr) {
                int b2 = wave + rr * 16;
                int act = s_act[b2];
                int pp = s_pp[b2];
                int hasA = act && (pp >= 0);
                int cf = act ? s_cf[b2] : 0;
                int l = act ? s_l[b2] : 0;
                int r = act ? s_r[b2] : 0;
                int A = hasA ? s_ls[b2] : 0;
                int C = cf ? s_rs[b2] : 0;
                p_act[rr] = act; p_first[rr] = s_first[b2]; p_nid[rr] = s_nid[b2];
                p_hasA[rr] = hasA; p_cf[rr] = cf; p_p[rr] = s_p[b2]; p_pp[rr] = pp;
                l4[rr] = ((const float4*)(feats + (size_t)l * 256))[lane];
                r4[rr] = ((const float4*)(feats + (size_t)r * 256))[lane];
                a4[rr] = ((const float4*)(feats + (size_t)A * 256))[lane];
                c4[rr] = ((const float4*)(feats + (size_t)C * 256))[lane];
                nA[rr] = s_norm[A];
                nC[rr] = s_norm[C];
            }
#pragma unroll
            for (int rr = 0; rr < 4; ++rr) {
                if (!p_act[rr]) continue;
                int b2 = wave + rr * 16;
                float4 a = l4[rr], bb = r4[rr];
                float4 v;
                v.x = a.x * sl4.x + bb.x * sr4.x + cb4.x;
                v.y = a.y * sl4.y + bb.y * sr4.y + cb4.y;
                v.z = a.z * sl4.z + bb.z * sr4.z + cb4.z;
                v.w = a.w * sl4.w + bb.w * sr4.w + cb4.w;
                float4 av = a4[rr], cv = c4[rr];
                float sv = v.x * v.x + v.y * v.y + v.z * v.z + v.w * v.w;
                float da = av.x * v.x + av.y * v.y + av.z * v.z + av.w * v.w;
                float dc = cv.x * v.x + cv.y * v.y + cv.z * v.z + cv.w * v.w;
#pragma unroll
                for (int off = 32; off >= 1; off >>= 1) {
                    sv += __shfl_down(sv, off);
                    da += __shfl_down(da, off);
                    dc += __shfl_down(dc, off);
                }
                if (p_first[rr])
                    ((float4*)(feats + (size_t)p_nid[rr] * 256))[lane] = v;
                if (lane == 0) {
                    float nn = sqrtf(sv);
                    if (p_first[rr]) s_norm[p_nid[rr]] = nn;
                    if (p_hasA[rr]) s_cos[b2][p_pp[rr]] = da / fmaxf(nA[rr] * nn, 1e-8f);
                    if (p_cf[rr])   s_cos[b2][p_p[rr]]  = dc / fmaxf(nn * nC[rr], 1e-8f);
                }
            }
        }
        __syncthreads();   // barrier 2
        Ncur = base + newc_r;
        Tcur += 2 * nact_r;
    }
    if (tid < 256) {
        feats[(size_t)Ncur * 256 + tid] = eos[tid];
        feats[(size_t)(Ncur + 1) * 256 + tid] = sos[tid];
    }
    if (tid == 0) { meta[2] = Ncur; meta[3] = Tcur; }
}

// ---- bf16 hi/lo conversion of all node features (8192 rows) ----
__global__ __launch_bounds__(256) void convert_feats_kernel(
    const float* __restrict__ feats, unsigned short* __restrict__ fh,
    unsigned short* __restrict__ fl) {
    int row = blockIdx.x * 4 + (threadIdx.x >> 6);
    int lane = threadIdx.x & 63;
    float4 v = ((const float4*)(feats + (size_t)row * 256))[lane];
    ushort4 h, l;
    h.x = f2bf(v.x); l.x = f2bf(v.x - bf2f(h.x));
    h.y = f2bf(v.y); l.y = f2bf(v.y - bf2f(h.y));
    h.z = f2bf(v.z); l.z = f2bf(v.z - bf2f(h.z));
    h.w = f2bf(v.w); l.w = f2bf(v.w - bf2f(h.w));
    ((ushort4*)(fh + (size_t)row * 256))[lane] = h;
    ((ushort4*)(fl + (size_t)row * 256))[lane] = l;
}

// ---- out rows (bf16 hi/lo) + exact fp32 target logit per triple ----
__global__ __launch_bounds__(256) void prep_outs_kernel(
    const float* __restrict__ feats, const int* __restrict__ targets,
    const int* __restrict__ meta, const float* __restrict__ comp_l,
    const float* __restrict__ comp_r, const float* __restrict__ cb,
    unsigned short* __restrict__ oh, unsigned short* __restrict__ ol,
    float* __restrict__ tdot) {
    int T = meta[3];
    int Ntot = meta[2] + 2;
    int t = blockIdx.x * 4 + (threadIdx.x >> 6);
    if (t >= T) return;
    int lane = threadIdx.x & 63;
    int c0 = 4 * (lane & 3);
    float4 sl4 = make_float4(1.f / (1.f + __expf(-comp_l[c0])),
                             1.f / (1.f + __expf(-comp_l[c0 + 1])),
                             1.f / (1.f + __expf(-comp_l[c0 + 2])),
                             1.f / (1.f + __expf(-comp_l[c0 + 3])));
    float4 sr4 = make_float4(1.f / (1.f + __expf(-comp_r[c0])),
                             1.f / (1.f + __expf(-comp_r[c0 + 1])),
                             1.f / (1.f + __expf(-comp_r[c0 + 2])),
                             1.f / (1.f + __expf(-comp_r[c0 + 3])));
    float4 cb4 = make_float4(cb[c0], cb[c0 + 1], cb[c0 + 2], cb[c0 + 3]);
    int t0 = targets[t * 3 + 0];
    int i1 = targets[t * 3 + 1], i2 = targets[t * 3 + 2];
    if (i1 < 0) i1 += Ntot;
    if (i2 < 0) i2 += Ntot;
    float4 a = ((const float4*)(feats + (size_t)i1 * 256))[lane];
    float4 b = ((const float4*)(feats + (size_t)i2 * 256))[lane];
    float4 ft = ((const float4*)(feats + (size_t)t0 * 256))[lane];
    float4 v;
    v.x = a.x * sl4.x + b.x * sr4.x + cb4.x;
    v.y = a.y * sl4.y + b.y * sr4.y + cb4.y;
    v.z = a.z * sl4.z + b.z * sr4.z + cb4.z;
    v.w = a.w * sl4.w + b.w * sr4.w + cb4.w;
    float d = v.x * ft.x + v.y * ft.y + v.z * ft.z + v.w * ft.w;
#pragma unroll
    for (int off = 32; off >= 1; off >>= 1) d += __shfl_down(d, off);
    if (lane == 0) tdot[t] = d;
    ushort4 h, l;
    h.x = f2bf(v.x); l.x = f2bf(v.x - bf2f(h.x));
    h.y = f2bf(v.y); l.y = f2bf(v.y - bf2f(h.y));
    h.z = f2bf(v.z); l.z = f2bf(v.z - bf2f(h.z));
    h.w = f2bf(v.w); l.w = f2bf(v.w - bf2f(h.w));
    ((ushort4*)(oh + (size_t)t * 256))[lane] = h;
    ((ushort4*)(ol + (size_t)t * 256))[lane] = l;
}

// ---- loss: split-bf16 MFMA GEMM + per-lane online logsumexp ----
// 126 blocks x 512 threads (8 waves). Block = 64 triples x all nodes.
// Waves: 4 M-quarters x 2 N-halves of a 64x32 tile per nb step.
__global__ __launch_bounds__(512) void loss_mfma_kernel(
    const unsigned short* __restrict__ fh, const unsigned short* __restrict__ fl,
    const unsigned short* __restrict__ oh, const unsigned short* __restrict__ ol,
    const float* __restrict__ tdot, const int* __restrict__ meta,
    float* __restrict__ acc_out) {
    __shared__ float s_m[64][2], s_s[64][2];
    int T = meta[3];
    int Ntot = meta[2] + 2;
    int row0 = blockIdx.x * 64;
    if (row0 >= T) return;
    int tid = threadIdx.x, lane = tid & 63, w = tid >> 6;
    int mq = w >> 1, nq = w & 1;
    int mrow = row0 + mq * 16 + (lane & 15);
    int kq = lane >> 4;   // 0..3
    const short8* pah = (const short8*)(oh + (size_t)mrow * 256);
    const short8* pal = (const short8*)(ol + (size_t)mrow * 256);
    short8 Ah[8], Al[8];
#pragma unroll
    for (int ks = 0; ks < 8; ++ks) { Ah[ks] = pah[ks * 4 + kq]; Al[ks] = pal[ks * 4 + kq]; }
    float m0 = -1e30f, m1 = -1e30f, m2 = -1e30f, m3 = -1e30f;
    float s0 = 0.f, s1 = 0.f, s2 = 0.f, s3 = 0.f;
    for (int nb = 0; nb < Ntot; nb += 32) {
        int col = nb + nq * 16 + (lane & 15);
        const short8* pbh = (const short8*)(fh + (size_t)col * 256);
        const short8* pbl = (const short8*)(fl + (size_t)col * 256);
        f32x4 a0 = {0.f, 0.f, 0.f, 0.f}, a1 = a0, a2 = a0;
#pragma unroll
        for (int ks = 0; ks < 8; ++ks) {
            short8 Bh = pbh[ks * 4 + kq];
            short8 Bl = pbl[ks * 4 + kq];
            a0 = __builtin_amdgcn_mfma_f32_16x16x32_bf16(Ah[ks], Bh, a0, 0, 0, 0);
            a1 = __builtin_amdgcn_mfma_f32_16x16x32_bf16(Al[ks], Bh, a1, 0, 0, 0);
            a2 = __builtin_amdgcn_mfma_f32_16x16x32_bf16(Ah[ks], Bl, a2, 0, 0, 0);
        }
        bool cv = col < Ntot;
        float v0 = cv ? (a0[0] + a1[0] + a2[0]) : -INFINITY;
        float v1 = cv ? (a0[1] + a1[1] + a2[1]) : -INFINITY;
        float v2 = cv ? (a0[2] + a1[2] + a2[2]) : -INFINITY;
        float v3 = cv ? (a0[3] + a1[3] + a2[3]) : -INFINITY;
        if (v0 > m0) { s0 = s0 * __expf(m0 - v0) + 1.f; m0 = v0; } else s0 += __expf(v0 - m0);
        if (v1 > m1) { s1 = s1 * __expf(m1 - v1) + 1.f; m1 = v1; } else s1 += __expf(v1 - m1);
        if (v2 > m2) { s2 = s2 * __expf(m2 - v2) + 1.f; m2 = v2; } else s2 += __expf(v2 - m2);
        if (v3 > m3) { s3 = s3 * __expf(m3 - v3) + 1.f; m3 = v3; } else s3 += __expf(v3 - m3);
    }
    // combine the 16 cols of this lane-group (rows kq*4+i)
#pragma unroll
    for (int off = 1; off < 16; off <<= 1) {
        float mo, so, mn;
        mo = __shfl_xor(m0, off); so = __shfl_xor(s0, off);
        mn = fmaxf(m0, mo); s0 = s0 * __expf(m0 - mn) + so * __expf(mo - mn); m0 = mn;
        mo = __shfl_xor(m1, off); so = __shfl_xor(s1, off);
        mn = fmaxf(m1, mo); s1 = s1 * __expf(m1 - mn) + so * __expf(mo - mn); m1 = mn;
        mo = __shfl_xor(m2, off); so = __shfl_xor(s2, off);
        mn = fmaxf(m2, mo); s2 = s2 * __expf(m2 - mn) + so * __expf(mo - mn); m2 = mn;
        mo = __shfl_xor(m3, off); so = __shfl_xor(s3, off);
        mn = fmaxf(m3, mo); s3 = s3 * __expf(m3 - mn) + so * __expf(mo - mn); m3 = mn;
    }
    if ((lane & 15) == 0) {
        int rbase = mq * 16 + kq * 4;
        s_m[rbase + 0][nq] = m0; s_s[rbase + 0][nq] = s0;
        s_m[rbase + 1][nq] = m1; s_s[rbase + 1][nq] = s1;
        s_m[rbase + 2][nq] = m2; s_s[rbase + 2][nq] = s2;
        s_m[rbase + 3][nq] = m3; s_s[rbase + 3][nq] = s3;
    }
    __syncthreads();
    if (tid < 64) {
        int row = tid;
        float ma = s_m[row][0], mb = s_m[row][1];
        float mn = fmaxf(ma, mb);
        float ss = s_s[row][0] * __expf(ma - mn) + s_s[row][1] * __expf(mb - mn);
        float loss = 0.f;
        if (row0 + row < T) loss = (mn + __logf(ss)) - tdot[row0 + row];
#pragma unroll
        for (int off = 1; off < 64; off <<= 1) loss += __shfl_xor(loss, off);
        if (tid == 0) atomicAdd(acc_out, loss);
    }
}

__global__ void finalize_kernel(const float* __restrict__ acc, const int* __restrict__ meta,
                                float* __restrict__ out) {
    out[0] = acc[0] / (float)meta[3];
}

extern "C" void kernel_launch(void* const* d_in, const int* in_sizes, int n_in,
                              void* d_out, int out_size, void* d_ws, size_t ws_size,
                              hipStream_t stream) {
    const int* x = (const int*)d_in[0];
    const float* emb = (const float*)d_in[1];
    const float* comp_l = (const float*)d_in[2];
    const float* comp_r = (const float*)d_in[3];
    const float* cb = (const float*)d_in[4];
    const float* sos = (const float*)d_in[5];
    const float* eos = (const float*)d_in[6];
    float* out = (float*)d_out;

    float* feats = (float*)d_ws;                 // 8192*256 f32
    float* norms = feats + (size_t)NMAX * 256;   // 8192
    int* index_g = (int*)(norms + NMAX);         // 4096
    float* cos_g = (float*)(index_g + 4096);     // 4096
    int* presence = (int*)(cos_g + 4096);        // 30720
    int* rankbuf = presence + PRES;              // 30720
    int* tokens = rankbuf + PRES;                // 4096
    int* targets = tokens + 4096;                // 8192*3
    int* meta = targets + NMAX * 3;              // 64
    float* acc = (float*)(meta + 64);            // 64
    float* tdot = acc + 64;                      // 8192
    unsigned short* fh = (unsigned short*)(tdot + NMAX);       // 8192*256 bf16
    unsigned short* fl = fh + (size_t)NMAX * 256;
    unsigned short* oh = fl + (size_t)NMAX * 256;
    unsigned short* ol = oh + (size_t)NMAX * 256;

    hipMemsetAsync(presence, 0, PRES * sizeof(int), stream);
    hipMemsetAsync(acc, 0, sizeof(float), stream);

    mark_kernel<<<16, 256, 0, stream>>>(x, presence);
    scan_kernel<<<1, 1024, 0, stream>>>(presence, rankbuf, tokens, meta);
    map_index_kernel<<<16, 256, 0, stream>>>(x, rankbuf, meta, index_g);
    copy_feats_kernel<<<4096, 64, 0, stream>>>(emb, tokens, meta, feats, norms);
    init_cos_kernel<<<64 * 63, 64, 0, stream>>>(feats, norms, index_g, cos_g);
    iterate_kernel<<<1, 1024, 0, stream>>>(feats, norms, index_g, cos_g,
                                           targets, meta, comp_l, comp_r, cb, eos, sos);
    convert_feats_kernel<<<2048, 256, 0, stream>>>(feats, fh, fl);
    prep_outs_kernel<<<2016, 256, 0, stream>>>(feats, targets, meta, comp_l, comp_r,
                                               cb, oh, ol, tdot);
    loss_mfma_kernel<<<126, 512, 0, stream>>>(fh, fl, oh, ol, tdot, meta, acc);
    finalize_kernel<<<1, 1, 0, stream>>>(acc, meta, out);
}

// Round 5
// 717.652 us; speedup vs baseline: 4.6907x; 2.1073x over previous
//
#include <hip/hip_runtime.h>
#include <math.h>

// Banyan compose: phase-1 schedule construction + phase-2 CE replay, all on device.
// Sizes: B=64, L=64, E=256, CH=16. V=30000. Node ids < 8192.
// Phase 1 is split: (a) 64 parallel per-row tree builds (rows are independent;
// dedup only affects IDs, not values), (b) one-wave integer id-assignment replay,
// (c) parallel feature scatter.

#define NMAX 8192
#define PRES 30720
#define HBITS 13
#define HSIZE 8192
#define HMASK 8191

typedef float f32x4 __attribute__((ext_vector_type(4)));
typedef short short8 __attribute__((ext_vector_type(8)));

__device__ __forceinline__ unsigned hash0(int key) {
    return (((unsigned)key) * 2654435761u) >> (32 - HBITS);
}

__device__ __forceinline__ unsigned short f2bf(float f) {
    unsigned u = __float_as_uint(f);
    unsigned r = ((u >> 16) & 1u) + 0x7FFFu;
    return (unsigned short)((u + r) >> 16);
}
__device__ __forceinline__ float bf2f(unsigned short b) {
    return __uint_as_float(((unsigned)b) << 16);
}

// ---- setup kernels ----

__global__ void mark_kernel(const int* __restrict__ x, int* __restrict__ presence) {
    int i = blockIdx.x * blockDim.x + threadIdx.x;
    if (i < 4096) presence[x[i]] = 1;
}

__global__ __launch_bounds__(1024) void scan_kernel(const int* __restrict__ presence,
                                                    int* __restrict__ rank,
                                                    int* __restrict__ tokens,
                                                    int* __restrict__ meta) {
    __shared__ int part[1024];
    int tid = threadIdx.x;
    int base = tid * 30;
    int loc[30];
    int s = 0;
#pragma unroll
    for (int i = 0; i < 30; ++i) { loc[i] = s; s += presence[base + i]; }
    part[tid] = s;
    __syncthreads();
    for (int off = 1; off < 1024; off <<= 1) {
        int v = (tid >= off) ? part[tid - off] : 0;
        __syncthreads();
        part[tid] += v;
        __syncthreads();
    }
    int excl = (tid == 0) ? 0 : part[tid - 1];
#pragma unroll
    for (int i = 0; i < 30; ++i) {
        int r = excl + loc[i];
        rank[base + i] = r;
        if (presence[base + i]) tokens[r] = base + i;
    }
    if (tid == 1023) { meta[0] = part[1023]; meta[1] = part[1023] - 1; }
}

__global__ void map_index_kernel(const int* __restrict__ x, const int* __restrict__ rank,
                                 const int* __restrict__ meta, int* __restrict__ index_g) {
    int i = blockIdx.x * blockDim.x + threadIdx.x;
    if (i < 4096) {
        int r = rank[x[i]];
        index_g[i] = (r == meta[0] - 1) ? -1 : r;
    }
}

__global__ void copy_feats_kernel(const float* __restrict__ emb, const int* __restrict__ tokens,
                                  const int* __restrict__ meta, float* __restrict__ feats,
                                  float* __restrict__ norms) {
    int n = blockIdx.x;
    if (n >= meta[1]) return;
    int t = tokens[n];
    int k = threadIdx.x; // 64
    const float4* src = (const float4*)(emb + (size_t)t * 256);
    float4* dst = (float4*)(feats + (size_t)n * 256);
    float4 v = src[k];
    dst[k] = v;
    float ss = v.x * v.x + v.y * v.y + v.z * v.z + v.w * v.w;
#pragma unroll
    for (int off = 32; off >= 1; off >>= 1) ss += __shfl_down(ss, off);
    if (k == 0) norms[n] = sqrtf(ss);
}

__global__ void init_cos_kernel(const float* __restrict__ feats, const float* __restrict__ norms,
                                const int* __restrict__ index_g, float* __restrict__ cos_g) {
    int bid = blockIdx.x;
    int b = bid / 63, j = bid % 63;
    int l = index_g[b * 64 + j], r = index_g[b * 64 + j + 1];
    float c = -INFINITY;
    if (r != -1) {
        int k = threadIdx.x;
        const float4* fa = (const float4*)(feats + (size_t)l * 256);
        const float4* fb = (const float4*)(feats + (size_t)r * 256);
        float4 a = fa[k], bb = fb[k];
        float d = a.x * bb.x + a.y * bb.y + a.z * bb.z + a.w * bb.w;
#pragma unroll
        for (int off = 32; off >= 1; off >>= 1) d += __shfl_down(d, off);
        c = d / fmaxf(norms[l] * norms[r], 1e-8f);
    }
    if (threadIdx.x == 0) cos_g[b * 64 + j] = c;
}

// ---- pass 1: per-row tree build. 64 blocks x 1 wave, all features in LDS ----
// Local ids: 0..63 = leaf positions (pads included, gid -1), 64+it = internal.

__global__ __launch_bounds__(64) void treebuild_kernel(
    const float* __restrict__ feats, const float* __restrict__ norms_g,
    const int* __restrict__ index_g, const float* __restrict__ cos_g,
    float* __restrict__ rowfeats, int4* __restrict__ rec,
    const float* __restrict__ comp_l, const float* __restrict__ comp_r,
    const float* __restrict__ cb) {
    __shared__ float lf[127][256];   // 127 KB: 64 leaves + 63 internal
    __shared__ float lnorm[128];
    int b = blockIdx.x;
    int lane = threadIdx.x;
    int c0 = 4 * (lane & 3);
    float4 sl4 = make_float4(1.f / (1.f + __expf(-comp_l[c0])),
                             1.f / (1.f + __expf(-comp_l[c0 + 1])),
                             1.f / (1.f + __expf(-comp_l[c0 + 2])),
                             1.f / (1.f + __expf(-comp_l[c0 + 3])));
    float4 sr4 = make_float4(1.f / (1.f + __expf(-comp_r[c0])),
                             1.f / (1.f + __expf(-comp_r[c0 + 1])),
                             1.f / (1.f + __expf(-comp_r[c0 + 2])),
                             1.f / (1.f + __expf(-comp_r[c0 + 3])));
    float4 cb4 = make_float4(cb[c0], cb[c0 + 1], cb[c0 + 2], cb[c0 + 3]);

    int gid = index_g[b * 64 + lane];          // leaf gid of position `lane`
    int isreal = (gid >= 0) ? 1 : 0;
    // load leaf feature rows into LDS
    for (int j = 0; j < 64; ++j) {
        int g = __shfl(gid, j);
        int gc = g < 0 ? 0 : g;
        float4 v = ((const float4*)(feats + (size_t)gc * 256))[lane];
        ((float4*)&lf[j][0])[lane] = v;
    }
    lnorm[lane] = (gid >= 0) ? norms_g[gid] : 0.f;
    float cosr = (lane < 63) ? cos_g[b * 64 + lane] : -INFINITY;
    int locid = lane;
    unsigned long long alive = ~0ull;
    int nreal = 64 - __popcll(__ballot(gid < 0));

    for (int it = 0; it < 63; ++it) {
        int act = (nreal >= 2) ? 1 : 0;
        // argmax (value, first index) butterfly
        float c = cosr; int jj = lane;
#pragma unroll
        for (int off = 1; off < 64; off <<= 1) {
            float c2 = __shfl_xor(c, off);
            int j2 = __shfl_xor(jj, off);
            if (c2 > c || (c2 == c && j2 < jj)) { c = c2; jj = j2; }
        }
        int p = jj;
        unsigned long long after = (alive >> 1) >> p;
        int q = (p + 1 + __builtin_ctzll(after | 0x8000000000000000ull)) & 63;
        unsigned long long bel = alive & ((1ull << p) - 1ull);
        int pp = bel ? (63 - __builtin_clzll(bel)) : -1;
        unsigned long long aft2 = (q < 63) ? (alive >> (q + 1)) : 0ull;
        int ssp = aft2 ? (q + 1 + __builtin_ctzll(aft2)) : -1;
        int l_loc = __shfl(locid, p);
        int r_loc = __shfl(locid, q);
        int ls_loc = (pp >= 0) ? __shfl(locid, pp) : -1;
        int rs_loc = (ssp >= 0) ? __shfl(locid, ssp) : -2;
        int Creal = (ssp >= 0) ? __shfl(isreal, ssp & 63) : 0;
        if (act) {
            int nl = 64 + it;
            float4 a = ((const float4*)&lf[l_loc][0])[lane];
            float4 bb = ((const float4*)&lf[r_loc][0])[lane];
            float4 v;
            v.x = a.x * sl4.x + bb.x * sr4.x + cb4.x;
            v.y = a.y * sl4.y + bb.y * sr4.y + cb4.y;
            v.z = a.z * sl4.z + bb.z * sr4.z + cb4.z;
            v.w = a.w * sl4.w + bb.w * sr4.w + cb4.w;
            ((float4*)&lf[nl][0])[lane] = v;
            ((float4*)(rowfeats + ((size_t)b * 63 + it) * 256))[lane] = v;
            float4 av = (pp >= 0) ? ((const float4*)&lf[ls_loc < 0 ? 0 : ls_loc][0])[lane]
                                  : make_float4(0.f, 0.f, 0.f, 0.f);
            float4 cv = Creal ? ((const float4*)&lf[rs_loc < 0 ? 0 : rs_loc][0])[lane]
                              : make_float4(0.f, 0.f, 0.f, 0.f);
            float sv = v.x * v.x + v.y * v.y + v.z * v.z + v.w * v.w;
            float da = av.x * v.x + av.y * v.y + av.z * v.z + av.w * v.w;
            float dc = cv.x * v.x + cv.y * v.y + cv.z * v.z + cv.w * v.w;
#pragma unroll
            for (int off = 1; off < 64; off <<= 1) {
                sv += __shfl_xor(sv, off);
                da += __shfl_xor(da, off);
                dc += __shfl_xor(dc, off);
            }
            float nn = sqrtf(sv);
            if (lane == 0) lnorm[nl] = nn;
            float nA = (pp >= 0) ? lnorm[ls_loc < 0 ? 0 : ls_loc] : 1.f;
            float nC = Creal ? lnorm[rs_loc < 0 ? 0 : rs_loc] : 1.f;
            float cosA = da / fmaxf(nA * nn, 1e-8f);
            float cosC = Creal ? (dc / fmaxf(nn * nC, 1e-8f)) : -INFINITY;
            if (lane == p) { cosr = cosC; locid = nl; }
            if (lane == pp) cosr = cosA;
            if (lane == q) cosr = -INFINITY;
            alive &= ~(1ull << q);
            nreal -= 1;
        }
        if (lane == 0)
            rec[b * 63 + it] = make_int4(act ? l_loc : -9, r_loc, ls_loc, rs_loc);
    }
}

// ---- pass 2: one-wave global id assignment + dedup + targets ----

__global__ __launch_bounds__(64) void idassign_kernel(
    const int4* __restrict__ rec, const int* __restrict__ index_g,
    int* __restrict__ targets, int* __restrict__ meta, int* __restrict__ newsrc) {
    __shared__ int s_map[64][128];   // local id -> gid per row
    __shared__ int s_hk[HSIZE], s_hv[HSIZE];
    int lane = threadIdx.x;          // row b
    int b = lane;
    for (int i = lane; i < HSIZE; i += 64) s_hk[i] = -1;
    for (int i = lane; i < 4096; i += 64) s_map[i >> 6][i & 63] = index_g[i];
    int N0 = meta[1];
    int Ncur = N0, Tcur = 0;
    int4 R = rec[b * 63];
    for (int it = 0; it < 63; ++it) {
        int4 Rn = R;
        if (it + 1 < 63) Rn = rec[b * 63 + it + 1];
        int act = (R.x != -9) ? 1 : 0;
        int l_g = 0, r_g = 0, key = 0, nid = 0, newf = 0;
        int ls_g = -1, rs_g = -2;
        if (act) {
            l_g = s_map[b][R.x];
            r_g = s_map[b][R.y];
            ls_g = (R.z >= 0) ? s_map[b][R.z] : R.z;
            rs_g = (R.w >= 0) ? s_map[b][R.w] : R.w;
            key = (l_g << HBITS) | r_g;
            unsigned h = hash0(key);
            int found = 0;
            while (true) {
                int k2 = s_hk[h];
                if (k2 == -1) break;
                if (k2 == key) { found = 1; nid = s_hv[h]; break; }
                h = (h + 1) & HMASK;
            }
            newf = found ? 0 : 1;
        }
        unsigned long long actmask = __ballot(act != 0);
        unsigned long long newmask = __ballot(newf != 0);
        unsigned long long below = (1ull << b) - 1ull;
        int ar = __popcll(actmask & below);
        int nact = __popcll(actmask);
        int f = newf;
        if (newmask) {
            for (int j = 0; j < 64; ++j) {
                int kj = __shfl(key, j);
                if (f && ((newmask >> j) & 1ull) && j < b && kj == key) f = 0;
            }
        }
        unsigned long long firstmask = __ballot(f != 0);
        int rk = 0;
        if (firstmask) {
            for (int j = 0; j < 64; ++j) {
                int kj = __shfl(key, j);
                if (((firstmask >> j) & 1ull) && kj < key) rk++;
            }
        }
        int newc = __popcll(firstmask);
        if (newf) nid = Ncur + rk;
        if (f) {
            unsigned h = hash0(key);
            while (true) {
                int prev = atomicCAS(&s_hk[h], -1, key);
                if (prev == -1) { s_hv[h] = nid; break; }
                h = (h + 1) & HMASK;
            }
            newsrc[Ncur - N0 + rk] = (b << 6) | it;
        }
        if (act) {
            int o1 = Tcur + ar;
            targets[o1 * 3 + 0] = l_g;
            targets[o1 * 3 + 1] = ls_g;
            targets[o1 * 3 + 2] = r_g;
            int o2 = Tcur + nact + ar;
            targets[o2 * 3 + 0] = r_g;
            targets[o2 * 3 + 1] = l_g;
            targets[o2 * 3 + 2] = rs_g;
            s_map[b][64 + it] = nid;
        }
        Ncur += newc;
        Tcur += 2 * nact;
        R = Rn;
    }
    if (lane == 0) { meta[2] = Ncur; meta[3] = Tcur; meta[4] = Ncur - N0; }
}

// ---- pass 3: scatter first-occurrence composed rows into global feats ----

__global__ __launch_bounds__(64) void materialize_kernel(
    const float* __restrict__ rowfeats, const int* __restrict__ newsrc,
    const int* __restrict__ meta, float* __restrict__ feats) {
    int g = blockIdx.x;
    if (g >= meta[4]) return;
    int pk = newsrc[g];
    int b = pk >> 6, it = pk & 63;
    int N0 = meta[1];
    ((float4*)(feats + (size_t)(N0 + g) * 256))[threadIdx.x] =
        ((const float4*)(rowfeats + ((size_t)b * 63 + it) * 256))[threadIdx.x];
}

__global__ void append_kernel(const float* __restrict__ eos, const float* __restrict__ sos,
                              const int* __restrict__ meta, float* __restrict__ feats) {
    int n = meta[2];
    feats[(size_t)n * 256 + threadIdx.x] = eos[threadIdx.x];
    feats[(size_t)(n + 1) * 256 + threadIdx.x] = sos[threadIdx.x];
}

// ---- bf16 conversion (hi only for B side) ----
__global__ __launch_bounds__(256) void convert_feats_kernel(
    const float* __restrict__ feats, unsigned short* __restrict__ fh) {
    int row = blockIdx.x * 4 + (threadIdx.x >> 6);
    int lane = threadIdx.x & 63;
    float4 v = ((const float4*)(feats + (size_t)row * 256))[lane];
    ushort4 h;
    h.x = f2bf(v.x); h.y = f2bf(v.y); h.z = f2bf(v.z); h.w = f2bf(v.w);
    ((ushort4*)(fh + (size_t)row * 256))[lane] = h;
}

// ---- out rows (bf16 hi/lo) + exact fp32 target logit ----
__global__ __launch_bounds__(256) void prep_outs_kernel(
    const float* __restrict__ feats, const int* __restrict__ targets,
    const int* __restrict__ meta, const float* __restrict__ comp_l,
    const float* __restrict__ comp_r, const float* __restrict__ cb,
    unsigned short* __restrict__ oh, unsigned short* __restrict__ ol,
    float* __restrict__ tdot) {
    int T = meta[3];
    int Ntot = meta[2] + 2;
    int t = blockIdx.x * 4 + (threadIdx.x >> 6);
    if (t >= T) return;
    int lane = threadIdx.x & 63;
    int c0 = 4 * (lane & 3);
    float4 sl4 = make_float4(1.f / (1.f + __expf(-comp_l[c0])),
                             1.f / (1.f + __expf(-comp_l[c0 + 1])),
                             1.f / (1.f + __expf(-comp_l[c0 + 2])),
                             1.f / (1.f + __expf(-comp_l[c0 + 3])));
    float4 sr4 = make_float4(1.f / (1.f + __expf(-comp_r[c0])),
                             1.f / (1.f + __expf(-comp_r[c0 + 1])),
                             1.f / (1.f + __expf(-comp_r[c0 + 2])),
                             1.f / (1.f + __expf(-comp_r[c0 + 3])));
    float4 cb4 = make_float4(cb[c0], cb[c0 + 1], cb[c0 + 2], cb[c0 + 3]);
    int t0 = targets[t * 3 + 0];
    int i1 = targets[t * 3 + 1], i2 = targets[t * 3 + 2];
    if (i1 < 0) i1 += Ntot;
    if (i2 < 0) i2 += Ntot;
    float4 a = ((const float4*)(feats + (size_t)i1 * 256))[lane];
    float4 b = ((const float4*)(feats + (size_t)i2 * 256))[lane];
    float4 ft = ((const float4*)(feats + (size_t)t0 * 256))[lane];
    float4 v;
    v.x = a.x * sl4.x + b.x * sr4.x + cb4.x;
    v.y = a.y * sl4.y + b.y * sr4.y + cb4.y;
    v.z = a.z * sl4.z + b.z * sr4.z + cb4.z;
    v.w = a.w * sl4.w + b.w * sr4.w + cb4.w;
    float d = v.x * ft.x + v.y * ft.y + v.z * ft.z + v.w * ft.w;
#pragma unroll
    for (int off = 32; off >= 1; off >>= 1) d += __shfl_down(d, off);
    if (lane == 0) tdot[t] = d;
    ushort4 h, l;
    h.x = f2bf(v.x); l.x = f2bf(v.x - bf2f(h.x));
    h.y = f2bf(v.y); l.y = f2bf(v.y - bf2f(h.y));
    h.z = f2bf(v.z); l.z = f2bf(v.z - bf2f(h.z));
    h.w = f2bf(v.w); l.w = f2bf(v.w - bf2f(h.w));
    ((ushort4*)(oh + (size_t)t * 256))[lane] = h;
    ((ushort4*)(ol + (size_t)t * 256))[lane] = l;
}

// ---- loss: (Ah+Al)xBh MFMA, 64 rows/block, 2 col-slabs, partial (m,s) ----
__global__ __launch_bounds__(512) void loss_mfma_kernel(
    const unsigned short* __restrict__ fh, const unsigned short* __restrict__ oh,
    const unsigned short* __restrict__ ol, const int* __restrict__ meta,
    float2* __restrict__ partial) {
    __shared__ float s_m[64][2], s_s[64][2];
    int T = meta[3];
    int Ntot = meta[2] + 2;
    int row0 = blockIdx.x * 64;
    if (row0 >= T) return;
    int slab = blockIdx.y;
    int half = ((Ntot + 63) >> 6) << 5;   // multiple of 32
    int cstart = slab ? half : 0;
    int cend = slab ? Ntot : half;
    int tid = threadIdx.x, lane = tid & 63, w = tid >> 6;
    int mq = w >> 1, nq = w & 1;
    int mrow = row0 + mq * 16 + (lane & 15);
    int kq = lane >> 4;
    const short8* pah = (const short8*)(oh + (size_t)mrow * 256);
    const short8* pal = (const short8*)(ol + (size_t)mrow * 256);
    short8 Ah[8], Al[8];
#pragma unroll
    for (int ks = 0; ks < 8; ++ks) { Ah[ks] = pah[ks * 4 + kq]; Al[ks] = pal[ks * 4 + kq]; }
    float m0 = -1e30f, m1 = -1e30f, m2 = -1e30f, m3 = -1e30f;
    float s0 = 0.f, s1 = 0.f, s2 = 0.f, s3 = 0.f;
    for (int nb = cstart; nb < cend; nb += 32) {
        int col = nb + nq * 16 + (lane & 15);
        const short8* pbh = (const short8*)(fh + (size_t)col * 256);
        f32x4 a0 = {0.f, 0.f, 0.f, 0.f}, a1 = a0;
#pragma unroll
        for (int ks = 0; ks < 8; ++ks) {
            short8 Bh = pbh[ks * 4 + kq];
            a0 = __builtin_amdgcn_mfma_f32_16x16x32_bf16(Ah[ks], Bh, a0, 0, 0, 0);
            a1 = __builtin_amdgcn_mfma_f32_16x16x32_bf16(Al[ks], Bh, a1, 0, 0, 0);
        }
        bool cv = col < cend;
        float v0 = cv ? (a0[0] + a1[0]) : -INFINITY;
        float v1 = cv ? (a0[1] + a1[1]) : -INFINITY;
        float v2 = cv ? (a0[2] + a1[2]) : -INFINITY;
        float v3 = cv ? (a0[3] + a1[3]) : -INFINITY;
        if (v0 > m0) { s0 = s0 * __expf(m0 - v0) + 1.f; m0 = v0; } else s0 += __expf(v0 - m0);
        if (v1 > m1) { s1 = s1 * __expf(m1 - v1) + 1.f; m1 = v1; } else s1 += __expf(v1 - m1);
        if (v2 > m2) { s2 = s2 * __expf(m2 - v2) + 1.f; m2 = v2; } else s2 += __expf(v2 - m2);
        if (v3 > m3) { s3 = s3 * __expf(m3 - v3) + 1.f; m3 = v3; } else s3 += __expf(v3 - m3);
    }
#pragma unroll
    for (int off = 1; off < 16; off <<= 1) {
        float mo, so, mn;
        mo = __shfl_xor(m0, off); so = __shfl_xor(s0, off);
        mn = fmaxf(m0, mo); s0 = s0 * __expf(m0 - mn) + so * __expf(mo - mn); m0 = mn;
        mo = __shfl_xor(m1, off); so = __shfl_xor(s1, off);
        mn = fmaxf(m1, mo); s1 = s1 * __expf(m1 - mn) + so * __expf(mo - mn); m1 = mn;
        mo = __shfl_xor(m2, off); so = __shfl_xor(s2, off);
        mn = fmaxf(m2, mo); s2 = s2 * __expf(m2 - mn) + so * __expf(mo - mn); m2 = mn;
        mo = __shfl_xor(m3, off); so = __shfl_xor(s3, off);
        mn = fmaxf(m3, mo); s3 = s3 * __expf(m3 - mn) + so * __expf(mo - mn); m3 = mn;
    }
    if ((lane & 15) == 0) {
        int rbase = mq * 16 + kq * 4;
        s_m[rbase + 0][nq] = m0; s_s[rbase + 0][nq] = s0;
        s_m[rbase + 1][nq] = m1; s_s[rbase + 1][nq] = s1;
        s_m[rbase + 2][nq] = m2; s_s[rbase + 2][nq] = s2;
        s_m[rbase + 3][nq] = m3; s_s[rbase + 3][nq] = s3;
    }
    __syncthreads();
    if (tid < 64) {
        float ma = s_m[tid][0], mb = s_m[tid][1];
        float mn = fmaxf(ma, mb);
        float ss = s_s[tid][0] * __expf(ma - mn) + s_s[tid][1] * __expf(mb - mn);
        partial[(size_t)slab * NMAX + row0 + tid] = make_float2(mn, ss);
    }
}

__global__ __launch_bounds__(256) void combine_kernel(
    const float2* __restrict__ partial, const float* __restrict__ tdot,
    const int* __restrict__ meta, float* __restrict__ acc) {
    int T = meta[3];
    int r = blockIdx.x * 256 + threadIdx.x;
    float loss = 0.f;
    if (r < T) {
        float2 p0 = partial[r], p1 = partial[NMAX + r];
        float mn = fmaxf(p0.x, p1.x);
        float ss = p0.y * __expf(p0.x - mn) + p1.y * __expf(p1.x - mn);
        loss = (mn + __logf(ss)) - tdot[r];
    }
#pragma unroll
    for (int off = 32; off >= 1; off >>= 1) loss += __shfl_down(loss, off);
    if ((threadIdx.x & 63) == 0) atomicAdd(acc, loss);
}

__global__ void finalize_kernel(const float* __restrict__ acc, const int* __restrict__ meta,
                                float* __restrict__ out) {
    out[0] = acc[0] / (float)meta[3];
}

extern "C" void kernel_launch(void* const* d_in, const int* in_sizes, int n_in,
                              void* d_out, int out_size, void* d_ws, size_t ws_size,
                              hipStream_t stream) {
    const int* x = (const int*)d_in[0];
    const float* emb = (const float*)d_in[1];
    const float* comp_l = (const float*)d_in[2];
    const float* comp_r = (const float*)d_in[3];
    const float* cb = (const float*)d_in[4];
    const float* sos = (const float*)d_in[5];
    const float* eos = (const float*)d_in[6];
    float* out = (float*)d_out;

    float* feats = (float*)d_ws;                   // 8192*256
    float* norms = feats + (size_t)NMAX * 256;     // 8192
    int* index_g = (int*)(norms + NMAX);           // 4096
    float* cos_g = (float*)(index_g + 4096);       // 4096
    int* presence = (int*)(cos_g + 4096);          // 30720
    int* rankbuf = presence + PRES;                // 30720
    int* tokens = rankbuf + PRES;                  // 4096
    int* targets = tokens + 4096;                  // 8192*3
    int* meta = targets + NMAX * 3;                // 64
    float* acc = (float*)(meta + 64);              // 64
    float* tdot = acc + 64;                        // 8192
    float2* partial = (float2*)(tdot + NMAX);      // 2*8192 float2
    int4* rec = (int4*)(partial + 2 * NMAX);       // 64*63 int4
    int* newsrc = (int*)(rec + 64 * 63);           // 4096
    float* rowfeats = (float*)(newsrc + 4096);     // 64*63*256
    unsigned short* fh = (unsigned short*)(rowfeats + (size_t)64 * 63 * 256);
    unsigned short* oh = fh + (size_t)NMAX * 256;
    unsigned short* ol = oh + (size_t)NMAX * 256;

    hipMemsetAsync(presence, 0, PRES * sizeof(int), stream);
    hipMemsetAsync(acc, 0, sizeof(float), stream);

    mark_kernel<<<16, 256, 0, stream>>>(x, presence);
    scan_kernel<<<1, 1024, 0, stream>>>(presence, rankbuf, tokens, meta);
    map_index_kernel<<<16, 256, 0, stream>>>(x, rankbuf, meta, index_g);
    copy_feats_kernel<<<4096, 64, 0, stream>>>(emb, tokens, meta, feats, norms);
    init_cos_kernel<<<64 * 63, 64, 0, stream>>>(feats, norms, index_g, cos_g);
    treebuild_kernel<<<64, 64, 0, stream>>>(feats, norms, index_g, cos_g,
                                            rowfeats, rec, comp_l, comp_r, cb);
    idassign_kernel<<<1, 64, 0, stream>>>(rec, index_g, targets, meta, newsrc);
    materialize_kernel<<<4032, 64, 0, stream>>>(rowfeats, newsrc, meta, feats);
    append_kernel<<<1, 256, 0, stream>>>(eos, sos, meta, feats);
    convert_feats_kernel<<<2048, 256, 0, stream>>>(feats, fh);
    prep_outs_kernel<<<2016, 256, 0, stream>>>(feats, targets, meta, comp_l, comp_r,
                                               cb, oh, ol, tdot);
    loss_mfma_kernel<<<dim3(126, 2), 512, 0, stream>>>(fh, oh, ol, meta, partial);
    combine_kernel<<<32, 256, 0, stream>>>(partial, tdot, meta, acc);
    finalize_kernel<<<1, 1, 0, stream>>>(acc, meta, out);
}

// Round 6
// 521.965 us; speedup vs baseline: 6.4493x; 1.3749x over previous
//
#include <hip/hip_runtime.h>
#include <math.h>

// Banyan compose: phase-1 schedule construction + phase-2 CE replay, all on device.
// Sizes: B=64, L=64, E=256, CH=16. V=30000. Node ids < 8192.
// Phase 1 is split: (a) 64 parallel per-row tree builds (rows are independent;
// dedup only affects IDs, not values), (b) one-wave integer id-assignment replay,
// (c) parallel feature scatter.

#define NMAX 8192
#define PRES 30720
#define HBITS 13
#define HSIZE 8192
#define HMASK 8191

typedef float f32x4 __attribute__((ext_vector_type(4)));
typedef short short8 __attribute__((ext_vector_type(8)));

__device__ __forceinline__ unsigned hash0(int key) {
    return (((unsigned)key) * 2654435761u) >> (32 - HBITS);
}

__device__ __forceinline__ unsigned short f2bf(float f) {
    unsigned u = __float_as_uint(f);
    unsigned r = ((u >> 16) & 1u) + 0x7FFFu;
    return (unsigned short)((u + r) >> 16);
}
__device__ __forceinline__ float bf2f(unsigned short b) {
    return __uint_as_float(((unsigned)b) << 16);
}

// ---- setup kernels ----

__global__ void mark_kernel(const int* __restrict__ x, int* __restrict__ presence) {
    int i = blockIdx.x * blockDim.x + threadIdx.x;
    if (i < 4096) presence[x[i]] = 1;
}

__global__ __launch_bounds__(1024) void scan_kernel(const int* __restrict__ presence,
                                                    int* __restrict__ rank,
                                                    int* __restrict__ tokens,
                                                    int* __restrict__ meta) {
    __shared__ int part[1024];
    int tid = threadIdx.x;
    int base = tid * 30;
    int loc[30];
    int s = 0;
#pragma unroll
    for (int i = 0; i < 30; ++i) { loc[i] = s; s += presence[base + i]; }
    part[tid] = s;
    __syncthreads();
    for (int off = 1; off < 1024; off <<= 1) {
        int v = (tid >= off) ? part[tid - off] : 0;
        __syncthreads();
        part[tid] += v;
        __syncthreads();
    }
    int excl = (tid == 0) ? 0 : part[tid - 1];
#pragma unroll
    for (int i = 0; i < 30; ++i) {
        int r = excl + loc[i];
        rank[base + i] = r;
        if (presence[base + i]) tokens[r] = base + i;
    }
    if (tid == 1023) { meta[0] = part[1023]; meta[1] = part[1023] - 1; }
}

__global__ void map_index_kernel(const int* __restrict__ x, const int* __restrict__ rank,
                                 const int* __restrict__ meta, int* __restrict__ index_g) {
    int i = blockIdx.x * blockDim.x + threadIdx.x;
    if (i < 4096) {
        int r = rank[x[i]];
        index_g[i] = (r == meta[0] - 1) ? -1 : r;
    }
}

__global__ void copy_feats_kernel(const float* __restrict__ emb, const int* __restrict__ tokens,
                                  const int* __restrict__ meta, float* __restrict__ feats,
                                  float* __restrict__ norms) {
    int n = blockIdx.x;
    if (n >= meta[1]) return;
    int t = tokens[n];
    int k = threadIdx.x; // 64
    const float4* src = (const float4*)(emb + (size_t)t * 256);
    float4* dst = (float4*)(feats + (size_t)n * 256);
    float4 v = src[k];
    dst[k] = v;
    float ss = v.x * v.x + v.y * v.y + v.z * v.z + v.w * v.w;
#pragma unroll
    for (int off = 32; off >= 1; off >>= 1) ss += __shfl_down(ss, off);
    if (k == 0) norms[n] = sqrtf(ss);
}

__global__ void init_cos_kernel(const float* __restrict__ feats, const float* __restrict__ norms,
                                const int* __restrict__ index_g, float* __restrict__ cos_g) {
    int bid = blockIdx.x;
    int b = bid / 63, j = bid % 63;
    int l = index_g[b * 64 + j], r = index_g[b * 64 + j + 1];
    float c = -INFINITY;
    if (r != -1) {
        int k = threadIdx.x;
        const float4* fa = (const float4*)(feats + (size_t)l * 256);
        const float4* fb = (const float4*)(feats + (size_t)r * 256);
        float4 a = fa[k], bb = fb[k];
        float d = a.x * bb.x + a.y * bb.y + a.z * bb.z + a.w * bb.w;
#pragma unroll
        for (int off = 32; off >= 1; off >>= 1) d += __shfl_down(d, off);
        c = d / fmaxf(norms[l] * norms[r], 1e-8f);
    }
    if (threadIdx.x == 0) cos_g[b * 64 + j] = c;
}

// ---- pass 1: per-row tree build. 64 blocks x 1 wave, all features in LDS ----

__global__ __launch_bounds__(64) void treebuild_kernel(
    const float* __restrict__ feats, const float* __restrict__ norms_g,
    const int* __restrict__ index_g, const float* __restrict__ cos_g,
    float* __restrict__ rowfeats, int4* __restrict__ rec,
    const float* __restrict__ comp_l, const float* __restrict__ comp_r,
    const float* __restrict__ cb) {
    __shared__ float lf[127][256];
    __shared__ float lnorm[128];
    int b = blockIdx.x;
    int lane = threadIdx.x;
    int c0 = 4 * (lane & 3);
    float4 sl4 = make_float4(1.f / (1.f + __expf(-comp_l[c0])),
                             1.f / (1.f + __expf(-comp_l[c0 + 1])),
                             1.f / (1.f + __expf(-comp_l[c0 + 2])),
                             1.f / (1.f + __expf(-comp_l[c0 + 3])));
    float4 sr4 = make_float4(1.f / (1.f + __expf(-comp_r[c0])),
                             1.f / (1.f + __expf(-comp_r[c0 + 1])),
                             1.f / (1.f + __expf(-comp_r[c0 + 2])),
                             1.f / (1.f + __expf(-comp_r[c0 + 3])));
    float4 cb4 = make_float4(cb[c0], cb[c0 + 1], cb[c0 + 2], cb[c0 + 3]);

    int gid = index_g[b * 64 + lane];
    int isreal = (gid >= 0) ? 1 : 0;
    for (int j = 0; j < 64; ++j) {
        int g = __shfl(gid, j);
        int gc = g < 0 ? 0 : g;
        float4 v = ((const float4*)(feats + (size_t)gc * 256))[lane];
        ((float4*)&lf[j][0])[lane] = v;
    }
    lnorm[lane] = (gid >= 0) ? norms_g[gid] : 0.f;
    float cosr = (lane < 63) ? cos_g[b * 64 + lane] : -INFINITY;
    int locid = lane;
    unsigned long long alive = ~0ull;
    int nreal = 64 - __popcll(__ballot(gid < 0));

    for (int it = 0; it < 63; ++it) {
        int act = (nreal >= 2) ? 1 : 0;
        float c = cosr; int jj = lane;
#pragma unroll
        for (int off = 1; off < 64; off <<= 1) {
            float c2 = __shfl_xor(c, off);
            int j2 = __shfl_xor(jj, off);
            if (c2 > c || (c2 == c && j2 < jj)) { c = c2; jj = j2; }
        }
        int p = jj;
        unsigned long long after = (alive >> 1) >> p;
        int q = (p + 1 + __builtin_ctzll(after | 0x8000000000000000ull)) & 63;
        unsigned long long bel = alive & ((1ull << p) - 1ull);
        int pp = bel ? (63 - __builtin_clzll(bel)) : -1;
        unsigned long long aft2 = (q < 63) ? (alive >> (q + 1)) : 0ull;
        int ssp = aft2 ? (q + 1 + __builtin_ctzll(aft2)) : -1;
        int l_loc = __shfl(locid, p);
        int r_loc = __shfl(locid, q);
        int ls_loc = (pp >= 0) ? __shfl(locid, pp) : -1;
        int rs_loc = (ssp >= 0) ? __shfl(locid, ssp) : -2;
        int Creal = (ssp >= 0) ? __shfl(isreal, ssp & 63) : 0;
        if (act) {
            int nl = 64 + it;
            float4 a = ((const float4*)&lf[l_loc][0])[lane];
            float4 bb = ((const float4*)&lf[r_loc][0])[lane];
            float4 v;
            v.x = a.x * sl4.x + bb.x * sr4.x + cb4.x;
            v.y = a.y * sl4.y + bb.y * sr4.y + cb4.y;
            v.z = a.z * sl4.z + bb.z * sr4.z + cb4.z;
            v.w = a.w * sl4.w + bb.w * sr4.w + cb4.w;
            ((float4*)&lf[nl][0])[lane] = v;
            ((float4*)(rowfeats + ((size_t)b * 63 + it) * 256))[lane] = v;
            float4 av = (pp >= 0) ? ((const float4*)&lf[ls_loc < 0 ? 0 : ls_loc][0])[lane]
                                  : make_float4(0.f, 0.f, 0.f, 0.f);
            float4 cv = Creal ? ((const float4*)&lf[rs_loc < 0 ? 0 : rs_loc][0])[lane]
                              : make_float4(0.f, 0.f, 0.f, 0.f);
            float sv = v.x * v.x + v.y * v.y + v.z * v.z + v.w * v.w;
            float da = av.x * v.x + av.y * v.y + av.z * v.z + av.w * v.w;
            float dc = cv.x * v.x + cv.y * v.y + cv.z * v.z + cv.w * v.w;
#pragma unroll
            for (int off = 1; off < 64; off <<= 1) {
                sv += __shfl_xor(sv, off);
                da += __shfl_xor(da, off);
                dc += __shfl_xor(dc, off);
            }
            float nn = sqrtf(sv);
            if (lane == 0) lnorm[nl] = nn;
            float nA = (pp >= 0) ? lnorm[ls_loc < 0 ? 0 : ls_loc] : 1.f;
            float nC = Creal ? lnorm[rs_loc < 0 ? 0 : rs_loc] : 1.f;
            float cosA = da / fmaxf(nA * nn, 1e-8f);
            float cosC = Creal ? (dc / fmaxf(nn * nC, 1e-8f)) : -INFINITY;
            if (lane == p) { cosr = cosC; locid = nl; }
            if (lane == pp) cosr = cosA;
            if (lane == q) cosr = -INFINITY;
            alive &= ~(1ull << q);
            nreal -= 1;
        }
        if (lane == 0)
            rec[b * 63 + it] = make_int4(act ? l_loc : -9, r_loc, ls_loc, rs_loc);
    }
}

// ---- pass 2: one-wave global id assignment + dedup + targets ----
// Dedup/rank via LDS broadcast-read loops (pipelined ds_read, ~6cy each) instead
// of __shfl all-to-all (128 serialized ~120cy ds_bpermute round-trips).

__global__ __launch_bounds__(64) void idassign_kernel(
    const int4* __restrict__ rec, const int* __restrict__ index_g,
    int* __restrict__ targets, int* __restrict__ meta, int* __restrict__ newsrc) {
    __shared__ int s_map[64][128];   // local id -> gid per row
    __shared__ int s_hk[HSIZE], s_hv[HSIZE];
    __shared__ int s_keyarr[64];
    int lane = threadIdx.x;          // row b
    int b = lane;
    for (int i = lane; i < HSIZE; i += 64) s_hk[i] = -1;
    for (int i = lane; i < 4096; i += 64) s_map[i >> 6][i & 63] = index_g[i];
    int N0 = meta[1];
    int Ncur = N0, Tcur = 0;
    int4 R = rec[b * 63];
    for (int it = 0; it < 63; ++it) {
        int4 Rn = R;
        if (it + 1 < 63) Rn = rec[b * 63 + it + 1];
        int act = (R.x != -9) ? 1 : 0;
        int l_g = 0, r_g = 0, key = 0, nid = 0, newf = 0;
        int ls_g = -1, rs_g = -2;
        if (act) {
            l_g = s_map[b][R.x];
            r_g = s_map[b][R.y];
            ls_g = (R.z >= 0) ? s_map[b][R.z] : R.z;
            rs_g = (R.w >= 0) ? s_map[b][R.w] : R.w;
            key = (l_g << HBITS) | r_g;
            unsigned h = hash0(key);
            int found = 0;
            while (true) {
                int k2 = s_hk[h];
                if (k2 == -1) break;
                if (k2 == key) { found = 1; nid = s_hv[h]; break; }
                h = (h + 1) & HMASK;
            }
            newf = found ? 0 : 1;
        }
        s_keyarr[b] = key;
        __builtin_amdgcn_wave_barrier();
        unsigned long long actmask = __ballot(act != 0);
        unsigned long long newmask = __ballot(newf != 0);
        unsigned long long below = (1ull << b) - 1ull;
        int ar = __popcll(actmask & below);
        int nact = __popcll(actmask);
        // first-occurrence among in-iteration duplicates: LDS broadcast reads
        int f = newf;
        {
            unsigned long long nm_bel = newmask & below;
            int kill = 0;
#pragma unroll
            for (int j = 0; j < 64; ++j) {
                int kj = s_keyarr[j];
                kill |= (((nm_bel >> j) & 1ull) && kj == key) ? 1 : 0;
            }
            if (kill) f = 0;
        }
        unsigned long long firstmask = __ballot(f != 0);
        // rank among sorted unique new keys: LDS broadcast reads
        int rk = 0;
#pragma unroll
        for (int j = 0; j < 64; ++j) {
            int kj = s_keyarr[j];
            rk += (((firstmask >> j) & 1ull) && kj < key) ? 1 : 0;
        }
        int newc = __popcll(firstmask);
        if (newf) nid = Ncur + rk;
        if (f) {
            unsigned h = hash0(key);
            while (true) {
                int prev = atomicCAS(&s_hk[h], -1, key);
                if (prev == -1) { s_hv[h] = nid; break; }
                h = (h + 1) & HMASK;
            }
            newsrc[Ncur - N0 + rk] = (b << 6) | it;
        }
        if (act) {
            int o1 = Tcur + ar;
            targets[o1 * 3 + 0] = l_g;
            targets[o1 * 3 + 1] = ls_g;
            targets[o1 * 3 + 2] = r_g;
            int o2 = Tcur + nact + ar;
            targets[o2 * 3 + 0] = r_g;
            targets[o2 * 3 + 1] = l_g;
            targets[o2 * 3 + 2] = rs_g;
            s_map[b][64 + it] = nid;
        }
        Ncur += newc;
        Tcur += 2 * nact;
        R = Rn;
    }
    if (lane == 0) { meta[2] = Ncur; meta[3] = Tcur; meta[4] = Ncur - N0; }
}

// ---- pass 3: scatter first-occurrence composed rows into global feats ----

__global__ __launch_bounds__(64) void materialize_kernel(
    const float* __restrict__ rowfeats, const int* __restrict__ newsrc,
    const int* __restrict__ meta, float* __restrict__ feats) {
    int g = blockIdx.x;
    if (g >= meta[4]) return;
    int pk = newsrc[g];
    int b = pk >> 6, it = pk & 63;
    int N0 = meta[1];
    ((float4*)(feats + (size_t)(N0 + g) * 256))[threadIdx.x] =
        ((const float4*)(rowfeats + ((size_t)b * 63 + it) * 256))[threadIdx.x];
}

__global__ void append_kernel(const float* __restrict__ eos, const float* __restrict__ sos,
                              const int* __restrict__ meta, float* __restrict__ feats) {
    int n = meta[2];
    feats[(size_t)n * 256 + threadIdx.x] = eos[threadIdx.x];
    feats[(size_t)(n + 1) * 256 + threadIdx.x] = sos[threadIdx.x];
}

// ---- bf16 conversion (hi only for B side) ----
__global__ __launch_bounds__(256) void convert_feats_kernel(
    const float* __restrict__ feats, unsigned short* __restrict__ fh) {
    int row = blockIdx.x * 4 + (threadIdx.x >> 6);
    int lane = threadIdx.x & 63;
    float4 v = ((const float4*)(feats + (size_t)row * 256))[lane];
    ushort4 h;
    h.x = f2bf(v.x); h.y = f2bf(v.y); h.z = f2bf(v.z); h.w = f2bf(v.w);
    ((ushort4*)(fh + (size_t)row * 256))[lane] = h;
}

// ---- out rows (bf16 hi/lo) + exact fp32 target logit ----
__global__ __launch_bounds__(256) void prep_outs_kernel(
    const float* __restrict__ feats, const int* __restrict__ targets,
    const int* __restrict__ meta, const float* __restrict__ comp_l,
    const float* __restrict__ comp_r, const float* __restrict__ cb,
    unsigned short* __restrict__ oh, unsigned short* __restrict__ ol,
    float* __restrict__ tdot) {
    int T = meta[3];
    int Ntot = meta[2] + 2;
    int t = blockIdx.x * 4 + (threadIdx.x >> 6);
    if (t >= T) return;
    int lane = threadIdx.x & 63;
    int c0 = 4 * (lane & 3);
    float4 sl4 = make_float4(1.f / (1.f + __expf(-comp_l[c0])),
                             1.f / (1.f + __expf(-comp_l[c0 + 1])),
                             1.f / (1.f + __expf(-comp_l[c0 + 2])),
                             1.f / (1.f + __expf(-comp_l[c0 + 3])));
    float4 sr4 = make_float4(1.f / (1.f + __expf(-comp_r[c0])),
                             1.f / (1.f + __expf(-comp_r[c0 + 1])),
                             1.f / (1.f + __expf(-comp_r[c0 + 2])),
                             1.f / (1.f + __expf(-comp_r[c0 + 3])));
    float4 cb4 = make_float4(cb[c0], cb[c0 + 1], cb[c0 + 2], cb[c0 + 3]);
    int t0 = targets[t * 3 + 0];
    int i1 = targets[t * 3 + 1], i2 = targets[t * 3 + 2];
    if (i1 < 0) i1 += Ntot;
    if (i2 < 0) i2 += Ntot;
    float4 a = ((const float4*)(feats + (size_t)i1 * 256))[lane];
    float4 b = ((const float4*)(feats + (size_t)i2 * 256))[lane];
    float4 ft = ((const float4*)(feats + (size_t)t0 * 256))[lane];
    float4 v;
    v.x = a.x * sl4.x + b.x * sr4.x + cb4.x;
    v.y = a.y * sl4.y + b.y * sr4.y + cb4.y;
    v.z = a.z * sl4.z + b.z * sr4.z + cb4.z;
    v.w = a.w * sl4.w + b.w * sr4.w + cb4.w;
    float d = v.x * ft.x + v.y * ft.y + v.z * ft.z + v.w * ft.w;
#pragma unroll
    for (int off = 32; off >= 1; off >>= 1) d += __shfl_down(d, off);
    if (lane == 0) tdot[t] = d;
    ushort4 h, l;
    h.x = f2bf(v.x); l.x = f2bf(v.x - bf2f(h.x));
    h.y = f2bf(v.y); l.y = f2bf(v.y - bf2f(h.y));
    h.z = f2bf(v.z); l.z = f2bf(v.z - bf2f(h.z));
    h.w = f2bf(v.w); l.w = f2bf(v.w - bf2f(h.w));
    ((ushort4*)(oh + (size_t)t * 256))[lane] = h;
    ((ushort4*)(ol + (size_t)t * 256))[lane] = l;
}

// ---- loss: (Ah+Al)xBh MFMA, 64 rows/block, 2 col-slabs, partial (m,s) ----
__global__ __launch_bounds__(512) void loss_mfma_kernel(
    const unsigned short* __restrict__ fh, const unsigned short* __restrict__ oh,
    const unsigned short* __restrict__ ol, const int* __restrict__ meta,
    float2* __restrict__ partial) {
    __shared__ float s_m[64][2], s_s[64][2];
    int T = meta[3];
    int Ntot = meta[2] + 2;
    int row0 = blockIdx.x * 64;
    if (row0 >= T) return;
    int slab = blockIdx.y;
    int half = ((Ntot + 63) >> 6) << 5;   // multiple of 32
    int cstart = slab ? half : 0;
    int cend = slab ? Ntot : half;
    int tid = threadIdx.x, lane = tid & 63, w = tid >> 6;
    int mq = w >> 1, nq = w & 1;
    int mrow = row0 + mq * 16 + (lane & 15);
    int kq = lane >> 4;
    const short8* pah = (const short8*)(oh + (size_t)mrow * 256);
    const short8* pal = (const short8*)(ol + (size_t)mrow * 256);
    short8 Ah[8], Al[8];
#pragma unroll
    for (int ks = 0; ks < 8; ++ks) { Ah[ks] = pah[ks * 4 + kq]; Al[ks] = pal[ks * 4 + kq]; }
    float m0 = -1e30f, m1 = -1e30f, m2 = -1e30f, m3 = -1e30f;
    float s0 = 0.f, s1 = 0.f, s2 = 0.f, s3 = 0.f;
    for (int nb = cstart; nb < cend; nb += 32) {
        int col = nb + nq * 16 + (lane & 15);
        const short8* pbh = (const short8*)(fh + (size_t)col * 256);
        f32x4 a0 = {0.f, 0.f, 0.f, 0.f}, a1 = a0;
#pragma unroll
        for (int ks = 0; ks < 8; ++ks) {
            short8 Bh = pbh[ks * 4 + kq];
            a0 = __builtin_amdgcn_mfma_f32_16x16x32_bf16(Ah[ks], Bh, a0, 0, 0, 0);
            a1 = __builtin_amdgcn_mfma_f32_16x16x32_bf16(Al[ks], Bh, a1, 0, 0, 0);
        }
        bool cv = col < cend;
        float v0 = cv ? (a0[0] + a1[0]) : -INFINITY;
        float v1 = cv ? (a0[1] + a1[1]) : -INFINITY;
        float v2 = cv ? (a0[2] + a1[2]) : -INFINITY;
        float v3 = cv ? (a0[3] + a1[3]) : -INFINITY;
        if (v0 > m0) { s0 = s0 * __expf(m0 - v0) + 1.f; m0 = v0; } else s0 += __expf(v0 - m0);
        if (v1 > m1) { s1 = s1 * __expf(m1 - v1) + 1.f; m1 = v1; } else s1 += __expf(v1 - m1);
        if (v2 > m2) { s2 = s2 * __expf(m2 - v2) + 1.f; m2 = v2; } else s2 += __expf(v2 - m2);
        if (v3 > m3) { s3 = s3 * __expf(m3 - v3) + 1.f; m3 = v3; } else s3 += __expf(v3 - m3);
    }
#pragma unroll
    for (int off = 1; off < 16; off <<= 1) {
        float mo, so, mn;
        mo = __shfl_xor(m0, off); so = __shfl_xor(s0, off);
        mn = fmaxf(m0, mo); s0 = s0 * __expf(m0 - mn) + so * __expf(mo - mn); m0 = mn;
        mo = __shfl_xor(m1, off); so = __shfl_xor(s1, off);
        mn = fmaxf(m1, mo); s1 = s1 * __expf(m1 - mn) + so * __expf(mo - mn); m1 = mn;
        mo = __shfl_xor(m2, off); so = __shfl_xor(s2, off);
        mn = fmaxf(m2, mo); s2 = s2 * __expf(m2 - mn) + so * __expf(mo - mn); m2 = mn;
        mo = __shfl_xor(m3, off); so = __shfl_xor(s3, off);
        mn = fmaxf(m3, mo); s3 = s3 * __expf(m3 - mn) + so * __expf(mo - mn); m3 = mn;
    }
    if ((lane & 15) == 0) {
        int rbase = mq * 16 + kq * 4;
        s_m[rbase + 0][nq] = m0; s_s[rbase + 0][nq] = s0;
        s_m[rbase + 1][nq] = m1; s_s[rbase + 1][nq] = s1;
        s_m[rbase + 2][nq] = m2; s_s[rbase + 2][nq] = s2;
        s_m[rbase + 3][nq] = m3; s_s[rbase + 3][nq] = s3;
    }
    __syncthreads();
    if (tid < 64) {
        float ma = s_m[tid][0], mb = s_m[tid][1];
        float mn = fmaxf(ma, mb);
        float ss = s_s[tid][0] * __expf(ma - mn) + s_s[tid][1] * __expf(mb - mn);
        partial[(size_t)slab * NMAX + row0 + tid] = make_float2(mn, ss);
    }
}

__global__ __launch_bounds__(256) void combine_kernel(
    const float2* __restrict__ partial, const float* __restrict__ tdot,
    const int* __restrict__ meta, float* __restrict__ acc) {
    int T = meta[3];
    int r = blockIdx.x * 256 + threadIdx.x;
    float loss = 0.f;
    if (r < T) {
        float2 p0 = partial[r], p1 = partial[NMAX + r];
        float mn = fmaxf(p0.x, p1.x);
        float ss = p0.y * __expf(p0.x - mn) + p1.y * __expf(p1.x - mn);
        loss = (mn + __logf(ss)) - tdot[r];
    }
#pragma unroll
    for (int off = 32; off >= 1; off >>= 1) loss += __shfl_down(loss, off);
    if ((threadIdx.x & 63) == 0) atomicAdd(acc, loss);
}

__global__ void finalize_kernel(const float* __restrict__ acc, const int* __restrict__ meta,
                                float* __restrict__ out) {
    out[0] = acc[0] / (float)meta[3];
}

extern "C" void kernel_launch(void* const* d_in, const int* in_sizes, int n_in,
                              void* d_out, int out_size, void* d_ws, size_t ws_size,
                              hipStream_t stream) {
    const int* x = (const int*)d_in[0];
    const float* emb = (const float*)d_in[1];
    const float* comp_l = (const float*)d_in[2];
    const float* comp_r = (const float*)d_in[3];
    const float* cb = (const float*)d_in[4];
    const float* sos = (const float*)d_in[5];
    const float* eos = (const float*)d_in[6];
    float* out = (float*)d_out;

    float* feats = (float*)d_ws;                   // 8192*256
    float* norms = feats + (size_t)NMAX * 256;     // 8192
    int* index_g = (int*)(norms + NMAX);           // 4096
    float* cos_g = (float*)(index_g + 4096);       // 4096
    int* presence = (int*)(cos_g + 4096);          // 30720
    int* rankbuf = presence + PRES;                // 30720
    int* tokens = rankbuf + PRES;                  // 4096
    int* targets = tokens + 4096;                  // 8192*3
    int* meta = targets + NMAX * 3;                // 64
    float* acc = (float*)(meta + 64);              // 64
    float* tdot = acc + 64;                        // 8192
    float2* partial = (float2*)(tdot + NMAX);      // 2*8192 float2
    int4* rec = (int4*)(partial + 2 * NMAX);       // 64*63 int4
    int* newsrc = (int*)(rec + 64 * 63);           // 4096
    float* rowfeats = (float*)(newsrc + 4096);     // 64*63*256
    unsigned short* fh = (unsigned short*)(rowfeats + (size_t)64 * 63 * 256);
    unsigned short* oh = fh + (size_t)NMAX * 256;
    unsigned short* ol = oh + (size_t)NMAX * 256;

    hipMemsetAsync(presence, 0, PRES * sizeof(int), stream);
    hipMemsetAsync(acc, 0, sizeof(float), stream);

    mark_kernel<<<16, 256, 0, stream>>>(x, presence);
    scan_kernel<<<1, 1024, 0, stream>>>(presence, rankbuf, tokens, meta);
    map_index_kernel<<<16, 256, 0, stream>>>(x, rankbuf, meta, index_g);
    copy_feats_kernel<<<4096, 64, 0, stream>>>(emb, tokens, meta, feats, norms);
    init_cos_kernel<<<64 * 63, 64, 0, stream>>>(feats, norms, index_g, cos_g);
    treebuild_kernel<<<64, 64, 0, stream>>>(feats, norms, index_g, cos_g,
                                            rowfeats, rec, comp_l, comp_r, cb);
    idassign_kernel<<<1, 64, 0, stream>>>(rec, index_g, targets, meta, newsrc);
    materialize_kernel<<<4032, 64, 0, stream>>>(rowfeats, newsrc, meta, feats);
    append_kernel<<<1, 256, 0, stream>>>(eos, sos, meta, feats);
    convert_feats_kernel<<<2048, 256, 0, stream>>>(feats, fh);
    prep_outs_kernel<<<2016, 256, 0, stream>>>(feats, targets, meta, comp_l, comp_r,
                                               cb, oh, ol, tdot);
    loss_mfma_kernel<<<dim3(126, 2), 512, 0, stream>>>(fh, oh, ol, meta, partial);
    combine_kernel<<<32, 256, 0, stream>>>(partial, tdot, meta, acc);
    finalize_kernel<<<1, 1, 0, stream>>>(acc, meta, out);
}

// Round 7
// 380.319 us; speedup vs baseline: 8.8512x; 1.3724x over previous
//
#include <hip/hip_runtime.h>
#include <math.h>

// Banyan compose: phase-1 schedule construction + phase-2 CE replay, all on device.
// Sizes: B=64, L=64, E=256, CH=16. V=30000. Node ids < 8192.
// Phase 1 split: (a) 64 parallel per-row tree builds, (b) one-wave integer
// id-assignment replay (CAS-dedup; id order is arbitrary — loss is permutation-
// invariant in node id), (c) parallel feature scatter.

#define NMAX 8192
#define PRES 30720
#define HBITS 13
#define HSIZE 8192
#define HMASK 8191

typedef float f32x4 __attribute__((ext_vector_type(4)));
typedef short short8 __attribute__((ext_vector_type(8)));

__device__ __forceinline__ unsigned hash0(int key) {
    return (((unsigned)key) * 2654435761u) >> (32 - HBITS);
}

__device__ __forceinline__ unsigned short f2bf(float f) {
    unsigned u = __float_as_uint(f);
    unsigned r = ((u >> 16) & 1u) + 0x7FFFu;
    return (unsigned short)((u + r) >> 16);
}
__device__ __forceinline__ float bf2f(unsigned short b) {
    return __uint_as_float(((unsigned)b) << 16);
}

// ---- setup kernels ----

__global__ void mark_kernel(const int* __restrict__ x, int* __restrict__ presence) {
    int i = blockIdx.x * blockDim.x + threadIdx.x;
    if (i < 4096) presence[x[i]] = 1;
}

__global__ __launch_bounds__(1024) void scan_kernel(const int* __restrict__ presence,
                                                    int* __restrict__ rank,
                                                    int* __restrict__ tokens,
                                                    int* __restrict__ meta) {
    __shared__ int part[1024];
    int tid = threadIdx.x;
    int base = tid * 30;
    int loc[30];
    int s = 0;
#pragma unroll
    for (int i = 0; i < 30; ++i) { loc[i] = s; s += presence[base + i]; }
    part[tid] = s;
    __syncthreads();
    for (int off = 1; off < 1024; off <<= 1) {
        int v = (tid >= off) ? part[tid - off] : 0;
        __syncthreads();
        part[tid] += v;
        __syncthreads();
    }
    int excl = (tid == 0) ? 0 : part[tid - 1];
#pragma unroll
    for (int i = 0; i < 30; ++i) {
        int r = excl + loc[i];
        rank[base + i] = r;
        if (presence[base + i]) tokens[r] = base + i;
    }
    if (tid == 1023) { meta[0] = part[1023]; meta[1] = part[1023] - 1; }
}

__global__ void map_index_kernel(const int* __restrict__ x, const int* __restrict__ rank,
                                 const int* __restrict__ meta, int* __restrict__ index_g) {
    int i = blockIdx.x * blockDim.x + threadIdx.x;
    if (i < 4096) {
        int r = rank[x[i]];
        index_g[i] = (r == meta[0] - 1) ? -1 : r;
    }
}

__global__ void copy_feats_kernel(const float* __restrict__ emb, const int* __restrict__ tokens,
                                  const int* __restrict__ meta, float* __restrict__ feats,
                                  float* __restrict__ norms) {
    int n = blockIdx.x;
    if (n >= meta[1]) return;
    int t = tokens[n];
    int k = threadIdx.x; // 64
    const float4* src = (const float4*)(emb + (size_t)t * 256);
    float4* dst = (float4*)(feats + (size_t)n * 256);
    float4 v = src[k];
    dst[k] = v;
    float ss = v.x * v.x + v.y * v.y + v.z * v.z + v.w * v.w;
#pragma unroll
    for (int off = 32; off >= 1; off >>= 1) ss += __shfl_down(ss, off);
    if (k == 0) norms[n] = sqrtf(ss);
}

__global__ void init_cos_kernel(const float* __restrict__ feats, const float* __restrict__ norms,
                                const int* __restrict__ index_g, float* __restrict__ cos_g) {
    int bid = blockIdx.x;
    int b = bid / 63, j = bid % 63;
    int l = index_g[b * 64 + j], r = index_g[b * 64 + j + 1];
    float c = -INFINITY;
    if (r != -1) {
        int k = threadIdx.x;
        const float4* fa = (const float4*)(feats + (size_t)l * 256);
        const float4* fb = (const float4*)(feats + (size_t)r * 256);
        float4 a = fa[k], bb = fb[k];
        float d = a.x * bb.x + a.y * bb.y + a.z * bb.z + a.w * bb.w;
#pragma unroll
        for (int off = 32; off >= 1; off >>= 1) d += __shfl_down(d, off);
        c = d / fmaxf(norms[l] * norms[r], 1e-8f);
    }
    if (threadIdx.x == 0) cos_g[b * 64 + j] = c;
}

// ---- pass 1: per-row tree build. 64 blocks x 1 wave, all features in LDS ----

__global__ __launch_bounds__(64) void treebuild_kernel(
    const float* __restrict__ feats, const float* __restrict__ norms_g,
    const int* __restrict__ index_g, const float* __restrict__ cos_g,
    float* __restrict__ rowfeats, int4* __restrict__ rec,
    const float* __restrict__ comp_l, const float* __restrict__ comp_r,
    const float* __restrict__ cb) {
    __shared__ float lf[127][256];
    __shared__ float lnorm[128];
    int b = blockIdx.x;
    int lane = threadIdx.x;
    int c0 = 4 * (lane & 3);
    float4 sl4 = make_float4(1.f / (1.f + __expf(-comp_l[c0])),
                             1.f / (1.f + __expf(-comp_l[c0 + 1])),
                             1.f / (1.f + __expf(-comp_l[c0 + 2])),
                             1.f / (1.f + __expf(-comp_l[c0 + 3])));
    float4 sr4 = make_float4(1.f / (1.f + __expf(-comp_r[c0])),
                             1.f / (1.f + __expf(-comp_r[c0 + 1])),
                             1.f / (1.f + __expf(-comp_r[c0 + 2])),
                             1.f / (1.f + __expf(-comp_r[c0 + 3])));
    float4 cb4 = make_float4(cb[c0], cb[c0 + 1], cb[c0 + 2], cb[c0 + 3]);

    int gid = index_g[b * 64 + lane];
    int isreal = (gid >= 0) ? 1 : 0;
    for (int j = 0; j < 64; ++j) {
        int g = __shfl(gid, j);
        int gc = g < 0 ? 0 : g;
        float4 v = ((const float4*)(feats + (size_t)gc * 256))[lane];
        ((float4*)&lf[j][0])[lane] = v;
    }
    lnorm[lane] = (gid >= 0) ? norms_g[gid] : 0.f;
    float cosr = (lane < 63) ? cos_g[b * 64 + lane] : -INFINITY;
    int locid = lane;
    unsigned long long alive = ~0ull;
    int nreal = 64 - __popcll(__ballot(gid < 0));

    for (int it = 0; it < 63; ++it) {
        int act = (nreal >= 2) ? 1 : 0;
        float c = cosr; int jj = lane;
#pragma unroll
        for (int off = 1; off < 64; off <<= 1) {
            float c2 = __shfl_xor(c, off);
            int j2 = __shfl_xor(jj, off);
            if (c2 > c || (c2 == c && j2 < jj)) { c = c2; jj = j2; }
        }
        int p = jj;
        unsigned long long after = (alive >> 1) >> p;
        int q = (p + 1 + __builtin_ctzll(after | 0x8000000000000000ull)) & 63;
        unsigned long long bel = alive & ((1ull << p) - 1ull);
        int pp = bel ? (63 - __builtin_clzll(bel)) : -1;
        unsigned long long aft2 = (q < 63) ? (alive >> (q + 1)) : 0ull;
        int ssp = aft2 ? (q + 1 + __builtin_ctzll(aft2)) : -1;
        int l_loc = __shfl(locid, p);
        int r_loc = __shfl(locid, q);
        int ls_loc = (pp >= 0) ? __shfl(locid, pp) : -1;
        int rs_loc = (ssp >= 0) ? __shfl(locid, ssp) : -2;
        int Creal = (ssp >= 0) ? __shfl(isreal, ssp & 63) : 0;
        if (act) {
            int nl = 64 + it;
            float4 a = ((const float4*)&lf[l_loc][0])[lane];
            float4 bb = ((const float4*)&lf[r_loc][0])[lane];
            float4 v;
            v.x = a.x * sl4.x + bb.x * sr4.x + cb4.x;
            v.y = a.y * sl4.y + bb.y * sr4.y + cb4.y;
            v.z = a.z * sl4.z + bb.z * sr4.z + cb4.z;
            v.w = a.w * sl4.w + bb.w * sr4.w + cb4.w;
            ((float4*)&lf[nl][0])[lane] = v;
            ((float4*)(rowfeats + ((size_t)b * 63 + it) * 256))[lane] = v;
            float4 av = (pp >= 0) ? ((const float4*)&lf[ls_loc < 0 ? 0 : ls_loc][0])[lane]
                                  : make_float4(0.f, 0.f, 0.f, 0.f);
            float4 cv = Creal ? ((const float4*)&lf[rs_loc < 0 ? 0 : rs_loc][0])[lane]
                              : make_float4(0.f, 0.f, 0.f, 0.f);
            float sv = v.x * v.x + v.y * v.y + v.z * v.z + v.w * v.w;
            float da = av.x * v.x + av.y * v.y + av.z * v.z + av.w * v.w;
            float dc = cv.x * v.x + cv.y * v.y + cv.z * v.z + cv.w * v.w;
#pragma unroll
            for (int off = 1; off < 64; off <<= 1) {
                sv += __shfl_xor(sv, off);
                da += __shfl_xor(da, off);
                dc += __shfl_xor(dc, off);
            }
            float nn = sqrtf(sv);
            if (lane == 0) lnorm[nl] = nn;
            float nA = (pp >= 0) ? lnorm[ls_loc < 0 ? 0 : ls_loc] : 1.f;
            float nC = Creal ? lnorm[rs_loc < 0 ? 0 : rs_loc] : 1.f;
            float cosA = da / fmaxf(nA * nn, 1e-8f);
            float cosC = Creal ? (dc / fmaxf(nn * nC, 1e-8f)) : -INFINITY;
            if (lane == p) { cosr = cosC; locid = nl; }
            if (lane == pp) cosr = cosA;
            if (lane == q) cosr = -INFINITY;
            alive &= ~(1ull << q);
            nreal -= 1;
        }
        if (lane == 0)
            rec[b * 63 + it] = make_int4(act ? l_loc : -9, r_loc, ls_loc, rs_loc);
    }
}

// ---- pass 2: one-wave id assignment. CAS-probe dedup; id order arbitrary
// (loss is permutation-invariant in node id), so no sort-rank / first-occ scans.

__global__ __launch_bounds__(64) void idassign_kernel(
    const int4* __restrict__ rec, const int* __restrict__ index_g,
    int* __restrict__ targets, int* __restrict__ meta, int* __restrict__ newsrc) {
    __shared__ int s_map[64][128];   // local id -> gid per row
    __shared__ int s_hk[HSIZE], s_hv[HSIZE];
    int b = threadIdx.x;             // row
    for (int i = b; i < HSIZE; i += 64) s_hk[i] = -1;
    for (int i = b; i < 4096; i += 64) s_map[i >> 6][i & 63] = index_g[i];
    int N0 = meta[1];
    int Ncur = N0, Tcur = 0;
    __syncthreads();
    int4 R = rec[b * 63];
    for (int it = 0; it < 63; ++it) {
        int4 Rn = R;
        if (it + 1 < 63) Rn = rec[b * 63 + it + 1];   // prefetch next record
        int act = (R.x != -9) ? 1 : 0;
        int l_g = 0, r_g = 0, key = 0, nid = 0;
        int ls_g = -1, rs_g = -2;
        unsigned h = 0;
        int won = 0, need = 0;
        if (act) {
            l_g = s_map[b][R.x];
            r_g = s_map[b][R.y];
            ls_g = (R.z >= 0) ? s_map[b][R.z] : R.z;
            rs_g = (R.w >= 0) ? s_map[b][R.w] : R.w;
            key = (l_g << HBITS) | r_g;
            h = hash0(key);
            need = 1;
        }
        // CAS probe: terminate having inserted (won) or located the key's slot.
        while (__any(need)) {
            if (need) {
                int prev = atomicCAS(&s_hk[h], -1, key);
                if (prev == -1) { won = 1; need = 0; }
                else if (prev == key) { need = 0; }
                else { h = (h + 1) & HMASK; }
            }
        }
        unsigned long long actmask = __ballot(act != 0);
        unsigned long long winmask = __ballot(won != 0);
        unsigned long long below = (1ull << b) - 1ull;
        int ar = __popcll(actmask & below);
        int nact = __popcll(actmask);
        int newc = __popcll(winmask);
        if (won) {
            nid = Ncur + __popcll(winmask & below);
            s_hv[h] = nid;
        }
        __syncthreads();   // winners' s_hv visible to same-iteration duplicates
        if (act && !won) nid = s_hv[h];
        if (won) newsrc[nid - N0] = (b << 6) | it;
        if (act) {
            int o1 = Tcur + ar;
            targets[o1 * 3 + 0] = l_g;
            targets[o1 * 3 + 1] = ls_g;
            targets[o1 * 3 + 2] = r_g;
            int o2 = Tcur + nact + ar;
            targets[o2 * 3 + 0] = r_g;
            targets[o2 * 3 + 1] = l_g;
            targets[o2 * 3 + 2] = rs_g;
            s_map[b][64 + it] = nid;
        }
        Ncur += newc;
        Tcur += 2 * nact;
        R = Rn;
    }
    if (b == 0) { meta[2] = Ncur; meta[3] = Tcur; meta[4] = Ncur - N0; }
}

// ---- pass 3: scatter first-occurrence composed rows into global feats ----

__global__ __launch_bounds__(64) void materialize_kernel(
    const float* __restrict__ rowfeats, const int* __restrict__ newsrc,
    const int* __restrict__ meta, float* __restrict__ feats) {
    int g = blockIdx.x;
    if (g >= meta[4]) return;
    int pk = newsrc[g];
    int b = pk >> 6, it = pk & 63;
    int N0 = meta[1];
    ((float4*)(feats + (size_t)(N0 + g) * 256))[threadIdx.x] =
        ((const float4*)(rowfeats + ((size_t)b * 63 + it) * 256))[threadIdx.x];
}

__global__ void append_kernel(const float* __restrict__ eos, const float* __restrict__ sos,
                              const int* __restrict__ meta, float* __restrict__ feats) {
    int n = meta[2];
    feats[(size_t)n * 256 + threadIdx.x] = eos[threadIdx.x];
    feats[(size_t)(n + 1) * 256 + threadIdx.x] = sos[threadIdx.x];
}

// ---- bf16 conversion (hi only for B side) ----
__global__ __launch_bounds__(256) void convert_feats_kernel(
    const float* __restrict__ feats, unsigned short* __restrict__ fh) {
    int row = blockIdx.x * 4 + (threadIdx.x >> 6);
    int lane = threadIdx.x & 63;
    float4 v = ((const float4*)(feats + (size_t)row * 256))[lane];
    ushort4 h;
    h.x = f2bf(v.x); h.y = f2bf(v.y); h.z = f2bf(v.z); h.w = f2bf(v.w);
    ((ushort4*)(fh + (size_t)row * 256))[lane] = h;
}

// ---- out rows (bf16 hi/lo) + exact fp32 target logit ----
__global__ __launch_bounds__(256) void prep_outs_kernel(
    const float* __restrict__ feats, const int* __restrict__ targets,
    const int* __restrict__ meta, const float* __restrict__ comp_l,
    const float* __restrict__ comp_r, const float* __restrict__ cb,
    unsigned short* __restrict__ oh, unsigned short* __restrict__ ol,
    float* __restrict__ tdot) {
    int T = meta[3];
    int Ntot = meta[2] + 2;
    int t = blockIdx.x * 4 + (threadIdx.x >> 6);
    if (t >= T) return;
    int lane = threadIdx.x & 63;
    int c0 = 4 * (lane & 3);
    float4 sl4 = make_float4(1.f / (1.f + __expf(-comp_l[c0])),
                             1.f / (1.f + __expf(-comp_l[c0 + 1])),
                             1.f / (1.f + __expf(-comp_l[c0 + 2])),
                             1.f / (1.f + __expf(-comp_l[c0 + 3])));
    float4 sr4 = make_float4(1.f / (1.f + __expf(-comp_r[c0])),
                             1.f / (1.f + __expf(-comp_r[c0 + 1])),
                             1.f / (1.f + __expf(-comp_r[c0 + 2])),
                             1.f / (1.f + __expf(-comp_r[c0 + 3])));
    float4 cb4 = make_float4(cb[c0], cb[c0 + 1], cb[c0 + 2], cb[c0 + 3]);
    int t0 = targets[t * 3 + 0];
    int i1 = targets[t * 3 + 1], i2 = targets[t * 3 + 2];
    if (i1 < 0) i1 += Ntot;
    if (i2 < 0) i2 += Ntot;
    float4 a = ((const float4*)(feats + (size_t)i1 * 256))[lane];
    float4 b = ((const float4*)(feats + (size_t)i2 * 256))[lane];
    float4 ft = ((const float4*)(feats + (size_t)t0 * 256))[lane];
    float4 v;
    v.x = a.x * sl4.x + b.x * sr4.x + cb4.x;
    v.y = a.y * sl4.y + b.y * sr4.y + cb4.y;
    v.z = a.z * sl4.z + b.z * sr4.z + cb4.z;
    v.w = a.w * sl4.w + b.w * sr4.w + cb4.w;
    float d = v.x * ft.x + v.y * ft.y + v.z * ft.z + v.w * ft.w;
#pragma unroll
    for (int off = 32; off >= 1; off >>= 1) d += __shfl_down(d, off);
    if (lane == 0) tdot[t] = d;
    ushort4 h, l;
    h.x = f2bf(v.x); l.x = f2bf(v.x - bf2f(h.x));
    h.y = f2bf(v.y); l.y = f2bf(v.y - bf2f(h.y));
    h.z = f2bf(v.z); l.z = f2bf(v.z - bf2f(h.z));
    h.w = f2bf(v.w); l.w = f2bf(v.w - bf2f(h.w));
    ((ushort4*)(oh + (size_t)t * 256))[lane] = h;
    ((ushort4*)(ol + (size_t)t * 256))[lane] = l;
}

// ---- loss: (Ah+Al)xBh MFMA, 64 rows/block, 2 col-slabs, partial (m,s) ----
__global__ __launch_bounds__(512) void loss_mfma_kernel(
    const unsigned short* __restrict__ fh, const unsigned short* __restrict__ oh,
    const unsigned short* __restrict__ ol, const int* __restrict__ meta,
    float2* __restrict__ partial) {
    __shared__ float s_m[64][2], s_s[64][2];
    int T = meta[3];
    int Ntot = meta[2] + 2;
    int row0 = blockIdx.x * 64;
    if (row0 >= T) return;
    int slab = blockIdx.y;
    int half = ((Ntot + 63) >> 6) << 5;   // multiple of 32
    int cstart = slab ? half : 0;
    int cend = slab ? Ntot : half;
    int tid = threadIdx.x, lane = tid & 63, w = tid >> 6;
    int mq = w >> 1, nq = w & 1;
    int mrow = row0 + mq * 16 + (lane & 15);
    int kq = lane >> 4;
    const short8* pah = (const short8*)(oh + (size_t)mrow * 256);
    const short8* pal = (const short8*)(ol + (size_t)mrow * 256);
    short8 Ah[8], Al[8];
#pragma unroll
    for (int ks = 0; ks < 8; ++ks) { Ah[ks] = pah[ks * 4 + kq]; Al[ks] = pal[ks * 4 + kq]; }
    float m0 = -1e30f, m1 = -1e30f, m2 = -1e30f, m3 = -1e30f;
    float s0 = 0.f, s1 = 0.f, s2 = 0.f, s3 = 0.f;
    for (int nb = cstart; nb < cend; nb += 32) {
        int col = nb + nq * 16 + (lane & 15);
        const short8* pbh = (const short8*)(fh + (size_t)col * 256);
        f32x4 a0 = {0.f, 0.f, 0.f, 0.f}, a1 = a0;
#pragma unroll
        for (int ks = 0; ks < 8; ++ks) {
            short8 Bh = pbh[ks * 4 + kq];
            a0 = __builtin_amdgcn_mfma_f32_16x16x32_bf16(Ah[ks], Bh, a0, 0, 0, 0);
            a1 = __builtin_amdgcn_mfma_f32_16x16x32_bf16(Al[ks], Bh, a1, 0, 0, 0);
        }
        bool cv = col < cend;
        float v0 = cv ? (a0[0] + a1[0]) : -INFINITY;
        float v1 = cv ? (a0[1] + a1[1]) : -INFINITY;
        float v2 = cv ? (a0[2] + a1[2]) : -INFINITY;
        float v3 = cv ? (a0[3] + a1[3]) : -INFINITY;
        if (v0 > m0) { s0 = s0 * __expf(m0 - v0) + 1.f; m0 = v0; } else s0 += __expf(v0 - m0);
        if (v1 > m1) { s1 = s1 * __expf(m1 - v1) + 1.f; m1 = v1; } else s1 += __expf(v1 - m1);
        if (v2 > m2) { s2 = s2 * __expf(m2 - v2) + 1.f; m2 = v2; } else s2 += __expf(v2 - m2);
        if (v3 > m3) { s3 = s3 * __expf(m3 - v3) + 1.f; m3 = v3; } else s3 += __expf(v3 - m3);
    }
#pragma unroll
    for (int off = 1; off < 16; off <<= 1) {
        float mo, so, mn;
        mo = __shfl_xor(m0, off); so = __shfl_xor(s0, off);
        mn = fmaxf(m0, mo); s0 = s0 * __expf(m0 - mn) + so * __expf(mo - mn); m0 = mn;
        mo = __shfl_xor(m1, off); so = __shfl_xor(s1, off);
        mn = fmaxf(m1, mo); s1 = s1 * __expf(m1 - mn) + so * __expf(mo - mn); m1 = mn;
        mo = __shfl_xor(m2, off); so = __shfl_xor(s2, off);
        mn = fmaxf(m2, mo); s2 = s2 * __expf(m2 - mn) + so * __expf(mo - mn); m2 = mn;
        mo = __shfl_xor(m3, off); so = __shfl_xor(s3, off);
        mn = fmaxf(m3, mo); s3 = s3 * __expf(m3 - mn) + so * __expf(mo - mn); m3 = mn;
    }
    if ((lane & 15) == 0) {
        int rbase = mq * 16 + kq * 4;
        s_m[rbase + 0][nq] = m0; s_s[rbase + 0][nq] = s0;
        s_m[rbase + 1][nq] = m1; s_s[rbase + 1][nq] = s1;
        s_m[rbase + 2][nq] = m2; s_s[rbase + 2][nq] = s2;
        s_m[rbase + 3][nq] = m3; s_s[rbase + 3][nq] = s3;
    }
    __syncthreads();
    if (tid < 64) {
        float ma = s_m[tid][0], mb = s_m[tid][1];
        float mn = fmaxf(ma, mb);
        float ss = s_s[tid][0] * __expf(ma - mn) + s_s[tid][1] * __expf(mb - mn);
        partial[(size_t)slab * NMAX + row0 + tid] = make_float2(mn, ss);
    }
}

__global__ __launch_bounds__(256) void combine_kernel(
    const float2* __restrict__ partial, const float* __restrict__ tdot,
    const int* __restrict__ meta, float* __restrict__ acc) {
    int T = meta[3];
    int r = blockIdx.x * 256 + threadIdx.x;
    float loss = 0.f;
    if (r < T) {
        float2 p0 = partial[r], p1 = partial[NMAX + r];
        float mn = fmaxf(p0.x, p1.x);
        float ss = p0.y * __expf(p0.x - mn) + p1.y * __expf(p1.x - mn);
        loss = (mn + __logf(ss)) - tdot[r];
    }
#pragma unroll
    for (int off = 32; off >= 1; off >>= 1) loss += __shfl_down(loss, off);
    if ((threadIdx.x & 63) == 0) atomicAdd(acc, loss);
}

__global__ void finalize_kernel(const float* __restrict__ acc, const int* __restrict__ meta,
                                float* __restrict__ out) {
    out[0] = acc[0] / (float)meta[3];
}

extern "C" void kernel_launch(void* const* d_in, const int* in_sizes, int n_in,
                              void* d_out, int out_size, void* d_ws, size_t ws_size,
                              hipStream_t stream) {
    const int* x = (const int*)d_in[0];
    const float* emb = (const float*)d_in[1];
    const float* comp_l = (const float*)d_in[2];
    const float* comp_r = (const float*)d_in[3];
    const float* cb = (const float*)d_in[4];
    const float* sos = (const float*)d_in[5];
    const float* eos = (const float*)d_in[6];
    float* out = (float*)d_out;

    float* feats = (float*)d_ws;                   // 8192*256
    float* norms = feats + (size_t)NMAX * 256;     // 8192
    int* index_g = (int*)(norms + NMAX);           // 4096
    float* cos_g = (float*)(index_g + 4096);       // 4096
    int* presence = (int*)(cos_g + 4096);          // 30720
    int* rankbuf = presence + PRES;                // 30720
    int* tokens = rankbuf + PRES;                  // 4096
    int* targets = tokens + 4096;                  // 8192*3
    int* meta = targets + NMAX * 3;                // 64
    float* acc = (float*)(meta + 64);              // 64
    float* tdot = acc + 64;                        // 8192
    float2* partial = (float2*)(tdot + NMAX);      // 2*8192 float2
    int4* rec = (int4*)(partial + 2 * NMAX);       // 64*63 int4
    int* newsrc = (int*)(rec + 64 * 63);           // 4096
    float* rowfeats = (float*)(newsrc + 4096);     // 64*63*256
    unsigned short* fh = (unsigned short*)(rowfeats + (size_t)64 * 63 * 256);
    unsigned short* oh = fh + (size_t)NMAX * 256;
    unsigned short* ol = oh + (size_t)NMAX * 256;

    hipMemsetAsync(presence, 0, PRES * sizeof(int), stream);
    hipMemsetAsync(acc, 0, sizeof(float), stream);

    mark_kernel<<<16, 256, 0, stream>>>(x, presence);
    scan_kernel<<<1, 1024, 0, stream>>>(presence, rankbuf, tokens, meta);
    map_index_kernel<<<16, 256, 0, stream>>>(x, rankbuf, meta, index_g);
    copy_feats_kernel<<<4096, 64, 0, stream>>>(emb, tokens, meta, feats, norms);
    init_cos_kernel<<<64 * 63, 64, 0, stream>>>(feats, norms, index_g, cos_g);
    treebuild_kernel<<<64, 64, 0, stream>>>(feats, norms, index_g, cos_g,
                                            rowfeats, rec, comp_l, comp_r, cb);
    idassign_kernel<<<1, 64, 0, stream>>>(rec, index_g, targets, meta, newsrc);
    materialize_kernel<<<4032, 64, 0, stream>>>(rowfeats, newsrc, meta, feats);
    append_kernel<<<1, 256, 0, stream>>>(eos, sos, meta, feats);
    convert_feats_kernel<<<2048, 256, 0, stream>>>(feats, fh);
    prep_outs_kernel<<<2016, 256, 0, stream>>>(feats, targets, meta, comp_l, comp_r,
                                               cb, oh, ol, tdot);
    loss_mfma_kernel<<<dim3(126, 2), 512, 0, stream>>>(fh, oh, ol, meta, partial);
    combine_kernel<<<32, 256, 0, stream>>>(partial, tdot, meta, acc);
    finalize_kernel<<<1, 1, 0, stream>>>(acc, meta, out);
}

// Round 8
// 269.721 us; speedup vs baseline: 12.4807x; 1.4100x over previous
//
#include <hip/hip_runtime.h>
#include <math.h>

// Banyan compose: phase-1 schedule construction + phase-2 CE replay, all on device.
// Sizes: B=64, L=64, E=256, CH=16. V=30000. Node ids < 8192.
// Phase 1 split: (a) 64 parallel per-row tree builds, (b) one-wave integer
// id-assignment replay (CAS-dedup; id order arbitrary — loss is permutation-
// invariant in node id), (c) parallel feature scatter.
// Phase 2: bf16 MFMA logits GEMM (fragment-major B layout), online logsumexp.

#define NMAX 8192
#define PRES 30720
#define HBITS 13
#define HSIZE 8192
#define HMASK 8191
#define LOG2E 1.44269504f
#define LN2 0.69314718f

typedef float f32x4 __attribute__((ext_vector_type(4)));
typedef short short8 __attribute__((ext_vector_type(8)));

__device__ __forceinline__ unsigned hash0(int key) {
    return (((unsigned)key) * 2654435761u) >> (32 - HBITS);
}

__device__ __forceinline__ unsigned short f2bf(float f) {
    unsigned u = __float_as_uint(f);
    unsigned r = ((u >> 16) & 1u) + 0x7FFFu;
    return (unsigned short)((u + r) >> 16);
}
__device__ __forceinline__ float bf2f(unsigned short b) {
    return __uint_as_float(((unsigned)b) << 16);
}

// ---- setup kernels ----

__global__ void mark_kernel(const int* __restrict__ x, int* __restrict__ presence) {
    int i = blockIdx.x * blockDim.x + threadIdx.x;
    if (i < 4096) presence[x[i]] = 1;
}

__global__ __launch_bounds__(1024) void scan_kernel(const int* __restrict__ presence,
                                                    int* __restrict__ rank,
                                                    int* __restrict__ tokens,
                                                    int* __restrict__ meta) {
    __shared__ int part[1024];
    int tid = threadIdx.x;
    int base = tid * 30;
    int loc[30];
    int s = 0;
#pragma unroll
    for (int i = 0; i < 30; ++i) { loc[i] = s; s += presence[base + i]; }
    part[tid] = s;
    __syncthreads();
    for (int off = 1; off < 1024; off <<= 1) {
        int v = (tid >= off) ? part[tid - off] : 0;
        __syncthreads();
        part[tid] += v;
        __syncthreads();
    }
    int excl = (tid == 0) ? 0 : part[tid - 1];
#pragma unroll
    for (int i = 0; i < 30; ++i) {
        int r = excl + loc[i];
        rank[base + i] = r;
        if (presence[base + i]) tokens[r] = base + i;
    }
    if (tid == 1023) { meta[0] = part[1023]; meta[1] = part[1023] - 1; }
}

__global__ void map_index_kernel(const int* __restrict__ x, const int* __restrict__ rank,
                                 const int* __restrict__ meta, int* __restrict__ index_g) {
    int i = blockIdx.x * blockDim.x + threadIdx.x;
    if (i < 4096) {
        int r = rank[x[i]];
        index_g[i] = (r == meta[0] - 1) ? -1 : r;
    }
}

__global__ void copy_feats_kernel(const float* __restrict__ emb, const int* __restrict__ tokens,
                                  const int* __restrict__ meta, float* __restrict__ feats,
                                  float* __restrict__ norms) {
    int n = blockIdx.x;
    if (n >= meta[1]) return;
    int t = tokens[n];
    int k = threadIdx.x; // 64
    const float4* src = (const float4*)(emb + (size_t)t * 256);
    float4* dst = (float4*)(feats + (size_t)n * 256);
    float4 v = src[k];
    dst[k] = v;
    float ss = v.x * v.x + v.y * v.y + v.z * v.z + v.w * v.w;
#pragma unroll
    for (int off = 32; off >= 1; off >>= 1) ss += __shfl_down(ss, off);
    if (k == 0) norms[n] = sqrtf(ss);
}

__global__ void init_cos_kernel(const float* __restrict__ feats, const float* __restrict__ norms,
                                const int* __restrict__ index_g, float* __restrict__ cos_g) {
    int bid = blockIdx.x;
    int b = bid / 63, j = bid % 63;
    int l = index_g[b * 64 + j], r = index_g[b * 64 + j + 1];
    float c = -INFINITY;
    if (r != -1) {
        int k = threadIdx.x;
        const float4* fa = (const float4*)(feats + (size_t)l * 256);
        const float4* fb = (const float4*)(feats + (size_t)r * 256);
        float4 a = fa[k], bb = fb[k];
        float d = a.x * bb.x + a.y * bb.y + a.z * bb.z + a.w * bb.w;
#pragma unroll
        for (int off = 32; off >= 1; off >>= 1) d += __shfl_down(d, off);
        c = d / fmaxf(norms[l] * norms[r], 1e-8f);
    }
    if (threadIdx.x == 0) cos_g[b * 64 + j] = c;
}

// ---- pass 1: per-row tree build. 64 blocks x 1 wave, all features in LDS ----

__global__ __launch_bounds__(64) void treebuild_kernel(
    const float* __restrict__ feats, const float* __restrict__ norms_g,
    const int* __restrict__ index_g, const float* __restrict__ cos_g,
    float* __restrict__ rowfeats, int4* __restrict__ rec,
    const float* __restrict__ comp_l, const float* __restrict__ comp_r,
    const float* __restrict__ cb) {
    __shared__ float lf[127][256];
    __shared__ float lnorm[128];
    int b = blockIdx.x;
    int lane = threadIdx.x;
    int c0 = 4 * (lane & 3);
    float4 sl4 = make_float4(1.f / (1.f + __expf(-comp_l[c0])),
                             1.f / (1.f + __expf(-comp_l[c0 + 1])),
                             1.f / (1.f + __expf(-comp_l[c0 + 2])),
                             1.f / (1.f + __expf(-comp_l[c0 + 3])));
    float4 sr4 = make_float4(1.f / (1.f + __expf(-comp_r[c0])),
                             1.f / (1.f + __expf(-comp_r[c0 + 1])),
                             1.f / (1.f + __expf(-comp_r[c0 + 2])),
                             1.f / (1.f + __expf(-comp_r[c0 + 3])));
    float4 cb4 = make_float4(cb[c0], cb[c0 + 1], cb[c0 + 2], cb[c0 + 3]);

    int gid = index_g[b * 64 + lane];
    int isreal = (gid >= 0) ? 1 : 0;
    for (int j = 0; j < 64; ++j) {
        int g = __shfl(gid, j);
        int gc = g < 0 ? 0 : g;
        float4 v = ((const float4*)(feats + (size_t)gc * 256))[lane];
        ((float4*)&lf[j][0])[lane] = v;
    }
    lnorm[lane] = (gid >= 0) ? norms_g[gid] : 0.f;
    float cosr = (lane < 63) ? cos_g[b * 64 + lane] : -INFINITY;
    int locid = lane;
    unsigned long long alive = ~0ull;
    int nreal = 64 - __popcll(__ballot(gid < 0));

    for (int it = 0; it < 63; ++it) {
        int act = (nreal >= 2) ? 1 : 0;
        float c = cosr; int jj = lane;
#pragma unroll
        for (int off = 1; off < 64; off <<= 1) {
            float c2 = __shfl_xor(c, off);
            int j2 = __shfl_xor(jj, off);
            if (c2 > c || (c2 == c && j2 < jj)) { c = c2; jj = j2; }
        }
        int p = jj;
        unsigned long long after = (alive >> 1) >> p;
        int q = (p + 1 + __builtin_ctzll(after | 0x8000000000000000ull)) & 63;
        unsigned long long bel = alive & ((1ull << p) - 1ull);
        int pp = bel ? (63 - __builtin_clzll(bel)) : -1;
        unsigned long long aft2 = (q < 63) ? (alive >> (q + 1)) : 0ull;
        int ssp = aft2 ? (q + 1 + __builtin_ctzll(aft2)) : -1;
        int l_loc = __shfl(locid, p);
        int r_loc = __shfl(locid, q);
        int ls_loc = (pp >= 0) ? __shfl(locid, pp) : -1;
        int rs_loc = (ssp >= 0) ? __shfl(locid, ssp) : -2;
        int Creal = (ssp >= 0) ? __shfl(isreal, ssp & 63) : 0;
        if (act) {
            int nl = 64 + it;
            float4 a = ((const float4*)&lf[l_loc][0])[lane];
            float4 bb = ((const float4*)&lf[r_loc][0])[lane];
            float4 v;
            v.x = a.x * sl4.x + bb.x * sr4.x + cb4.x;
            v.y = a.y * sl4.y + bb.y * sr4.y + cb4.y;
            v.z = a.z * sl4.z + bb.z * sr4.z + cb4.z;
            v.w = a.w * sl4.w + bb.w * sr4.w + cb4.w;
            ((float4*)&lf[nl][0])[lane] = v;
            ((float4*)(rowfeats + ((size_t)b * 63 + it) * 256))[lane] = v;
            float4 av = (pp >= 0) ? ((const float4*)&lf[ls_loc < 0 ? 0 : ls_loc][0])[lane]
                                  : make_float4(0.f, 0.f, 0.f, 0.f);
            float4 cv = Creal ? ((const float4*)&lf[rs_loc < 0 ? 0 : rs_loc][0])[lane]
                              : make_float4(0.f, 0.f, 0.f, 0.f);
            float sv = v.x * v.x + v.y * v.y + v.z * v.z + v.w * v.w;
            float da = av.x * v.x + av.y * v.y + av.z * v.z + av.w * v.w;
            float dc = cv.x * v.x + cv.y * v.y + cv.z * v.z + cv.w * v.w;
#pragma unroll
            for (int off = 1; off < 64; off <<= 1) {
                sv += __shfl_xor(sv, off);
                da += __shfl_xor(da, off);
                dc += __shfl_xor(dc, off);
            }
            float nn = sqrtf(sv);
            if (lane == 0) lnorm[nl] = nn;
            float nA = (pp >= 0) ? lnorm[ls_loc < 0 ? 0 : ls_loc] : 1.f;
            float nC = Creal ? lnorm[rs_loc < 0 ? 0 : rs_loc] : 1.f;
            float cosA = da / fmaxf(nA * nn, 1e-8f);
            float cosC = Creal ? (dc / fmaxf(nn * nC, 1e-8f)) : -INFINITY;
            if (lane == p) { cosr = cosC; locid = nl; }
            if (lane == pp) cosr = cosA;
            if (lane == q) cosr = -INFINITY;
            alive &= ~(1ull << q);
            nreal -= 1;
        }
        if (lane == 0)
            rec[b * 63 + it] = make_int4(act ? l_loc : -9, r_loc, ls_loc, rs_loc);
    }
}

// ---- pass 2: one-wave id assignment (CAS-probe dedup, arbitrary id order) ----

__global__ __launch_bounds__(64) void idassign_kernel(
    const int4* __restrict__ rec, const int* __restrict__ index_g,
    int* __restrict__ targets, int* __restrict__ meta, int* __restrict__ newsrc) {
    __shared__ int s_map[64][128];   // local id -> gid per row
    __shared__ int s_hk[HSIZE], s_hv[HSIZE];
    int b = threadIdx.x;             // row
    for (int i = b; i < HSIZE; i += 64) s_hk[i] = -1;
    for (int i = b; i < 4096; i += 64) s_map[i >> 6][i & 63] = index_g[i];
    int N0 = meta[1];
    int Ncur = N0, Tcur = 0;
    __syncthreads();
    int4 R = rec[b * 63];
    for (int it = 0; it < 63; ++it) {
        int4 Rn = R;
        if (it + 1 < 63) Rn = rec[b * 63 + it + 1];   // prefetch next record
        int act = (R.x != -9) ? 1 : 0;
        int l_g = 0, r_g = 0, key = 0, nid = 0;
        int ls_g = -1, rs_g = -2;
        unsigned h = 0;
        int won = 0, need = 0;
        if (act) {
            l_g = s_map[b][R.x];
            r_g = s_map[b][R.y];
            ls_g = (R.z >= 0) ? s_map[b][R.z] : R.z;
            rs_g = (R.w >= 0) ? s_map[b][R.w] : R.w;
            key = (l_g << HBITS) | r_g;
            h = hash0(key);
            need = 1;
        }
        while (__any(need)) {
            if (need) {
                int prev = atomicCAS(&s_hk[h], -1, key);
                if (prev == -1) { won = 1; need = 0; }
                else if (prev == key) { need = 0; }
                else { h = (h + 1) & HMASK; }
            }
        }
        unsigned long long actmask = __ballot(act != 0);
        unsigned long long winmask = __ballot(won != 0);
        unsigned long long below = (1ull << b) - 1ull;
        int ar = __popcll(actmask & below);
        int nact = __popcll(actmask);
        int newc = __popcll(winmask);
        if (won) {
            nid = Ncur + __popcll(winmask & below);
            s_hv[h] = nid;
        }
        __syncthreads();   // winners' s_hv visible to same-iteration duplicates
        if (act && !won) nid = s_hv[h];
        if (won) newsrc[nid - N0] = (b << 6) | it;
        if (act) {
            int o1 = Tcur + ar;
            targets[o1 * 3 + 0] = l_g;
            targets[o1 * 3 + 1] = ls_g;
            targets[o1 * 3 + 2] = r_g;
            int o2 = Tcur + nact + ar;
            targets[o2 * 3 + 0] = r_g;
            targets[o2 * 3 + 1] = l_g;
            targets[o2 * 3 + 2] = rs_g;
            s_map[b][64 + it] = nid;
        }
        Ncur += newc;
        Tcur += 2 * nact;
        R = Rn;
    }
    if (b == 0) { meta[2] = Ncur; meta[3] = Tcur; meta[4] = Ncur - N0; }
}

// ---- pass 3: scatter first-occurrence composed rows into global feats ----

__global__ __launch_bounds__(64) void materialize_kernel(
    const float* __restrict__ rowfeats, const int* __restrict__ newsrc,
    const int* __restrict__ meta, float* __restrict__ feats) {
    int g = blockIdx.x;
    if (g >= meta[4]) return;
    int pk = newsrc[g];
    int b = pk >> 6, it = pk & 63;
    int N0 = meta[1];
    ((float4*)(feats + (size_t)(N0 + g) * 256))[threadIdx.x] =
        ((const float4*)(rowfeats + ((size_t)b * 63 + it) * 256))[threadIdx.x];
}

__global__ void append_kernel(const float* __restrict__ eos, const float* __restrict__ sos,
                              const int* __restrict__ meta, float* __restrict__ feats) {
    int n = meta[2];
    feats[(size_t)n * 256 + threadIdx.x] = eos[threadIdx.x];
    feats[(size_t)(n + 1) * 256 + threadIdx.x] = sos[threadIdx.x];
}

// ---- bf16 conversion to fragment-major layout ----
// fhT[tile][ks][kq*16+col] (short8): tile = row/16, col = row%16, element
// range of entry = [(ks*4+kq)*8, +8). A wave's B-load for (tile, ks) is then
// fhT + tile*512 + ks*64 + lane  -> 64 consecutive short8 = coalesced 1KB.
__global__ __launch_bounds__(256) void convert_feats_kernel(
    const float* __restrict__ feats, short8* __restrict__ fhT) {
    int g = blockIdx.x * 256 + threadIdx.x;   // over NMAX*32 short8s
    int tile = g >> 9, rem = g & 511;
    int ks = rem >> 6, lane64 = rem & 63;
    int kq = lane64 >> 4, col = lane64 & 15;
    int row = tile * 16 + col;
    int e0 = (ks * 4 + kq) * 8;
    const float4* src = (const float4*)(feats + (size_t)row * 256 + e0);
    float4 v0 = src[0], v1 = src[1];
    short8 o;
    o[0] = (short)f2bf(v0.x); o[1] = (short)f2bf(v0.y);
    o[2] = (short)f2bf(v0.z); o[3] = (short)f2bf(v0.w);
    o[4] = (short)f2bf(v1.x); o[5] = (short)f2bf(v1.y);
    o[6] = (short)f2bf(v1.z); o[7] = (short)f2bf(v1.w);
    fhT[g] = o;
}

// ---- out rows (bf16) + exact fp32 target logit ----
__global__ __launch_bounds__(256) void prep_outs_kernel(
    const float* __restrict__ feats, const int* __restrict__ targets,
    const int* __restrict__ meta, const float* __restrict__ comp_l,
    const float* __restrict__ comp_r, const float* __restrict__ cb,
    unsigned short* __restrict__ oh, float* __restrict__ tdot) {
    int T = meta[3];
    int Ntot = meta[2] + 2;
    int t = blockIdx.x * 4 + (threadIdx.x >> 6);
    if (t >= T) return;
    int lane = threadIdx.x & 63;
    int c0 = 4 * (lane & 3);
    float4 sl4 = make_float4(1.f / (1.f + __expf(-comp_l[c0])),
                             1.f / (1.f + __expf(-comp_l[c0 + 1])),
                             1.f / (1.f + __expf(-comp_l[c0 + 2])),
                             1.f / (1.f + __expf(-comp_l[c0 + 3])));
    float4 sr4 = make_float4(1.f / (1.f + __expf(-comp_r[c0])),
                             1.f / (1.f + __expf(-comp_r[c0 + 1])),
                             1.f / (1.f + __expf(-comp_r[c0 + 2])),
                             1.f / (1.f + __expf(-comp_r[c0 + 3])));
    float4 cb4 = make_float4(cb[c0], cb[c0 + 1], cb[c0 + 2], cb[c0 + 3]);
    int t0 = targets[t * 3 + 0];
    int i1 = targets[t * 3 + 1], i2 = targets[t * 3 + 2];
    if (i1 < 0) i1 += Ntot;
    if (i2 < 0) i2 += Ntot;
    float4 a = ((const float4*)(feats + (size_t)i1 * 256))[lane];
    float4 b = ((const float4*)(feats + (size_t)i2 * 256))[lane];
    float4 ft = ((const float4*)(feats + (size_t)t0 * 256))[lane];
    float4 v;
    v.x = a.x * sl4.x + b.x * sr4.x + cb4.x;
    v.y = a.y * sl4.y + b.y * sr4.y + cb4.y;
    v.z = a.z * sl4.z + b.z * sr4.z + cb4.z;
    v.w = a.w * sl4.w + b.w * sr4.w + cb4.w;
    float d = v.x * ft.x + v.y * ft.y + v.z * ft.z + v.w * ft.w;
#pragma unroll
    for (int off = 32; off >= 1; off >>= 1) d += __shfl_down(d, off);
    if (lane == 0) tdot[t] = d;
    ushort4 h;
    h.x = f2bf(v.x); h.y = f2bf(v.y); h.z = f2bf(v.z); h.w = f2bf(v.w);
    ((ushort4*)(oh + (size_t)t * 256))[lane] = h;
}

// ---- loss: bf16 MFMA with coalesced fragment-major B, 4 col-slabs ----
// 126 x 4 blocks, 512 threads (8 waves = 4 row-quadrants x 2 col-halves).
// Two independent K-chains (ks 0-3, 4-7) for MFMA ILP. Online logsumexp in
// exp2 domain; partial (m2, s) per (slab, row).
__global__ __launch_bounds__(512) void loss_mfma_kernel(
    const short8* __restrict__ fhT, const unsigned short* __restrict__ oh,
    const int* __restrict__ meta, float2* __restrict__ partial) {
    __shared__ float s_m[64][2], s_s[64][2];
    int T = meta[3];
    int Ntot = meta[2] + 2;
    int row0 = blockIdx.x * 64;
    if (row0 >= T) return;
    int slab = blockIdx.y;
    int P = (Ntot + 127) >> 7;            // 32-col steps per slab
    int cstart = slab * (P << 5);
    int cend = min(Ntot, cstart + (P << 5));
    int tid = threadIdx.x, lane = tid & 63, w = tid >> 6;
    int mq = w >> 1, nq = w & 1;
    int mrow = row0 + mq * 16 + (lane & 15);
    int kq = lane >> 4;
    const short8* pah = (const short8*)(oh + (size_t)mrow * 256);
    short8 Ah[8];
#pragma unroll
    for (int ks = 0; ks < 8; ++ks) Ah[ks] = pah[ks * 4 + kq];
    float m0 = -1e30f, m1 = -1e30f, m2 = -1e30f, m3 = -1e30f;
    float s0 = 0.f, s1 = 0.f, s2 = 0.f, s3 = 0.f;
    for (int nb = cstart; nb < cend; nb += 32) {
        const short8* pb = fhT + ((size_t)(nb >> 4) + nq) * 512;
        f32x4 a0 = {0.f, 0.f, 0.f, 0.f}, a1 = a0;
#pragma unroll
        for (int ks = 0; ks < 4; ++ks) {
            a0 = __builtin_amdgcn_mfma_f32_16x16x32_bf16(Ah[ks], pb[ks * 64 + lane], a0, 0, 0, 0);
            a1 = __builtin_amdgcn_mfma_f32_16x16x32_bf16(Ah[ks + 4], pb[(ks + 4) * 64 + lane], a1, 0, 0, 0);
        }
        int col = nb + nq * 16 + (lane & 15);
        bool cv = col < cend;
        float v0 = cv ? (a0[0] + a1[0]) * LOG2E : -INFINITY;
        float v1 = cv ? (a0[1] + a1[1]) * LOG2E : -INFINITY;
        float v2 = cv ? (a0[2] + a1[2]) * LOG2E : -INFINITY;
        float v3 = cv ? (a0[3] + a1[3]) * LOG2E : -INFINITY;
        float mn;
        mn = fmaxf(m0, v0); s0 = s0 * exp2f(m0 - mn) + exp2f(v0 - mn); m0 = mn;
        mn = fmaxf(m1, v1); s1 = s1 * exp2f(m1 - mn) + exp2f(v1 - mn); m1 = mn;
        mn = fmaxf(m2, v2); s2 = s2 * exp2f(m2 - mn) + exp2f(v2 - mn); m2 = mn;
        mn = fmaxf(m3, v3); s3 = s3 * exp2f(m3 - mn) + exp2f(v3 - mn); m3 = mn;
    }
#pragma unroll
    for (int off = 1; off < 16; off <<= 1) {
        float mo, so, mn;
        mo = __shfl_xor(m0, off); so = __shfl_xor(s0, off);
        mn = fmaxf(m0, mo); s0 = s0 * exp2f(m0 - mn) + so * exp2f(mo - mn); m0 = mn;
        mo = __shfl_xor(m1, off); so = __shfl_xor(s1, off);
        mn = fmaxf(m1, mo); s1 = s1 * exp2f(m1 - mn) + so * exp2f(mo - mn); m1 = mn;
        mo = __shfl_xor(m2, off); so = __shfl_xor(s2, off);
        mn = fmaxf(m2, mo); s2 = s2 * exp2f(m2 - mn) + so * exp2f(mo - mn); m2 = mn;
        mo = __shfl_xor(m3, off); so = __shfl_xor(s3, off);
        mn = fmaxf(m3, mo); s3 = s3 * exp2f(m3 - mn) + so * exp2f(mo - mn); m3 = mn;
    }
    if ((lane & 15) == 0) {
        int rbase = mq * 16 + kq * 4;
        s_m[rbase + 0][nq] = m0; s_s[rbase + 0][nq] = s0;
        s_m[rbase + 1][nq] = m1; s_s[rbase + 1][nq] = s1;
        s_m[rbase + 2][nq] = m2; s_s[rbase + 2][nq] = s2;
        s_m[rbase + 3][nq] = m3; s_s[rbase + 3][nq] = s3;
    }
    __syncthreads();
    if (tid < 64) {
        float ma = s_m[tid][0], mb = s_m[tid][1];
        float mn = fmaxf(ma, mb);
        float ss = s_s[tid][0] * exp2f(ma - mn) + s_s[tid][1] * exp2f(mb - mn);
        partial[(size_t)slab * NMAX + row0 + tid] = make_float2(mn, ss);
    }
}

__global__ __launch_bounds__(256) void combine_kernel(
    const float2* __restrict__ partial, const float* __restrict__ tdot,
    const int* __restrict__ meta, float* __restrict__ acc) {
    int T = meta[3];
    int r = blockIdx.x * 256 + threadIdx.x;
    float loss = 0.f;
    if (r < T) {
        float2 p0 = partial[r];
        float2 p1 = partial[NMAX + r];
        float2 p2 = partial[2 * NMAX + r];
        float2 p3 = partial[3 * NMAX + r];
        float mn = fmaxf(fmaxf(p0.x, p1.x), fmaxf(p2.x, p3.x));
        float ss = p0.y * exp2f(p0.x - mn) + p1.y * exp2f(p1.x - mn) +
                   p2.y * exp2f(p2.x - mn) + p3.y * exp2f(p3.x - mn);
        loss = (mn + __log2f(ss)) * LN2 - tdot[r];
    }
#pragma unroll
    for (int off = 32; off >= 1; off >>= 1) loss += __shfl_down(loss, off);
    if ((threadIdx.x & 63) == 0) atomicAdd(acc, loss);
}

__global__ void finalize_kernel(const float* __restrict__ acc, const int* __restrict__ meta,
                                float* __restrict__ out) {
    out[0] = acc[0] / (float)meta[3];
}

extern "C" void kernel_launch(void* const* d_in, const int* in_sizes, int n_in,
                              void* d_out, int out_size, void* d_ws, size_t ws_size,
                              hipStream_t stream) {
    const int* x = (const int*)d_in[0];
    const float* emb = (const float*)d_in[1];
    const float* comp_l = (const float*)d_in[2];
    const float* comp_r = (const float*)d_in[3];
    const float* cb = (const float*)d_in[4];
    const float* sos = (const float*)d_in[5];
    const float* eos = (const float*)d_in[6];
    float* out = (float*)d_out;

    float* feats = (float*)d_ws;                   // 8192*256
    float* norms = feats + (size_t)NMAX * 256;     // 8192
    int* index_g = (int*)(norms + NMAX);           // 4096
    float* cos_g = (float*)(index_g + 4096);       // 4096
    int* presence = (int*)(cos_g + 4096);          // 30720
    int* rankbuf = presence + PRES;                // 30720
    int* tokens = rankbuf + PRES;                  // 4096
    int* targets = tokens + 4096;                  // 8192*3
    int* meta = targets + NMAX * 3;                // 64
    float* acc = (float*)(meta + 64);              // 64
    float* tdot = acc + 64;                        // 8192
    float2* partial = (float2*)(tdot + NMAX);      // 4*8192 float2
    int4* rec = (int4*)(partial + 4 * NMAX);       // 64*63 int4
    int* newsrc = (int*)(rec + 64 * 63);           // 4096
    float* rowfeats = (float*)(newsrc + 4096);     // 64*63*256
    short8* fhT = (short8*)(rowfeats + (size_t)64 * 63 * 256);   // NMAX*32 short8
    unsigned short* oh = (unsigned short*)(fhT + (size_t)NMAX * 32);

    hipMemsetAsync(presence, 0, PRES * sizeof(int), stream);
    hipMemsetAsync(acc, 0, sizeof(float), stream);

    mark_kernel<<<16, 256, 0, stream>>>(x, presence);
    scan_kernel<<<1, 1024, 0, stream>>>(presence, rankbuf, tokens, meta);
    map_index_kernel<<<16, 256, 0, stream>>>(x, rankbuf, meta, index_g);
    copy_feats_kernel<<<4096, 64, 0, stream>>>(emb, tokens, meta, feats, norms);
    init_cos_kernel<<<64 * 63, 64, 0, stream>>>(feats, norms, index_g, cos_g);
    treebuild_kernel<<<64, 64, 0, stream>>>(feats, norms, index_g, cos_g,
                                            rowfeats, rec, comp_l, comp_r, cb);
    idassign_kernel<<<1, 64, 0, stream>>>(rec, index_g, targets, meta, newsrc);
    materialize_kernel<<<4032, 64, 0, stream>>>(rowfeats, newsrc, meta, feats);
    append_kernel<<<1, 256, 0, stream>>>(eos, sos, meta, feats);
    convert_feats_kernel<<<1024, 256, 0, stream>>>(feats, fhT);
    prep_outs_kernel<<<2016, 256, 0, stream>>>(feats, targets, meta, comp_l, comp_r,
                                               cb, oh, tdot);
    loss_mfma_kernel<<<dim3(126, 4), 512, 0, stream>>>(fhT, oh, meta, partial);
    combine_kernel<<<32, 256, 0, stream>>>(partial, tdot, meta, acc);
    finalize_kernel<<<1, 1, 0, stream>>>(acc, meta, out);
}

// Round 9
// 254.110 us; speedup vs baseline: 13.2474x; 1.0614x over previous
//
#include <hip/hip_runtime.h>
#include <math.h>

// Banyan compose: phase-1 schedule construction + phase-2 CE replay, all on device.
// Sizes: B=64, L=64, E=256, CH=16. V=30000. Node ids < 8192.
// Phase 1 split: (a) 64 parallel per-row tree builds, (b) one-wave integer
// id-assignment replay (CAS-dedup; id order arbitrary — loss is permutation-
// invariant in node id), (c) parallel feature scatter.
// Phase 2: bf16 MFMA logits GEMM (fragment-major B layout), online logsumexp.

#define NMAX 8192
#define PRES 30720
#define HBITS 13
#define HSIZE 8192
#define HMASK 8191
#define LOG2E 1.44269504f
#define LN2 0.69314718f

typedef float f32x4 __attribute__((ext_vector_type(4)));
typedef short short8 __attribute__((ext_vector_type(8)));

__device__ __forceinline__ unsigned hash0(int key) {
    return (((unsigned)key) * 2654435761u) >> (32 - HBITS);
}

__device__ __forceinline__ unsigned short f2bf(float f) {
    unsigned u = __float_as_uint(f);
    unsigned r = ((u >> 16) & 1u) + 0x7FFFu;
    return (unsigned short)((u + r) >> 16);
}
__device__ __forceinline__ float bf2f(unsigned short b) {
    return __uint_as_float(((unsigned)b) << 16);
}

__device__ __forceinline__ float rdl_f(float v, int lane) {
    return __int_as_float(__builtin_amdgcn_readlane(__float_as_int(v), lane));
}

// DPP row_ror step: lane i receives lane (i+N)%16 of its 16-lane row.
// ror-based all-reduce: after steps 1,2,4,8 each lane holds the row total.
#define SUM_STEP(CTRL, X) \
    X += __int_as_float(__builtin_amdgcn_update_dpp(0, __float_as_int(X), CTRL, 0xF, 0xF, true));
#define SUM3_REDUCE(A, B, C) {                                                  \
    SUM_STEP(0x121, A) SUM_STEP(0x121, B) SUM_STEP(0x121, C)                    \
    SUM_STEP(0x122, A) SUM_STEP(0x122, B) SUM_STEP(0x122, C)                    \
    SUM_STEP(0x124, A) SUM_STEP(0x124, B) SUM_STEP(0x124, C)                    \
    SUM_STEP(0x128, A) SUM_STEP(0x128, B) SUM_STEP(0x128, C)                    \
    A = rdl_f(A, 0) + rdl_f(A, 16) + rdl_f(A, 32) + rdl_f(A, 48);               \
    B = rdl_f(B, 0) + rdl_f(B, 16) + rdl_f(B, 32) + rdl_f(B, 48);               \
    C = rdl_f(C, 0) + rdl_f(C, 16) + rdl_f(C, 32) + rdl_f(C, 48);               \
}
#define ARGMAX_STEP(CTRL, V, I) {                                               \
    float _ov = __int_as_float(__builtin_amdgcn_update_dpp(0, __float_as_int(V), CTRL, 0xF, 0xF, true)); \
    int _oi = __builtin_amdgcn_update_dpp(0, I, CTRL, 0xF, 0xF, true);          \
    if (_ov > V || (_ov == V && _oi < I)) { V = _ov; I = _oi; }                 \
}
// (max, first-index) all-reduce -> uniform result in all lanes.
#define ARGMAX_REDUCE(V, I) {                                                   \
    ARGMAX_STEP(0x121, V, I) ARGMAX_STEP(0x122, V, I)                           \
    ARGMAX_STEP(0x124, V, I) ARGMAX_STEP(0x128, V, I)                           \
    float _v0 = rdl_f(V, 0), _v1 = rdl_f(V, 16), _v2 = rdl_f(V, 32), _v3 = rdl_f(V, 48); \
    int _i0 = __builtin_amdgcn_readlane(I, 0), _i1 = __builtin_amdgcn_readlane(I, 16);   \
    int _i2 = __builtin_amdgcn_readlane(I, 32), _i3 = __builtin_amdgcn_readlane(I, 48);  \
    V = _v0; I = _i0;                                                           \
    if (_v1 > V || (_v1 == V && _i1 < I)) { V = _v1; I = _i1; }                 \
    if (_v2 > V || (_v2 == V && _i2 < I)) { V = _v2; I = _i2; }                 \
    if (_v3 > V || (_v3 == V && _i3 < I)) { V = _v3; I = _i3; }                 \
}

// ---- setup kernels ----

__global__ void mark_kernel(const int* __restrict__ x, int* __restrict__ presence) {
    int i = blockIdx.x * blockDim.x + threadIdx.x;
    if (i < 4096) presence[x[i]] = 1;
}

__global__ __launch_bounds__(1024) void scan_kernel(const int* __restrict__ presence,
                                                    int* __restrict__ rank,
                                                    int* __restrict__ tokens,
                                                    int* __restrict__ meta) {
    __shared__ int part[1024];
    int tid = threadIdx.x;
    int base = tid * 30;
    int loc[30];
    int s = 0;
#pragma unroll
    for (int i = 0; i < 30; ++i) { loc[i] = s; s += presence[base + i]; }
    part[tid] = s;
    __syncthreads();
    for (int off = 1; off < 1024; off <<= 1) {
        int v = (tid >= off) ? part[tid - off] : 0;
        __syncthreads();
        part[tid] += v;
        __syncthreads();
    }
    int excl = (tid == 0) ? 0 : part[tid - 1];
#pragma unroll
    for (int i = 0; i < 30; ++i) {
        int r = excl + loc[i];
        rank[base + i] = r;
        if (presence[base + i]) tokens[r] = base + i;
    }
    if (tid == 1023) { meta[0] = part[1023]; meta[1] = part[1023] - 1; }
}

__global__ void map_index_kernel(const int* __restrict__ x, const int* __restrict__ rank,
                                 const int* __restrict__ meta, int* __restrict__ index_g) {
    int i = blockIdx.x * blockDim.x + threadIdx.x;
    if (i < 4096) {
        int r = rank[x[i]];
        index_g[i] = (r == meta[0] - 1) ? -1 : r;
    }
}

__global__ void copy_feats_kernel(const float* __restrict__ emb, const int* __restrict__ tokens,
                                  const int* __restrict__ meta, float* __restrict__ feats,
                                  float* __restrict__ norms) {
    int n = blockIdx.x;
    if (n >= meta[1]) return;
    int t = tokens[n];
    int k = threadIdx.x; // 64
    const float4* src = (const float4*)(emb + (size_t)t * 256);
    float4* dst = (float4*)(feats + (size_t)n * 256);
    float4 v = src[k];
    dst[k] = v;
    float ss = v.x * v.x + v.y * v.y + v.z * v.z + v.w * v.w;
#pragma unroll
    for (int off = 32; off >= 1; off >>= 1) ss += __shfl_down(ss, off);
    if (k == 0) norms[n] = sqrtf(ss);
}

__global__ void init_cos_kernel(const float* __restrict__ feats, const float* __restrict__ norms,
                                const int* __restrict__ index_g, float* __restrict__ cos_g) {
    int bid = blockIdx.x;
    int b = bid / 63, j = bid % 63;
    int l = index_g[b * 64 + j], r = index_g[b * 64 + j + 1];
    float c = -INFINITY;
    if (r != -1) {
        int k = threadIdx.x;
        const float4* fa = (const float4*)(feats + (size_t)l * 256);
        const float4* fb = (const float4*)(feats + (size_t)r * 256);
        float4 a = fa[k], bb = fb[k];
        float d = a.x * bb.x + a.y * bb.y + a.z * bb.z + a.w * bb.w;
#pragma unroll
        for (int off = 32; off >= 1; off >>= 1) d += __shfl_down(d, off);
        c = d / fmaxf(norms[l] * norms[r], 1e-8f);
    }
    if (threadIdx.x == 0) cos_g[b * 64 + j] = c;
}

// ---- pass 1: per-row tree build. 64 blocks x 1 wave, features in LDS.
// Critical-path engineering: argmax over unchanged entries is computed in
// parallel with the compose/dot chain (final argmax = 3-candidate compare);
// reductions use DPP row_ror (VALU) + readlane instead of ds_bpermute
// butterflies; uniform broadcasts (locid/isreal/norms) use v_readlane.

__global__ __launch_bounds__(64) void treebuild_kernel(
    const float* __restrict__ feats, const float* __restrict__ norms_g,
    const int* __restrict__ index_g, const float* __restrict__ cos_g,
    float* __restrict__ rowfeats, int4* __restrict__ rec,
    const float* __restrict__ comp_l, const float* __restrict__ comp_r,
    const float* __restrict__ cb) {
    __shared__ float lf[127][256];
    int b = blockIdx.x;
    int lane = threadIdx.x;
    int c0 = 4 * (lane & 3);
    float4 sl4 = make_float4(1.f / (1.f + __expf(-comp_l[c0])),
                             1.f / (1.f + __expf(-comp_l[c0 + 1])),
                             1.f / (1.f + __expf(-comp_l[c0 + 2])),
                             1.f / (1.f + __expf(-comp_l[c0 + 3])));
    float4 sr4 = make_float4(1.f / (1.f + __expf(-comp_r[c0])),
                             1.f / (1.f + __expf(-comp_r[c0 + 1])),
                             1.f / (1.f + __expf(-comp_r[c0 + 2])),
                             1.f / (1.f + __expf(-comp_r[c0 + 3])));
    float4 cb4 = make_float4(cb[c0], cb[c0 + 1], cb[c0 + 2], cb[c0 + 3]);

    int gid = index_g[b * 64 + lane];
    int isreal = (gid >= 0) ? 1 : 0;
    for (int j = 0; j < 64; ++j) {
        int g = __shfl(gid, j);
        int gc = g < 0 ? 0 : g;
        float4 v = ((const float4*)(feats + (size_t)gc * 256))[lane];
        ((float4*)&lf[j][0])[lane] = v;
    }
    float n0 = (gid >= 0) ? norms_g[gid] : 0.f;   // norm of leaf at position `lane`
    float n1 = 0.f;                               // norm of internal node 64+lane
    float cosr = (lane < 63) ? cos_g[b * 64 + lane] : -INFINITY;
    int locid = lane;
    unsigned long long alive = ~0ull;
    int nreal = 64 - __popcll(__ballot(gid < 0));

    // initial argmax (uniform result)
    float Mv = cosr; int Mi = lane;
    ARGMAX_REDUCE(Mv, Mi);

    for (int it = 0; it < 63; ++it) {
        int act = (nreal >= 2) ? 1 : 0;
        int p = Mi;
        unsigned long long after = (alive >> 1) >> p;
        int q = (p + 1 + __builtin_ctzll(after | 0x8000000000000000ull)) & 63;
        unsigned long long bel = alive & ((1ull << p) - 1ull);
        int pp = bel ? (63 - __builtin_clzll(bel)) : -1;
        unsigned long long aft2 = (q < 63) ? (alive >> (q + 1)) : 0ull;
        int ssp = aft2 ? (q + 1 + __builtin_ctzll(aft2)) : -1;
        int l_loc = __builtin_amdgcn_readlane(locid, p);
        int r_loc = __builtin_amdgcn_readlane(locid, q);
        int lsl = __builtin_amdgcn_readlane(locid, pp < 0 ? 0 : pp);
        int rsl = __builtin_amdgcn_readlane(locid, ssp < 0 ? 0 : ssp);
        int ls_loc = (pp >= 0) ? lsl : -1;
        int rs_loc = (ssp >= 0) ? rsl : -2;
        int Creal = (ssp >= 0) ? __builtin_amdgcn_readlane(isreal, ssp) : 0;
        if (lane == 0)
            rec[b * 63 + it] = make_int4(act ? l_loc : -9, r_loc, ls_loc, rs_loc);
        if (act) {
            // masked argmax over entries unchanged this iteration — independent
            // of the dot chain below; the two chains overlap via ILP.
            float mv = (lane == p || lane == q || lane == pp) ? -INFINITY : cosr;
            float Mv2 = mv; int Mi2 = lane;
            ARGMAX_REDUCE(Mv2, Mi2);
            int nl = 64 + it;
            float4 a = ((const float4*)&lf[l_loc][0])[lane];
            float4 bb = ((const float4*)&lf[r_loc][0])[lane];
            float4 v;
            v.x = a.x * sl4.x + bb.x * sr4.x + cb4.x;
            v.y = a.y * sl4.y + bb.y * sr4.y + cb4.y;
            v.z = a.z * sl4.z + bb.z * sr4.z + cb4.z;
            v.w = a.w * sl4.w + bb.w * sr4.w + cb4.w;
            ((float4*)&lf[nl][0])[lane] = v;
            ((float4*)(rowfeats + ((size_t)b * 63 + it) * 256))[lane] = v;
            float4 av = (pp >= 0) ? ((const float4*)&lf[ls_loc < 0 ? 0 : ls_loc][0])[lane]
                                  : make_float4(0.f, 0.f, 0.f, 0.f);
            float4 cv = Creal ? ((const float4*)&lf[rs_loc < 0 ? 0 : rs_loc][0])[lane]
                              : make_float4(0.f, 0.f, 0.f, 0.f);
            float sv = v.x * v.x + v.y * v.y + v.z * v.z + v.w * v.w;
            float da = av.x * v.x + av.y * v.y + av.z * v.z + av.w * v.w;
            float dc = cv.x * v.x + cv.y * v.y + cv.z * v.z + cv.w * v.w;
            SUM3_REDUCE(sv, da, dc);      // uniform totals in all lanes
            float nn = sqrtf(sv);
            if (lane == it) n1 = nn;      // norm of node nl lives in lane it
            float nA = 1.f, nC = 1.f;
            if (pp >= 0) nA = (ls_loc < 64) ? rdl_f(n0, ls_loc) : rdl_f(n1, ls_loc - 64);
            if (Creal)   nC = (rs_loc < 64) ? rdl_f(n0, rs_loc) : rdl_f(n1, rs_loc - 64);
            float cosA = da / fmaxf(nA * nn, 1e-8f);
            float cosC = Creal ? (dc / fmaxf(nn * nC, 1e-8f)) : -INFINITY;
            if (lane == p) { cosr = cosC; locid = nl; }
            if (lane == pp) cosr = cosA;
            if (lane == q) cosr = -INFINITY;
            // fold the two updated entries into the next argmax
            if (pp >= 0 && (cosA > Mv2 || (cosA == Mv2 && pp < Mi2))) { Mv2 = cosA; Mi2 = pp; }
            if (cosC > Mv2 || (cosC == Mv2 && p < Mi2)) { Mv2 = cosC; Mi2 = p; }
            Mv = Mv2; Mi = Mi2;
            alive &= ~(1ull << q);
            nreal -= 1;
        }
    }
}

// ---- pass 2: one-wave id assignment (CAS-probe dedup, arbitrary id order) ----

__global__ __launch_bounds__(64) void idassign_kernel(
    const int4* __restrict__ rec, const int* __restrict__ index_g,
    int* __restrict__ targets, int* __restrict__ meta, int* __restrict__ newsrc) {
    __shared__ int s_map[64][128];   // local id -> gid per row
    __shared__ int s_hk[HSIZE], s_hv[HSIZE];
    int b = threadIdx.x;             // row
    for (int i = b; i < HSIZE; i += 64) s_hk[i] = -1;
    for (int i = b; i < 4096; i += 64) s_map[i >> 6][i & 63] = index_g[i];
    int N0 = meta[1];
    int Ncur = N0, Tcur = 0;
    __syncthreads();
    int4 R = rec[b * 63];
    for (int it = 0; it < 63; ++it) {
        int4 Rn = R;
        if (it + 1 < 63) Rn = rec[b * 63 + it + 1];   // prefetch next record
        int act = (R.x != -9) ? 1 : 0;
        int l_g = 0, r_g = 0, key = 0, nid = 0;
        int ls_g = -1, rs_g = -2;
        unsigned h = 0;
        int won = 0, need = 0;
        if (act) {
            l_g = s_map[b][R.x];
            r_g = s_map[b][R.y];
            ls_g = (R.z >= 0) ? s_map[b][R.z] : R.z;
            rs_g = (R.w >= 0) ? s_map[b][R.w] : R.w;
            key = (l_g << HBITS) | r_g;
            h = hash0(key);
            need = 1;
        }
        while (__any(need)) {
            if (need) {
                int prev = atomicCAS(&s_hk[h], -1, key);
                if (prev == -1) { won = 1; need = 0; }
                else if (prev == key) { need = 0; }
                else { h = (h + 1) & HMASK; }
            }
        }
        unsigned long long actmask = __ballot(act != 0);
        unsigned long long winmask = __ballot(won != 0);
        unsigned long long below = (1ull << b) - 1ull;
        int ar = __popcll(actmask & below);
        int nact = __popcll(actmask);
        int newc = __popcll(winmask);
        if (won) {
            nid = Ncur + __popcll(winmask & below);
            s_hv[h] = nid;
        }
        __syncthreads();   // winners' s_hv visible to same-iteration duplicates
        if (act && !won) nid = s_hv[h];
        if (won) newsrc[nid - N0] = (b << 6) | it;
        if (act) {
            int o1 = Tcur + ar;
            targets[o1 * 3 + 0] = l_g;
            targets[o1 * 3 + 1] = ls_g;
            targets[o1 * 3 + 2] = r_g;
            int o2 = Tcur + nact + ar;
            targets[o2 * 3 + 0] = r_g;
            targets[o2 * 3 + 1] = l_g;
            targets[o2 * 3 + 2] = rs_g;
            s_map[b][64 + it] = nid;
        }
        Ncur += newc;
        Tcur += 2 * nact;
        R = Rn;
    }
    if (b == 0) { meta[2] = Ncur; meta[3] = Tcur; meta[4] = Ncur - N0; }
}

// ---- pass 3: scatter first-occurrence composed rows into global feats ----

__global__ __launch_bounds__(64) void materialize_kernel(
    const float* __restrict__ rowfeats, const int* __restrict__ newsrc,
    const int* __restrict__ meta, float* __restrict__ feats) {
    int g = blockIdx.x;
    if (g >= meta[4]) return;
    int pk = newsrc[g];
    int b = pk >> 6, it = pk & 63;
    int N0 = meta[1];
    ((float4*)(feats + (size_t)(N0 + g) * 256))[threadIdx.x] =
        ((const float4*)(rowfeats + ((size_t)b * 63 + it) * 256))[threadIdx.x];
}

__global__ void append_kernel(const float* __restrict__ eos, const float* __restrict__ sos,
                              const int* __restrict__ meta, float* __restrict__ feats) {
    int n = meta[2];
    feats[(size_t)n * 256 + threadIdx.x] = eos[threadIdx.x];
    feats[(size_t)(n + 1) * 256 + threadIdx.x] = sos[threadIdx.x];
}

// ---- bf16 conversion to fragment-major layout ----
// fhT[tile][ks][kq*16+col] (short8): tile = row/16, col = row%16, element
// range of entry = [(ks*4+kq)*8, +8). A wave's B-load for (tile, ks) is then
// fhT + tile*512 + ks*64 + lane  -> 64 consecutive short8 = coalesced 1KB.
__global__ __launch_bounds__(256) void convert_feats_kernel(
    const float* __restrict__ feats, short8* __restrict__ fhT) {
    int g = blockIdx.x * 256 + threadIdx.x;   // over NMAX*32 short8s
    int tile = g >> 9, rem = g & 511;
    int ks = rem >> 6, lane64 = rem & 63;
    int kq = lane64 >> 4, col = lane64 & 15;
    int row = tile * 16 + col;
    int e0 = (ks * 4 + kq) * 8;
    const float4* src = (const float4*)(feats + (size_t)row * 256 + e0);
    float4 v0 = src[0], v1 = src[1];
    short8 o;
    o[0] = (short)f2bf(v0.x); o[1] = (short)f2bf(v0.y);
    o[2] = (short)f2bf(v0.z); o[3] = (short)f2bf(v0.w);
    o[4] = (short)f2bf(v1.x); o[5] = (short)f2bf(v1.y);
    o[6] = (short)f2bf(v1.z); o[7] = (short)f2bf(v1.w);
    fhT[g] = o;
}

// ---- out rows (bf16) + exact fp32 target logit ----
__global__ __launch_bounds__(256) void prep_outs_kernel(
    const float* __restrict__ feats, const int* __restrict__ targets,
    const int* __restrict__ meta, const float* __restrict__ comp_l,
    const float* __restrict__ comp_r, const float* __restrict__ cb,
    unsigned short* __restrict__ oh, float* __restrict__ tdot) {
    int T = meta[3];
    int Ntot = meta[2] + 2;
    int t = blockIdx.x * 4 + (threadIdx.x >> 6);
    if (t >= T) return;
    int lane = threadIdx.x & 63;
    int c0 = 4 * (lane & 3);
    float4 sl4 = make_float4(1.f / (1.f + __expf(-comp_l[c0])),
                             1.f / (1.f + __expf(-comp_l[c0 + 1])),
                             1.f / (1.f + __expf(-comp_l[c0 + 2])),
                             1.f / (1.f + __expf(-comp_l[c0 + 3])));
    float4 sr4 = make_float4(1.f / (1.f + __expf(-comp_r[c0])),
                             1.f / (1.f + __expf(-comp_r[c0 + 1])),
                             1.f / (1.f + __expf(-comp_r[c0 + 2])),
                             1.f / (1.f + __expf(-comp_r[c0 + 3])));
    float4 cb4 = make_float4(cb[c0], cb[c0 + 1], cb[c0 + 2], cb[c0 + 3]);
    int t0 = targets[t * 3 + 0];
    int i1 = targets[t * 3 + 1], i2 = targets[t * 3 + 2];
    if (i1 < 0) i1 += Ntot;
    if (i2 < 0) i2 += Ntot;
    float4 a = ((const float4*)(feats + (size_t)i1 * 256))[lane];
    float4 b = ((const float4*)(feats + (size_t)i2 * 256))[lane];
    float4 ft = ((const float4*)(feats + (size_t)t0 * 256))[lane];
    float4 v;
    v.x = a.x * sl4.x + b.x * sr4.x + cb4.x;
    v.y = a.y * sl4.y + b.y * sr4.y + cb4.y;
    v.z = a.z * sl4.z + b.z * sr4.z + cb4.z;
    v.w = a.w * sl4.w + b.w * sr4.w + cb4.w;
    float d = v.x * ft.x + v.y * ft.y + v.z * ft.z + v.w * ft.w;
#pragma unroll
    for (int off = 32; off >= 1; off >>= 1) d += __shfl_down(d, off);
    if (lane == 0) tdot[t] = d;
    ushort4 h;
    h.x = f2bf(v.x); h.y = f2bf(v.y); h.z = f2bf(v.z); h.w = f2bf(v.w);
    ((ushort4*)(oh + (size_t)t * 256))[lane] = h;
}

// ---- loss: bf16 MFMA with coalesced fragment-major B, 4 col-slabs ----
__global__ __launch_bounds__(512) void loss_mfma_kernel(
    const short8* __restrict__ fhT, const unsigned short* __restrict__ oh,
    const int* __restrict__ meta, float2* __restrict__ partial) {
    __shared__ float s_m[64][2], s_s[64][2];
    int T = meta[3];
    int Ntot = meta[2] + 2;
    int row0 = blockIdx.x * 64;
    if (row0 >= T) return;
    int slab = blockIdx.y;
    int P = (Ntot + 127) >> 7;            // 32-col steps per slab
    int cstart = slab * (P << 5);
    int cend = min(Ntot, cstart + (P << 5));
    int tid = threadIdx.x, lane = tid & 63, w = tid >> 6;
    int mq = w >> 1, nq = w & 1;
    int mrow = row0 + mq * 16 + (lane & 15);
    int kq = lane >> 4;
    const short8* pah = (const short8*)(oh + (size_t)mrow * 256);
    short8 Ah[8];
#pragma unroll
    for (int ks = 0; ks < 8; ++ks) Ah[ks] = pah[ks * 4 + kq];
    float m0 = -1e30f, m1 = -1e30f, m2 = -1e30f, m3 = -1e30f;
    float s0 = 0.f, s1 = 0.f, s2 = 0.f, s3 = 0.f;
    for (int nb = cstart; nb < cend; nb += 32) {
        const short8* pb = fhT + ((size_t)(nb >> 4) + nq) * 512;
        f32x4 a0 = {0.f, 0.f, 0.f, 0.f}, a1 = a0;
#pragma unroll
        for (int ks = 0; ks < 4; ++ks) {
            a0 = __builtin_amdgcn_mfma_f32_16x16x32_bf16(Ah[ks], pb[ks * 64 + lane], a0, 0, 0, 0);
            a1 = __builtin_amdgcn_mfma_f32_16x16x32_bf16(Ah[ks + 4], pb[(ks + 4) * 64 + lane], a1, 0, 0, 0);
        }
        int col = nb + nq * 16 + (lane & 15);
        bool cv = col < cend;
        float v0 = cv ? (a0[0] + a1[0]) * LOG2E : -INFINITY;
        float v1 = cv ? (a0[1] + a1[1]) * LOG2E : -INFINITY;
        float v2 = cv ? (a0[2] + a1[2]) * LOG2E : -INFINITY;
        float v3 = cv ? (a0[3] + a1[3]) * LOG2E : -INFINITY;
        float mn;
        mn = fmaxf(m0, v0); s0 = s0 * exp2f(m0 - mn) + exp2f(v0 - mn); m0 = mn;
        mn = fmaxf(m1, v1); s1 = s1 * exp2f(m1 - mn) + exp2f(v1 - mn); m1 = mn;
        mn = fmaxf(m2, v2); s2 = s2 * exp2f(m2 - mn) + exp2f(v2 - mn); m2 = mn;
        mn = fmaxf(m3, v3); s3 = s3 * exp2f(m3 - mn) + exp2f(v3 - mn); m3 = mn;
    }
#pragma unroll
    for (int off = 1; off < 16; off <<= 1) {
        float mo, so, mn;
        mo = __shfl_xor(m0, off); so = __shfl_xor(s0, off);
        mn = fmaxf(m0, mo); s0 = s0 * exp2f(m0 - mn) + so * exp2f(mo - mn); m0 = mn;
        mo = __shfl_xor(m1, off); so = __shfl_xor(s1, off);
        mn = fmaxf(m1, mo); s1 = s1 * exp2f(m1 - mn) + so * exp2f(mo - mn); m1 = mn;
        mo = __shfl_xor(m2, off); so = __shfl_xor(s2, off);
        mn = fmaxf(m2, mo); s2 = s2 * exp2f(m2 - mn) + so * exp2f(mo - mn); m2 = mn;
        mo = __shfl_xor(m3, off); so = __shfl_xor(s3, off);
        mn = fmaxf(m3, mo); s3 = s3 * exp2f(m3 - mn) + so * exp2f(mo - mn); m3 = mn;
    }
    if ((lane & 15) == 0) {
        int rbase = mq * 16 + kq * 4;
        s_m[rbase + 0][nq] = m0; s_s[rbase + 0][nq] = s0;
        s_m[rbase + 1][nq] = m1; s_s[rbase + 1][nq] = s1;
        s_m[rbase + 2][nq] = m2; s_s[rbase + 2][nq] = s2;
        s_m[rbase + 3][nq] = m3; s_s[rbase + 3][nq] = s3;
    }
    __syncthreads();
    if (tid < 64) {
        float ma = s_m[tid][0], mb = s_m[tid][1];
        float mn = fmaxf(ma, mb);
        float ss = s_s[tid][0] * exp2f(ma - mn) + s_s[tid][1] * exp2f(mb - mn);
        partial[(size_t)slab * NMAX + row0 + tid] = make_float2(mn, ss);
    }
}

__global__ __launch_bounds__(256) void combine_kernel(
    const float2* __restrict__ partial, const float* __restrict__ tdot,
    const int* __restrict__ meta, float* __restrict__ acc) {
    int T = meta[3];
    int r = blockIdx.x * 256 + threadIdx.x;
    float loss = 0.f;
    if (r < T) {
        float2 p0 = partial[r];
        float2 p1 = partial[NMAX + r];
        float2 p2 = partial[2 * NMAX + r];
        float2 p3 = partial[3 * NMAX + r];
        float mn = fmaxf(fmaxf(p0.x, p1.x), fmaxf(p2.x, p3.x));
        float ss = p0.y * exp2f(p0.x - mn) + p1.y * exp2f(p1.x - mn) +
                   p2.y * exp2f(p2.x - mn) + p3.y * exp2f(p3.x - mn);
        loss = (mn + __log2f(ss)) * LN2 - tdot[r];
    }
#pragma unroll
    for (int off = 32; off >= 1; off >>= 1) loss += __shfl_down(loss, off);
    if ((threadIdx.x & 63) == 0) atomicAdd(acc, loss);
}

__global__ void finalize_kernel(const float* __restrict__ acc, const int* __restrict__ meta,
                                float* __restrict__ out) {
    out[0] = acc[0] / (float)meta[3];
}

extern "C" void kernel_launch(void* const* d_in, const int* in_sizes, int n_in,
                              void* d_out, int out_size, void* d_ws, size_t ws_size,
                              hipStream_t stream) {
    const int* x = (const int*)d_in[0];
    const float* emb = (const float*)d_in[1];
    const float* comp_l = (const float*)d_in[2];
    const float* comp_r = (const float*)d_in[3];
    const float* cb = (const float*)d_in[4];
    const float* sos = (const float*)d_in[5];
    const float* eos = (const float*)d_in[6];
    float* out = (float*)d_out;

    float* feats = (float*)d_ws;                   // 8192*256
    float* norms = feats + (size_t)NMAX * 256;     // 8192
    int* index_g = (int*)(norms + NMAX);           // 4096
    float* cos_g = (float*)(index_g + 4096);       // 4096
    int* presence = (int*)(cos_g + 4096);          // 30720
    int* rankbuf = presence + PRES;                // 30720
    int* tokens = rankbuf + PRES;                  // 4096
    int* targets = tokens + 4096;                  // 8192*3
    int* meta = targets + NMAX * 3;                // 64
    float* acc = (float*)(meta + 64);              // 64
    float* tdot = acc + 64;                        // 8192
    float2* partial = (float2*)(tdot + NMAX);      // 4*8192 float2
    int4* rec = (int4*)(partial + 4 * NMAX);       // 64*63 int4
    int* newsrc = (int*)(rec + 64 * 63);           // 4096
    float* rowfeats = (float*)(newsrc + 4096);     // 64*63*256
    short8* fhT = (short8*)(rowfeats + (size_t)64 * 63 * 256);   // NMAX*32 short8
    unsigned short* oh = (unsigned short*)(fhT + (size_t)NMAX * 32);

    hipMemsetAsync(presence, 0, PRES * sizeof(int), stream);
    hipMemsetAsync(acc, 0, sizeof(float), stream);

    mark_kernel<<<16, 256, 0, stream>>>(x, presence);
    scan_kernel<<<1, 1024, 0, stream>>>(presence, rankbuf, tokens, meta);
    map_index_kernel<<<16, 256, 0, stream>>>(x, rankbuf, meta, index_g);
    copy_feats_kernel<<<4096, 64, 0, stream>>>(emb, tokens, meta, feats, norms);
    init_cos_kernel<<<64 * 63, 64, 0, stream>>>(feats, norms, index_g, cos_g);
    treebuild_kernel<<<64, 64, 0, stream>>>(feats, norms, index_g, cos_g,
                                            rowfeats, rec, comp_l, comp_r, cb);
    idassign_kernel<<<1, 64, 0, stream>>>(rec, index_g, targets, meta, newsrc);
    materialize_kernel<<<4032, 64, 0, stream>>>(rowfeats, newsrc, meta, feats);
    append_kernel<<<1, 256, 0, stream>>>(eos, sos, meta, feats);
    convert_feats_kernel<<<1024, 256, 0, stream>>>(feats, fhT);
    prep_outs_kernel<<<2016, 256, 0, stream>>>(feats, targets, meta, comp_l, comp_r,
                                               cb, oh, tdot);
    loss_mfma_kernel<<<dim3(126, 4), 512, 0, stream>>>(fhT, oh, meta, partial);
    combine_kernel<<<32, 256, 0, stream>>>(partial, tdot, meta, acc);
    finalize_kernel<<<1, 1, 0, stream>>>(acc, meta, out);
}

// Round 10
// 249.465 us; speedup vs baseline: 13.4940x; 1.0186x over previous
//
#include <hip/hip_runtime.h>
#include <math.h>

// Banyan compose: phase-1 schedule construction + phase-2 CE replay, all on device.
// Sizes: B=64, L=64, E=256, CH=16. V=30000. Node ids < 8192.
// Phase 1 split: (a) 64 parallel per-row tree builds, (b) one-wave integer
// id-assignment replay (CAS-dedup; id order arbitrary — loss is permutation-
// invariant in node id), (c) parallel feature scatter.
// Phase 2: bf16 MFMA logits GEMM (fragment-major B layout), online logsumexp.

#define NMAX 8192
#define PRES 30720
#define HBITS 13
#define HSIZE 8192
#define HMASK 8191
#define LOG2E 1.44269504f
#define LN2 0.69314718f

typedef float f32x4 __attribute__((ext_vector_type(4)));
typedef short short8 __attribute__((ext_vector_type(8)));

__device__ __forceinline__ unsigned hash0(int key) {
    return (((unsigned)key) * 2654435761u) >> (32 - HBITS);
}

__device__ __forceinline__ unsigned short f2bf(float f) {
    unsigned u = __float_as_uint(f);
    unsigned r = ((u >> 16) & 1u) + 0x7FFFu;
    return (unsigned short)((u + r) >> 16);
}
__device__ __forceinline__ float bf2f(unsigned short b) {
    return __uint_as_float(((unsigned)b) << 16);
}

__device__ __forceinline__ float rdl_f(float v, int lane) {
    return __int_as_float(__builtin_amdgcn_readlane(__float_as_int(v), lane));
}

// DPP row_ror step: lane i receives lane (i+N)%16 of its 16-lane row.
#define SUM_STEP(CTRL, X) \
    X += __int_as_float(__builtin_amdgcn_update_dpp(0, __float_as_int(X), CTRL, 0xF, 0xF, true));
#define SUM3_REDUCE(A, B, C) {                                                  \
    SUM_STEP(0x121, A) SUM_STEP(0x121, B) SUM_STEP(0x121, C)                    \
    SUM_STEP(0x122, A) SUM_STEP(0x122, B) SUM_STEP(0x122, C)                    \
    SUM_STEP(0x124, A) SUM_STEP(0x124, B) SUM_STEP(0x124, C)                    \
    SUM_STEP(0x128, A) SUM_STEP(0x128, B) SUM_STEP(0x128, C)                    \
    A = rdl_f(A, 0) + rdl_f(A, 16) + rdl_f(A, 32) + rdl_f(A, 48);               \
    B = rdl_f(B, 0) + rdl_f(B, 16) + rdl_f(B, 32) + rdl_f(B, 48);               \
    C = rdl_f(C, 0) + rdl_f(C, 16) + rdl_f(C, 32) + rdl_f(C, 48);               \
}
#define ARGMAX_STEP(CTRL, V, I) {                                               \
    float _ov = __int_as_float(__builtin_amdgcn_update_dpp(0, __float_as_int(V), CTRL, 0xF, 0xF, true)); \
    int _oi = __builtin_amdgcn_update_dpp(0, I, CTRL, 0xF, 0xF, true);          \
    if (_ov > V || (_ov == V && _oi < I)) { V = _ov; I = _oi; }                 \
}
#define ARGMAX_REDUCE(V, I) {                                                   \
    ARGMAX_STEP(0x121, V, I) ARGMAX_STEP(0x122, V, I)                           \
    ARGMAX_STEP(0x124, V, I) ARGMAX_STEP(0x128, V, I)                           \
    float _v0 = rdl_f(V, 0), _v1 = rdl_f(V, 16), _v2 = rdl_f(V, 32), _v3 = rdl_f(V, 48); \
    int _i0 = __builtin_amdgcn_readlane(I, 0), _i1 = __builtin_amdgcn_readlane(I, 16);   \
    int _i2 = __builtin_amdgcn_readlane(I, 32), _i3 = __builtin_amdgcn_readlane(I, 48);  \
    V = _v0; I = _i0;                                                           \
    if (_v1 > V || (_v1 == V && _i1 < I)) { V = _v1; I = _i1; }                 \
    if (_v2 > V || (_v2 == V && _i2 < I)) { V = _v2; I = _i2; }                 \
    if (_v3 > V || (_v3 == V && _i3 < I)) { V = _v3; I = _i3; }                 \
}

// ---- setup kernels ----

__global__ void mark_kernel(const int* __restrict__ x, int* __restrict__ presence) {
    int i = blockIdx.x * blockDim.x + threadIdx.x;
    if (i < 4096) presence[x[i]] = 1;
}

__global__ __launch_bounds__(1024) void scan_kernel(const int* __restrict__ presence,
                                                    int* __restrict__ rank,
                                                    int* __restrict__ tokens,
                                                    int* __restrict__ meta) {
    __shared__ int part[1024];
    int tid = threadIdx.x;
    int base = tid * 30;
    int loc[30];
    int s = 0;
#pragma unroll
    for (int i = 0; i < 30; ++i) { loc[i] = s; s += presence[base + i]; }
    part[tid] = s;
    __syncthreads();
    for (int off = 1; off < 1024; off <<= 1) {
        int v = (tid >= off) ? part[tid - off] : 0;
        __syncthreads();
        part[tid] += v;
        __syncthreads();
    }
    int excl = (tid == 0) ? 0 : part[tid - 1];
#pragma unroll
    for (int i = 0; i < 30; ++i) {
        int r = excl + loc[i];
        rank[base + i] = r;
        if (presence[base + i]) tokens[r] = base + i;
    }
    if (tid == 1023) { meta[0] = part[1023]; meta[1] = part[1023] - 1; }
}

__global__ void map_index_kernel(const int* __restrict__ x, const int* __restrict__ rank,
                                 const int* __restrict__ meta, int* __restrict__ index_g) {
    int i = blockIdx.x * blockDim.x + threadIdx.x;
    if (i < 4096) {
        int r = rank[x[i]];
        index_g[i] = (r == meta[0] - 1) ? -1 : r;
    }
}

__global__ void copy_feats_kernel(const float* __restrict__ emb, const int* __restrict__ tokens,
                                  const int* __restrict__ meta, float* __restrict__ feats,
                                  float* __restrict__ norms) {
    int n = blockIdx.x;
    if (n >= meta[1]) return;
    int t = tokens[n];
    int k = threadIdx.x; // 64
    const float4* src = (const float4*)(emb + (size_t)t * 256);
    float4* dst = (float4*)(feats + (size_t)n * 256);
    float4 v = src[k];
    dst[k] = v;
    float ss = v.x * v.x + v.y * v.y + v.z * v.z + v.w * v.w;
#pragma unroll
    for (int off = 32; off >= 1; off >>= 1) ss += __shfl_down(ss, off);
    if (k == 0) norms[n] = sqrtf(ss);
}

__global__ void init_cos_kernel(const float* __restrict__ feats, const float* __restrict__ norms,
                                const int* __restrict__ index_g, float* __restrict__ cos_g) {
    int bid = blockIdx.x;
    int b = bid / 63, j = bid % 63;
    int l = index_g[b * 64 + j], r = index_g[b * 64 + j + 1];
    float c = -INFINITY;
    if (r != -1) {
        int k = threadIdx.x;
        const float4* fa = (const float4*)(feats + (size_t)l * 256);
        const float4* fb = (const float4*)(feats + (size_t)r * 256);
        float4 a = fa[k], bb = fb[k];
        float d = a.x * bb.x + a.y * bb.y + a.z * bb.z + a.w * bb.w;
#pragma unroll
        for (int off = 32; off >= 1; off >>= 1) d += __shfl_down(d, off);
        c = d / fmaxf(norms[l] * norms[r], 1e-8f);
    }
    if (threadIdx.x == 0) cos_g[b * 64 + j] = c;
}

// ---- pass 1: per-row tree build. 64 blocks x 1 wave, features in LDS.
// No global stores inside the serial loop (rec + composed rows staged in LDS,
// dumped after); init uses uniform scalar loads (no shfl round-trips).

__global__ __launch_bounds__(64) void treebuild_kernel(
    const float* __restrict__ feats, const float* __restrict__ norms_g,
    const int* __restrict__ index_g, const float* __restrict__ cos_g,
    float* __restrict__ rowfeats, int4* __restrict__ rec,
    const float* __restrict__ comp_l, const float* __restrict__ comp_r,
    const float* __restrict__ cb) {
    __shared__ float lf[127][256];
    __shared__ int4 s_rec[63];
    int b = blockIdx.x;
    int lane = threadIdx.x;
    int c0 = 4 * (lane & 3);
    float4 sl4 = make_float4(1.f / (1.f + __expf(-comp_l[c0])),
                             1.f / (1.f + __expf(-comp_l[c0 + 1])),
                             1.f / (1.f + __expf(-comp_l[c0 + 2])),
                             1.f / (1.f + __expf(-comp_l[c0 + 3])));
    float4 sr4 = make_float4(1.f / (1.f + __expf(-comp_r[c0])),
                             1.f / (1.f + __expf(-comp_r[c0 + 1])),
                             1.f / (1.f + __expf(-comp_r[c0 + 2])),
                             1.f / (1.f + __expf(-comp_r[c0 + 3])));
    float4 cb4 = make_float4(cb[c0], cb[c0 + 1], cb[c0 + 2], cb[c0 + 3]);

    int gid = index_g[b * 64 + lane];
    int isreal = (gid >= 0) ? 1 : 0;
    // init: index_g[b*64+j] is uniform per j -> scalar loads, deeply pipelined.
    for (int j = 0; j < 64; ++j) {
        int g = index_g[b * 64 + j];
        int gc = g < 0 ? 0 : g;
        ((float4*)&lf[j][0])[lane] = ((const float4*)(feats + (size_t)gc * 256))[lane];
    }
    float n0 = (gid >= 0) ? norms_g[gid] : 0.f;   // norm of leaf at position `lane`
    float n1 = 0.f;                               // norm of internal node 64+lane
    float cosr = (lane < 63) ? cos_g[b * 64 + lane] : -INFINITY;
    int locid = lane;
    unsigned long long alive = ~0ull;
    int nreal = 64 - __popcll(__ballot(gid < 0));

    float Mv = cosr; int Mi = lane;
    ARGMAX_REDUCE(Mv, Mi);

    for (int it = 0; it < 63; ++it) {
        int act = (nreal >= 2) ? 1 : 0;
        int p = Mi;
        unsigned long long after = (alive >> 1) >> p;
        int q = (p + 1 + __builtin_ctzll(after | 0x8000000000000000ull)) & 63;
        unsigned long long bel = alive & ((1ull << p) - 1ull);
        int pp = bel ? (63 - __builtin_clzll(bel)) : -1;
        unsigned long long aft2 = (q < 63) ? (alive >> (q + 1)) : 0ull;
        int ssp = aft2 ? (q + 1 + __builtin_ctzll(aft2)) : -1;
        int l_loc = __builtin_amdgcn_readlane(locid, p);
        int r_loc = __builtin_amdgcn_readlane(locid, q);
        int lsl = __builtin_amdgcn_readlane(locid, pp < 0 ? 0 : pp);
        int rsl = __builtin_amdgcn_readlane(locid, ssp < 0 ? 0 : ssp);
        int ls_loc = (pp >= 0) ? lsl : -1;
        int rs_loc = (ssp >= 0) ? rsl : -2;
        int Creal = (ssp >= 0) ? __builtin_amdgcn_readlane(isreal, ssp) : 0;
        if (lane == 0)
            s_rec[it] = make_int4(act ? l_loc : -9, r_loc, ls_loc, rs_loc);
        if (act) {
            // masked argmax over unchanged entries — overlaps the dot chain (ILP)
            float mv = (lane == p || lane == q || lane == pp) ? -INFINITY : cosr;
            float Mv2 = mv; int Mi2 = lane;
            ARGMAX_REDUCE(Mv2, Mi2);
            int nl = 64 + it;
            float4 a = ((const float4*)&lf[l_loc][0])[lane];
            float4 bb = ((const float4*)&lf[r_loc][0])[lane];
            float4 v;
            v.x = a.x * sl4.x + bb.x * sr4.x + cb4.x;
            v.y = a.y * sl4.y + bb.y * sr4.y + cb4.y;
            v.z = a.z * sl4.z + bb.z * sr4.z + cb4.z;
            v.w = a.w * sl4.w + bb.w * sr4.w + cb4.w;
            ((float4*)&lf[nl][0])[lane] = v;
            float4 av = (pp >= 0) ? ((const float4*)&lf[ls_loc < 0 ? 0 : ls_loc][0])[lane]
                                  : make_float4(0.f, 0.f, 0.f, 0.f);
            float4 cv = Creal ? ((const float4*)&lf[rs_loc < 0 ? 0 : rs_loc][0])[lane]
                              : make_float4(0.f, 0.f, 0.f, 0.f);
            float sv = v.x * v.x + v.y * v.y + v.z * v.z + v.w * v.w;
            float da = av.x * v.x + av.y * v.y + av.z * v.z + av.w * v.w;
            float dc = cv.x * v.x + cv.y * v.y + cv.z * v.z + cv.w * v.w;
            SUM3_REDUCE(sv, da, dc);      // uniform totals in all lanes
            float nn = sqrtf(sv);
            if (lane == it) n1 = nn;      // norm of node nl lives in lane it
            float nA = 1.f, nC = 1.f;
            if (pp >= 0) nA = (ls_loc < 64) ? rdl_f(n0, ls_loc) : rdl_f(n1, ls_loc - 64);
            if (Creal)   nC = (rs_loc < 64) ? rdl_f(n0, rs_loc) : rdl_f(n1, rs_loc - 64);
            float cosA = da / fmaxf(nA * nn, 1e-8f);
            float cosC = Creal ? (dc / fmaxf(nn * nC, 1e-8f)) : -INFINITY;
            if (lane == p) { cosr = cosC; locid = nl; }
            if (lane == pp) cosr = cosA;
            if (lane == q) cosr = -INFINITY;
            if (pp >= 0 && (cosA > Mv2 || (cosA == Mv2 && pp < Mi2))) { Mv2 = cosA; Mi2 = pp; }
            if (cosC > Mv2 || (cosC == Mv2 && p < Mi2)) { Mv2 = cosC; Mi2 = p; }
            Mv = Mv2; Mi = Mi2;
            alive &= ~(1ull << q);
            nreal -= 1;
        }
    }
    // dump composed rows + records to global (coalesced, pipelined)
    for (int it = 0; it < 63; ++it) {
        ((float4*)(rowfeats + ((size_t)b * 63 + it) * 256))[lane] =
            ((const float4*)&lf[64 + it][0])[lane];
    }
    if (lane < 63) rec[b * 63 + lane] = s_rec[lane];
}

// ---- pass 2: one-wave id assignment (CAS-probe dedup, arbitrary id order) ----

__global__ __launch_bounds__(64) void idassign_kernel(
    const int4* __restrict__ rec, const int* __restrict__ index_g,
    int* __restrict__ targets, int* __restrict__ meta, int* __restrict__ newsrc) {
    __shared__ int s_map[64][128];   // local id -> gid per row
    __shared__ int s_hk[HSIZE], s_hv[HSIZE];
    int b = threadIdx.x;             // row
    for (int i = b; i < HSIZE; i += 64) s_hk[i] = -1;
    for (int i = b; i < 4096; i += 64) s_map[i >> 6][i & 63] = index_g[i];
    int N0 = meta[1];
    int Ncur = N0, Tcur = 0;
    __syncthreads();
    int4 R = rec[b * 63];
    for (int it = 0; it < 63; ++it) {
        int4 Rn = R;
        if (it + 1 < 63) Rn = rec[b * 63 + it + 1];   // prefetch next record
        int act = (R.x != -9) ? 1 : 0;
        int l_g = 0, r_g = 0, key = 0, nid = 0;
        int ls_g = -1, rs_g = -2;
        unsigned h = 0;
        int won = 0, need = 0;
        if (act) {
            l_g = s_map[b][R.x];
            r_g = s_map[b][R.y];
            ls_g = (R.z >= 0) ? s_map[b][R.z] : R.z;
            rs_g = (R.w >= 0) ? s_map[b][R.w] : R.w;
            key = (l_g << HBITS) | r_g;
            h = hash0(key);
            need = 1;
        }
        while (__any(need)) {
            if (need) {
                int prev = atomicCAS(&s_hk[h], -1, key);
                if (prev == -1) { won = 1; need = 0; }
                else if (prev == key) { need = 0; }
                else { h = (h + 1) & HMASK; }
            }
        }
        unsigned long long actmask = __ballot(act != 0);
        unsigned long long winmask = __ballot(won != 0);
        unsigned long long below = (1ull << b) - 1ull;
        int ar = __popcll(actmask & below);
        int nact = __popcll(actmask);
        int newc = __popcll(winmask);
        if (won) {
            nid = Ncur + __popcll(winmask & below);
            s_hv[h] = nid;
        }
        __syncthreads();   // winners' s_hv visible to same-iteration duplicates
        if (act && !won) nid = s_hv[h];
        if (won) newsrc[nid - N0] = (b << 6) | it;
        if (act) {
            int o1 = Tcur + ar;
            targets[o1 * 3 + 0] = l_g;
            targets[o1 * 3 + 1] = ls_g;
            targets[o1 * 3 + 2] = r_g;
            int o2 = Tcur + nact + ar;
            targets[o2 * 3 + 0] = r_g;
            targets[o2 * 3 + 1] = l_g;
            targets[o2 * 3 + 2] = rs_g;
            s_map[b][64 + it] = nid;
        }
        Ncur += newc;
        Tcur += 2 * nact;
        R = Rn;
    }
    if (b == 0) { meta[2] = Ncur; meta[3] = Tcur; meta[4] = Ncur - N0; }
}

// ---- pass 3: scatter first-occurrence composed rows into global feats ----

__global__ __launch_bounds__(64) void materialize_kernel(
    const float* __restrict__ rowfeats, const int* __restrict__ newsrc,
    const int* __restrict__ meta, float* __restrict__ feats) {
    int g = blockIdx.x;
    if (g >= meta[4]) return;
    int pk = newsrc[g];
    int b = pk >> 6, it = pk & 63;
    int N0 = meta[1];
    ((float4*)(feats + (size_t)(N0 + g) * 256))[threadIdx.x] =
        ((const float4*)(rowfeats + ((size_t)b * 63 + it) * 256))[threadIdx.x];
}

__global__ void append_kernel(const float* __restrict__ eos, const float* __restrict__ sos,
                              const int* __restrict__ meta, float* __restrict__ feats) {
    int n = meta[2];
    feats[(size_t)n * 256 + threadIdx.x] = eos[threadIdx.x];
    feats[(size_t)(n + 1) * 256 + threadIdx.x] = sos[threadIdx.x];
}

// ---- bf16 conversion to fragment-major layout ----
__global__ __launch_bounds__(256) void convert_feats_kernel(
    const float* __restrict__ feats, short8* __restrict__ fhT) {
    int g = blockIdx.x * 256 + threadIdx.x;   // over NMAX*32 short8s
    int tile = g >> 9, rem = g & 511;
    int ks = rem >> 6, lane64 = rem & 63;
    int kq = lane64 >> 4, col = lane64 & 15;
    int row = tile * 16 + col;
    int e0 = (ks * 4 + kq) * 8;
    const float4* src = (const float4*)(feats + (size_t)row * 256 + e0);
    float4 v0 = src[0], v1 = src[1];
    short8 o;
    o[0] = (short)f2bf(v0.x); o[1] = (short)f2bf(v0.y);
    o[2] = (short)f2bf(v0.z); o[3] = (short)f2bf(v0.w);
    o[4] = (short)f2bf(v1.x); o[5] = (short)f2bf(v1.y);
    o[6] = (short)f2bf(v1.z); o[7] = (short)f2bf(v1.w);
    fhT[g] = o;
}

// ---- out rows (bf16) + exact fp32 target logit ----
__global__ __launch_bounds__(256) void prep_outs_kernel(
    const float* __restrict__ feats, const int* __restrict__ targets,
    const int* __restrict__ meta, const float* __restrict__ comp_l,
    const float* __restrict__ comp_r, const float* __restrict__ cb,
    unsigned short* __restrict__ oh, float* __restrict__ tdot) {
    int T = meta[3];
    int Ntot = meta[2] + 2;
    int t = blockIdx.x * 4 + (threadIdx.x >> 6);
    if (t >= T) return;
    int lane = threadIdx.x & 63;
    int c0 = 4 * (lane & 3);
    float4 sl4 = make_float4(1.f / (1.f + __expf(-comp_l[c0])),
                             1.f / (1.f + __expf(-comp_l[c0 + 1])),
                             1.f / (1.f + __expf(-comp_l[c0 + 2])),
                             1.f / (1.f + __expf(-comp_l[c0 + 3])));
    float4 sr4 = make_float4(1.f / (1.f + __expf(-comp_r[c0])),
                             1.f / (1.f + __expf(-comp_r[c0 + 1])),
                             1.f / (1.f + __expf(-comp_r[c0 + 2])),
                             1.f / (1.f + __expf(-comp_r[c0 + 3])));
    float4 cb4 = make_float4(cb[c0], cb[c0 + 1], cb[c0 + 2], cb[c0 + 3]);
    int t0 = targets[t * 3 + 0];
    int i1 = targets[t * 3 + 1], i2 = targets[t * 3 + 2];
    if (i1 < 0) i1 += Ntot;
    if (i2 < 0) i2 += Ntot;
    float4 a = ((const float4*)(feats + (size_t)i1 * 256))[lane];
    float4 b = ((const float4*)(feats + (size_t)i2 * 256))[lane];
    float4 ft = ((const float4*)(feats + (size_t)t0 * 256))[lane];
    float4 v;
    v.x = a.x * sl4.x + b.x * sr4.x + cb4.x;
    v.y = a.y * sl4.y + b.y * sr4.y + cb4.y;
    v.z = a.z * sl4.z + b.z * sr4.z + cb4.z;
    v.w = a.w * sl4.w + b.w * sr4.w + cb4.w;
    float d = v.x * ft.x + v.y * ft.y + v.z * ft.z + v.w * ft.w;
#pragma unroll
    for (int off = 32; off >= 1; off >>= 1) d += __shfl_down(d, off);
    if (lane == 0) tdot[t] = d;
    ushort4 h;
    h.x = f2bf(v.x); h.y = f2bf(v.y); h.z = f2bf(v.z); h.w = f2bf(v.w);
    ((ushort4*)(oh + (size_t)t * 256))[lane] = h;
}

// ---- loss: bf16 MFMA with coalesced fragment-major B, 4 col-slabs ----
__global__ __launch_bounds__(512) void loss_mfma_kernel(
    const short8* __restrict__ fhT, const unsigned short* __restrict__ oh,
    const int* __restrict__ meta, float2* __restrict__ partial) {
    __shared__ float s_m[64][2], s_s[64][2];
    int T = meta[3];
    int Ntot = meta[2] + 2;
    int row0 = blockIdx.x * 64;
    if (row0 >= T) return;
    int slab = blockIdx.y;
    int P = (Ntot + 127) >> 7;            // 32-col steps per slab
    int cstart = slab * (P << 5);
    int cend = min(Ntot, cstart + (P << 5));
    int tid = threadIdx.x, lane = tid & 63, w = tid >> 6;
    int mq = w >> 1, nq = w & 1;
    int mrow = row0 + mq * 16 + (lane & 15);
    int kq = lane >> 4;
    const short8* pah = (const short8*)(oh + (size_t)mrow * 256);
    short8 Ah[8];
#pragma unroll
    for (int ks = 0; ks < 8; ++ks) Ah[ks] = pah[ks * 4 + kq];
    float m0 = -1e30f, m1 = -1e30f, m2 = -1e30f, m3 = -1e30f;
    float s0 = 0.f, s1 = 0.f, s2 = 0.f, s3 = 0.f;
    for (int nb = cstart; nb < cend; nb += 32) {
        const short8* pb = fhT + ((size_t)(nb >> 4) + nq) * 512;
        f32x4 a0 = {0.f, 0.f, 0.f, 0.f}, a1 = a0;
#pragma unroll
        for (int ks = 0; ks < 4; ++ks) {
            a0 = __builtin_amdgcn_mfma_f32_16x16x32_bf16(Ah[ks], pb[ks * 64 + lane], a0, 0, 0, 0);
            a1 = __builtin_amdgcn_mfma_f32_16x16x32_bf16(Ah[ks + 4], pb[(ks + 4) * 64 + lane], a1, 0, 0, 0);
        }
        int col = nb + nq * 16 + (lane & 15);
        bool cv = col < cend;
        float v0 = cv ? (a0[0] + a1[0]) * LOG2E : -INFINITY;
        float v1 = cv ? (a0[1] + a1[1]) * LOG2E : -INFINITY;
        float v2 = cv ? (a0[2] + a1[2]) * LOG2E : -INFINITY;
        float v3 = cv ? (a0[3] + a1[3]) * LOG2E : -INFINITY;
        // branchy online update: 1 exp2 in the common (no new max) case
        if (v0 > m0) { s0 = s0 * exp2f(m0 - v0) + 1.f; m0 = v0; } else s0 += exp2f(v0 - m0);
        if (v1 > m1) { s1 = s1 * exp2f(m1 - v1) + 1.f; m1 = v1; } else s1 += exp2f(v1 - m1);
        if (v2 > m2) { s2 = s2 * exp2f(m2 - v2) + 1.f; m2 = v2; } else s2 += exp2f(v2 - m2);
        if (v3 > m3) { s3 = s3 * exp2f(m3 - v3) + 1.f; m3 = v3; } else s3 += exp2f(v3 - m3);
    }
#pragma unroll
    for (int off = 1; off < 16; off <<= 1) {
        float mo, so, mn;
        mo = __shfl_xor(m0, off); so = __shfl_xor(s0, off);
        mn = fmaxf(m0, mo); s0 = s0 * exp2f(m0 - mn) + so * exp2f(mo - mn); m0 = mn;
        mo = __shfl_xor(m1, off); so = __shfl_xor(s1, off);
        mn = fmaxf(m1, mo); s1 = s1 * exp2f(m1 - mn) + so * exp2f(mo - mn); m1 = mn;
        mo = __shfl_xor(m2, off); so = __shfl_xor(s2, off);
        mn = fmaxf(m2, mo); s2 = s2 * exp2f(m2 - mn) + so * exp2f(mo - mn); m2 = mn;
        mo = __shfl_xor(m3, off); so = __shfl_xor(s3, off);
        mn = fmaxf(m3, mo); s3 = s3 * exp2f(m3 - mn) + so * exp2f(mo - mn); m3 = mn;
    }
    if ((lane & 15) == 0) {
        int rbase = mq * 16 + kq * 4;
        s_m[rbase + 0][nq] = m0; s_s[rbase + 0][nq] = s0;
        s_m[rbase + 1][nq] = m1; s_s[rbase + 1][nq] = s1;
        s_m[rbase + 2][nq] = m2; s_s[rbase + 2][nq] = s2;
        s_m[rbase + 3][nq] = m3; s_s[rbase + 3][nq] = s3;
    }
    __syncthreads();
    if (tid < 64) {
        float ma = s_m[tid][0], mb = s_m[tid][1];
        float mn = fmaxf(ma, mb);
        float ss = s_s[tid][0] * exp2f(ma - mn) + s_s[tid][1] * exp2f(mb - mn);
        partial[(size_t)slab * NMAX + row0 + tid] = make_float2(mn, ss);
    }
}

__global__ __launch_bounds__(256) void combine_kernel(
    const float2* __restrict__ partial, const float* __restrict__ tdot,
    const int* __restrict__ meta, float* __restrict__ acc) {
    int T = meta[3];
    int r = blockIdx.x * 256 + threadIdx.x;
    float loss = 0.f;
    if (r < T) {
        float2 p0 = partial[r];
        float2 p1 = partial[NMAX + r];
        float2 p2 = partial[2 * NMAX + r];
        float2 p3 = partial[3 * NMAX + r];
        float mn = fmaxf(fmaxf(p0.x, p1.x), fmaxf(p2.x, p3.x));
        float ss = p0.y * exp2f(p0.x - mn) + p1.y * exp2f(p1.x - mn) +
                   p2.y * exp2f(p2.x - mn) + p3.y * exp2f(p3.x - mn);
        loss = (mn + __log2f(ss)) * LN2 - tdot[r];
    }
#pragma unroll
    for (int off = 32; off >= 1; off >>= 1) loss += __shfl_down(loss, off);
    if ((threadIdx.x & 63) == 0) atomicAdd(acc, loss);
}

__global__ void finalize_kernel(const float* __restrict__ acc, const int* __restrict__ meta,
                                float* __restrict__ out) {
    out[0] = acc[0] / (float)meta[3];
}

extern "C" void kernel_launch(void* const* d_in, const int* in_sizes, int n_in,
                              void* d_out, int out_size, void* d_ws, size_t ws_size,
                              hipStream_t stream) {
    const int* x = (const int*)d_in[0];
    const float* emb = (const float*)d_in[1];
    const float* comp_l = (const float*)d_in[2];
    const float* comp_r = (const float*)d_in[3];
    const float* cb = (const float*)d_in[4];
    const float* sos = (const float*)d_in[5];
    const float* eos = (const float*)d_in[6];
    float* out = (float*)d_out;

    float* feats = (float*)d_ws;                   // 8192*256
    float* norms = feats + (size_t)NMAX * 256;     // 8192
    int* index_g = (int*)(norms + NMAX);           // 4096
    float* cos_g = (float*)(index_g + 4096);       // 4096
    int* presence = (int*)(cos_g + 4096);          // 30720
    int* rankbuf = presence + PRES;                // 30720
    int* tokens = rankbuf + PRES;                  // 4096
    int* targets = tokens + 4096;                  // 8192*3
    int* meta = targets + NMAX * 3;                // 64
    float* acc = (float*)(meta + 64);              // 64
    float* tdot = acc + 64;                        // 8192
    float2* partial = (float2*)(tdot + NMAX);      // 4*8192 float2
    int4* rec = (int4*)(partial + 4 * NMAX);       // 64*63 int4
    int* newsrc = (int*)(rec + 64 * 63);           // 4096
    float* rowfeats = (float*)(newsrc + 4096);     // 64*63*256
    short8* fhT = (short8*)(rowfeats + (size_t)64 * 63 * 256);   // NMAX*32 short8
    unsigned short* oh = (unsigned short*)(fhT + (size_t)NMAX * 32);

    hipMemsetAsync(presence, 0, PRES * sizeof(int), stream);
    hipMemsetAsync(acc, 0, sizeof(float), stream);

    mark_kernel<<<16, 256, 0, stream>>>(x, presence);
    scan_kernel<<<1, 1024, 0, stream>>>(presence, rankbuf, tokens, meta);
    map_index_kernel<<<16, 256, 0, stream>>>(x, rankbuf, meta, index_g);
    copy_feats_kernel<<<4096, 64, 0, stream>>>(emb, tokens, meta, feats, norms);
    init_cos_kernel<<<64 * 63, 64, 0, stream>>>(feats, norms, index_g, cos_g);
    treebuild_kernel<<<64, 64, 0, stream>>>(feats, norms, index_g, cos_g,
                                            rowfeats, rec, comp_l, comp_r, cb);
    idassign_kernel<<<1, 64, 0, stream>>>(rec, index_g, targets, meta, newsrc);
    materialize_kernel<<<4032, 64, 0, stream>>>(rowfeats, newsrc, meta, feats);
    append_kernel<<<1, 256, 0, stream>>>(eos, sos, meta, feats);
    convert_feats_kernel<<<1024, 256, 0, stream>>>(feats, fhT);
    prep_outs_kernel<<<2016, 256, 0, stream>>>(feats, targets, meta, comp_l, comp_r,
                                               cb, oh, tdot);
    loss_mfma_kernel<<<dim3(126, 4), 512, 0, stream>>>(fhT, oh, meta, partial);
    combine_kernel<<<32, 256, 0, stream>>>(partial, tdot, meta, acc);
    finalize_kernel<<<1, 1, 0, stream>>>(acc, meta, out);
}